// Round 1
// baseline (2734.618 us; speedup 1.0000x reference)
//
#include <hip/hip_runtime.h>
#include <math.h>

#define LN_EPS 1e-5f
#define COS_EPS 1e-8f

// ---------------- CSR build ----------------
__global__ void count_deg(const int* __restrict__ src, const int* __restrict__ dst,
                          int* __restrict__ deg_src, int* __restrict__ deg_dst, int E) {
    int e = blockIdx.x * blockDim.x + threadIdx.x;
    if (e < E) {
        atomicAdd(&deg_src[src[e]], 1);
        atomicAdd(&deg_dst[dst[e]], 1);
    }
}

// single-block exclusive scan (n up to ~64K); also initializes cursor = row_ptr
__global__ void scan_excl(const int* __restrict__ deg, int* __restrict__ rp,
                          int* __restrict__ cur, int n) {
    __shared__ int sdata[256];
    __shared__ int s_carry;
    if (threadIdx.x == 0) s_carry = 0;
    __syncthreads();
    for (int base = 0; base < n; base += 256) {
        int i = base + threadIdx.x;
        int v = (i < n) ? deg[i] : 0;
        sdata[threadIdx.x] = v;
        __syncthreads();
        for (int off = 1; off < 256; off <<= 1) {
            int t = (threadIdx.x >= off) ? sdata[threadIdx.x - off] : 0;
            __syncthreads();
            sdata[threadIdx.x] += t;
            __syncthreads();
        }
        int incl = sdata[threadIdx.x];
        if (i < n) {
            int ex = s_carry + incl - v;
            rp[i] = ex;
            cur[i] = ex;
        }
        __syncthreads();
        if (threadIdx.x == 255) s_carry += sdata[255];
        __syncthreads();
    }
    if (threadIdx.x == 0) rp[n] = s_carry;
}

__global__ void fill_csr(const int* __restrict__ src, const int* __restrict__ dst,
                         int* __restrict__ cur_src, int* __restrict__ cur_dst,
                         int* __restrict__ csr_src_dst, int* __restrict__ csr_dst_eid, int E) {
    int e = blockIdx.x * blockDim.x + threadIdx.x;
    if (e < E) {
        int s = src[e], d = dst[e];
        int p = atomicAdd(&cur_src[s], 1);
        csr_src_dst[p] = d;
        int q = atomicAdd(&cur_dst[d], 1);
        csr_dst_eid[q] = e;
    }
}

// ---------------- per-layer kernels ----------------

// mu[n] = mean over outgoing edges (src==n) of x[dst]. block = Fin threads, 1 node/block
__global__ void mu_kernel(const float* __restrict__ X, const int* __restrict__ rp,
                          const int* __restrict__ cdst, float* __restrict__ MU, int Fin) {
    int n = blockIdx.x;
    int f = threadIdx.x;
    int j0 = rp[n], j1 = rp[n + 1];
    float acc = 0.f;
    for (int j = j0; j < j1; ++j) {
        int d = cdst[j];
        acc += X[(size_t)d * Fin + f];
    }
    float deg = (float)(j1 - j0);
    MU[(size_t)n * Fin + f] = acc / fmaxf(deg, 1.f);
}

// per-node L2 norm of mu; one wave per node
__global__ void norm_kernel(const float* __restrict__ MU, float* __restrict__ NRM,
                            int N, int Fin) {
    int wid = (blockIdx.x * blockDim.x + threadIdx.x) >> 6;
    int lane = threadIdx.x & 63;
    if (wid >= N) return;
    const float* m = MU + (size_t)wid * Fin;
    float s = 0.f;
    for (int f = lane; f < Fin; f += 64) { float v = m[f]; s += v * v; }
    for (int msk = 32; msk > 0; msk >>= 1) s += __shfl_xor(s, msk, 64);
    if (lane == 0) NRM[wid] = sqrtf(s);
}

// cosine-similarity attention per edge; one wave per edge
__global__ void alpha_kernel(const float* __restrict__ MU, const float* __restrict__ NRM,
                             const int* __restrict__ src, const int* __restrict__ dst,
                             float* __restrict__ ALPHA, int E, int Fin) {
    int wid = (blockIdx.x * blockDim.x + threadIdx.x) >> 6;
    int lane = threadIdx.x & 63;
    if (wid >= E) return;
    int s = src[wid], d = dst[wid];
    const float* a = MU + (size_t)s * Fin;
    const float* c = MU + (size_t)d * Fin;
    float acc = 0.f;
    for (int f = lane; f < Fin; f += 64) acc += a[f] * c[f];
    for (int msk = 32; msk > 0; msk >>= 1) acc += __shfl_xor(acc, msk, 64);
    if (lane == 0) ALPHA[wid] = acc / fmaxf(NRM[s] * NRM[d], COS_EPS);
}

// Y = X @ W ; block = max(Co,64) threads, 16 rows/block, X rows staged in LDS
__global__ void gemm_kernel(const float* __restrict__ X, const float* __restrict__ W,
                            float* __restrict__ Y, int N, int Fin, int Co) {
    extern __shared__ float xs[];
    int row0 = blockIdx.x * 16;
    int t = threadIdx.x;
    int total = 16 * Fin;
    for (int i = t; i < total; i += blockDim.x) {
        int r = i / Fin, k = i - r * Fin;
        int row = row0 + r;
        xs[i] = (row < N) ? X[(size_t)row * Fin + k] : 0.f;
    }
    __syncthreads();
    if (t >= Co) return;
    float acc[16];
#pragma unroll
    for (int r = 0; r < 16; ++r) acc[r] = 0.f;
    for (int k = 0; k < Fin; k += 4) {
        float w0 = W[(size_t)(k + 0) * Co + t];
        float w1 = W[(size_t)(k + 1) * Co + t];
        float w2 = W[(size_t)(k + 2) * Co + t];
        float w3 = W[(size_t)(k + 3) * Co + t];
#pragma unroll
        for (int r = 0; r < 16; ++r) {
            float4 xv = *reinterpret_cast<const float4*>(&xs[r * Fin + k]);
            acc[r] = fmaf(xv.x, w0, acc[r]);
            acc[r] = fmaf(xv.y, w1, acc[r]);
            acc[r] = fmaf(xv.z, w2, acc[r]);
            acc[r] = fmaf(xv.w, w3, acc[r]);
        }
    }
    for (int r = 0; r < 16; ++r) {
        int row = row0 + r;
        if (row < N) Y[(size_t)row * Co + t] = acc[r];
    }
}

// Y = ELU(X @ W + S + Bb); same structure as gemm_kernel
__global__ void gemm_bias_elu_kernel(const float* __restrict__ X, const float* __restrict__ W,
                                     const float* __restrict__ Bb, const float* __restrict__ S,
                                     float* __restrict__ Y, int N, int Fin, int Co) {
    extern __shared__ float xs[];
    int row0 = blockIdx.x * 16;
    int t = threadIdx.x;
    int total = 16 * Fin;
    for (int i = t; i < total; i += blockDim.x) {
        int r = i / Fin, k = i - r * Fin;
        int row = row0 + r;
        xs[i] = (row < N) ? X[(size_t)row * Fin + k] : 0.f;
    }
    __syncthreads();
    if (t >= Co) return;
    float acc[16];
#pragma unroll
    for (int r = 0; r < 16; ++r) acc[r] = 0.f;
    for (int k = 0; k < Fin; k += 4) {
        float w0 = W[(size_t)(k + 0) * Co + t];
        float w1 = W[(size_t)(k + 1) * Co + t];
        float w2 = W[(size_t)(k + 2) * Co + t];
        float w3 = W[(size_t)(k + 3) * Co + t];
#pragma unroll
        for (int r = 0; r < 16; ++r) {
            float4 xv = *reinterpret_cast<const float4*>(&xs[r * Fin + k]);
            acc[r] = fmaf(xv.x, w0, acc[r]);
            acc[r] = fmaf(xv.y, w1, acc[r]);
            acc[r] = fmaf(xv.z, w2, acc[r]);
            acc[r] = fmaf(xv.w, w3, acc[r]);
        }
    }
    float bias = Bb[t];
    for (int r = 0; r < 16; ++r) {
        int row = row0 + r;
        if (row < N) {
            float o = acc[r] + S[(size_t)row * Co + t] + bias;
            Y[(size_t)row * Co + t] = (o > 0.f) ? o : expm1f(o);
        }
    }
}

// per-head LayerNorm in place; block = 64*H threads (one wave per head), 1 row/block
__global__ void ln_kernel(float* __restrict__ XL, const float* __restrict__ g,
                          const float* __restrict__ b, int H, int C) {
    int n = blockIdx.x;
    int h = threadIdx.x >> 6;
    int lane = threadIdx.x & 63;
    size_t idx = (size_t)n * H * C + (size_t)h * C + lane;
    float v = (lane < C) ? XL[idx] : 0.f;
    float s = v;
    for (int msk = 32; msk > 0; msk >>= 1) s += __shfl_xor(s, msk, 64);
    float mu_ = s / (float)C;
    float d = (lane < C) ? (v - mu_) : 0.f;
    float s2 = d * d;
    for (int msk = 32; msk > 0; msk >>= 1) s2 += __shfl_xor(s2, msk, 64);
    float var = s2 / (float)C;
    if (lane < C) {
        float y = (v - mu_) * rsqrtf(var + LN_EPS) * g[lane] + b[lane];
        XL[idx] = y;
    }
}

// S[n] = sum over incoming edges of xl_ln[src[e]]*alpha[e] + self-loop term
__global__ void scatter_kernel(const float* __restrict__ XLN, const float* __restrict__ ALPHA,
                               const int* __restrict__ rp_dst, const int* __restrict__ eid,
                               const int* __restrict__ src, const float* __restrict__ NRM,
                               float* __restrict__ S, int Co) {
    int n = blockIdx.x;
    int f = threadIdx.x;
    int j0 = rp_dst[n], j1 = rp_dst[n + 1];
    float acc = 0.f;
    for (int j = j0; j < j1; ++j) {
        int e = eid[j];
        int sn = src[e];
        float a = ALPHA[e];
        if (f < Co) acc += XLN[(size_t)sn * Co + f] * a;
    }
    float nn = NRM[n];
    float n2 = nn * nn;
    float aself = n2 / fmaxf(n2, COS_EPS);
    if (f < Co) {
        acc += XLN[(size_t)n * Co + f] * aself;
        S[(size_t)n * Co + f] = acc;
    }
}

// row-wise log_softmax; one wave per row
__global__ void logsoftmax_kernel(const float* __restrict__ S, float* __restrict__ OUT,
                                  int N, int C) {
    int wid = (blockIdx.x * blockDim.x + threadIdx.x) >> 6;
    int lane = threadIdx.x & 63;
    if (wid >= N) return;
    float v = (lane < C) ? S[(size_t)wid * C + lane] : -INFINITY;
    float mx = v;
    for (int msk = 32; msk > 0; msk >>= 1) mx = fmaxf(mx, __shfl_xor(mx, msk, 64));
    float ex = (lane < C) ? expf(v - mx) : 0.f;
    float se = ex;
    for (int msk = 32; msk > 0; msk >>= 1) se += __shfl_xor(se, msk, 64);
    if (lane < C) OUT[(size_t)wid * C + lane] = v - mx - logf(se);
}

extern "C" void kernel_launch(void* const* d_in, const int* in_sizes, int n_in,
                              void* d_out, int out_size, void* d_ws, size_t ws_size,
                              hipStream_t stream) {
    const float* x   = (const float*)d_in[0];
    const int*   ei  = (const int*)d_in[1];
    const float* W0  = (const float*)d_in[2];
    const float* g0  = (const float*)d_in[3];
    const float* b0  = (const float*)d_in[4];
    const float* B0  = (const float*)d_in[5];
    const float* bb0 = (const float*)d_in[6];
    const float* W1  = (const float*)d_in[7];
    const float* g1  = (const float*)d_in[8];
    const float* b1  = (const float*)d_in[9];
    const float* B1  = (const float*)d_in[10];
    const float* bb1 = (const float*)d_in[11];
    const float* W2  = (const float*)d_in[12];
    const float* g2  = (const float*)d_in[13];
    const float* b2  = (const float*)d_in[14];
    // d_in[15] (B2, 256x1) and d_in[16] (bb2, 1): per-row constant shifts ->
    // log_softmax is shift-invariant per row -> mathematically dead. Skipped.
    float* out = (float*)d_out;

    const int N = in_sizes[0] / 128;
    const int E = in_sizes[1] / 2;
    const int* src = ei;
    const int* dst = ei + E;

    char* ws = (char*)d_ws;
    size_t off = 0;
    auto alloc = [&](size_t bytes) -> void* {
        void* p = ws + off;
        off += (bytes + 255) & ~(size_t)255;
        return p;
    };
    int* deg_src     = (int*)alloc((size_t)N * 4);
    int* deg_dst     = (int*)alloc((size_t)N * 4);
    int* rp_src      = (int*)alloc((size_t)(N + 1) * 4);
    int* rp_dst      = (int*)alloc((size_t)(N + 1) * 4);
    int* cur_src     = (int*)alloc((size_t)N * 4);
    int* cur_dst     = (int*)alloc((size_t)N * 4);
    int* csr_src_dst = (int*)alloc((size_t)E * 4);
    int* csr_dst_eid = (int*)alloc((size_t)E * 4);
    float* ALPHA     = (float*)alloc((size_t)E * 4);
    float* NRM       = (float*)alloc((size_t)N * 4);
    float* M         = (float*)alloc((size_t)N * 256 * 4);
    float* P         = (float*)alloc((size_t)N * 256 * 4);
    float* Q         = (float*)alloc((size_t)N * 256 * 4);
    (void)ws_size;

    // ---- CSR build (graph static across layers) ----
    hipMemsetAsync(deg_src, 0, (size_t)N * 4, stream);
    hipMemsetAsync(deg_dst, 0, (size_t)N * 4, stream);
    int egrid = (E + 255) / 256;
    count_deg<<<egrid, 256, 0, stream>>>(src, dst, deg_src, deg_dst, E);
    scan_excl<<<1, 256, 0, stream>>>(deg_src, rp_src, cur_src, N);
    scan_excl<<<1, 256, 0, stream>>>(deg_dst, rp_dst, cur_dst, N);
    fill_csr<<<egrid, 256, 0, stream>>>(src, dst, cur_src, cur_dst,
                                        csr_src_dst, csr_dst_eid, E);

    int wgridN = (N * 64 + 255) / 256;   // one wave per node
    int wgridE = ((E + 3) / 4);          // one wave per edge (4 waves/block)

    auto run_layer = [&](const float* xin, int Fin, int H, int C,
                         const float* W, const float* g, const float* b,
                         const float* Bw, const float* Bb,
                         float* MU, float* XL, float* SBUF, float* OUTBUF) {
        int Co = H * C;
        int bt = (Co >= 64) ? Co : 64;
        mu_kernel<<<N, Fin, 0, stream>>>(xin, rp_src, csr_src_dst, MU, Fin);
        norm_kernel<<<wgridN, 256, 0, stream>>>(MU, NRM, N, Fin);
        alpha_kernel<<<wgridE, 256, 0, stream>>>(MU, NRM, src, dst, ALPHA, E, Fin);
        int ggrid = (N + 15) / 16;
        size_t lds = (size_t)16 * Fin * sizeof(float);
        gemm_kernel<<<ggrid, bt, lds, stream>>>(xin, W, XL, N, Fin, Co);
        ln_kernel<<<N, 64 * H, 0, stream>>>(XL, g, b, H, C);
        scatter_kernel<<<N, bt, 0, stream>>>(XL, ALPHA, rp_dst, csr_dst_eid, src,
                                             NRM, SBUF, Co);
        if (Bw) {
            gemm_bias_elu_kernel<<<ggrid, Co, lds, stream>>>(xin, Bw, Bb, SBUF,
                                                             OUTBUF, N, Fin, Co);
        }
    };

    // layer 0: x[N,128] -> Q[N,256]
    run_layer(x, 128, 4, 64, W0, g0, b0, B0, bb0, /*MU*/M, /*XL*/P, /*S*/M, /*out*/Q);
    // layer 1: Q[N,256] -> P[N,256]
    run_layer(Q, 256, 4, 64, W1, g1, b1, B1, bb1, /*MU*/M, /*XL*/P, /*S*/M, /*out*/P);
    // layer 2: P[N,256] -> S in M[N,40]; no bias GEMM (dead under log_softmax)
    run_layer(P, 256, 1, 40, W2, g2, b2, nullptr, nullptr, /*MU*/M, /*XL*/Q, /*S*/M, /*out*/nullptr);

    logsoftmax_kernel<<<wgridN, 256, 0, stream>>>(M, out, N, 40);
}

// Round 2
// 2012.145 us; speedup vs baseline: 1.3591x; 1.3591x over previous
//
#include <hip/hip_runtime.h>
#include <math.h>

#define LN_EPS 1e-5f
#define COS_EPS 1e-8f

typedef short bf16x8 __attribute__((ext_vector_type(8)));
typedef float f32x4 __attribute__((ext_vector_type(4)));

static __device__ __forceinline__ unsigned short f2bf(float f) {
    unsigned u = __float_as_uint(f);
    u = u + 0x7FFFu + ((u >> 16) & 1u);   // round-to-nearest-even
    return (unsigned short)(u >> 16);
}
static __device__ __forceinline__ float bf2f(short s) {
    return __uint_as_float(((unsigned)(unsigned short)s) << 16);
}

// ---------------- CSR build ----------------
__global__ void count_deg(const int* __restrict__ src, const int* __restrict__ dst,
                          int* __restrict__ deg_src, int* __restrict__ deg_dst, int E) {
    int e = blockIdx.x * blockDim.x + threadIdx.x;
    if (e < E) {
        atomicAdd(&deg_src[src[e]], 1);
        atomicAdd(&deg_dst[dst[e]], 1);
    }
}

__global__ void scan_excl(const int* __restrict__ deg, int* __restrict__ rp,
                          int* __restrict__ cur, int n) {
    __shared__ int sdata[256];
    __shared__ int s_carry;
    if (threadIdx.x == 0) s_carry = 0;
    __syncthreads();
    for (int base = 0; base < n; base += 256) {
        int i = base + threadIdx.x;
        int v = (i < n) ? deg[i] : 0;
        sdata[threadIdx.x] = v;
        __syncthreads();
        for (int off = 1; off < 256; off <<= 1) {
            int t = (threadIdx.x >= off) ? sdata[threadIdx.x - off] : 0;
            __syncthreads();
            sdata[threadIdx.x] += t;
            __syncthreads();
        }
        int incl = sdata[threadIdx.x];
        if (i < n) {
            int ex = s_carry + incl - v;
            rp[i] = ex;
            cur[i] = ex;
        }
        __syncthreads();
        if (threadIdx.x == 255) s_carry += sdata[255];
        __syncthreads();
    }
    if (threadIdx.x == 0) rp[n] = s_carry;
}

__global__ void fill_csr(const int* __restrict__ src, const int* __restrict__ dst,
                         int* __restrict__ cur_src, int* __restrict__ cur_dst,
                         int* __restrict__ csr_src_dst, int* __restrict__ csr_dst_eid, int E) {
    int e = blockIdx.x * blockDim.x + threadIdx.x;
    if (e < E) {
        int s = src[e], d = dst[e];
        int p = atomicAdd(&cur_src[s], 1);
        csr_src_dst[p] = d;
        int q = atomicAdd(&cur_dst[d], 1);
        csr_dst_eid[q] = e;
    }
}

// ---------------- casts / packing ----------------
__global__ void cast_bf16(const float* __restrict__ X, short* __restrict__ Y, int n4) {
    int i = blockIdx.x * blockDim.x + threadIdx.x;
    if (i >= n4) return;
    float4 v = reinterpret_cast<const float4*>(X)[i];
    short4 o;
    o.x = (short)f2bf(v.x); o.y = (short)f2bf(v.y);
    o.z = (short)f2bf(v.z); o.w = (short)f2bf(v.w);
    reinterpret_cast<short4*>(Y)[i] = o;
}

// Pack W (K x ncols f32, row-major) into per-lane MFMA B-fragment layout:
// Wp[((kt*NCT_total + ct_base + ctl)*64 + lane)*8 + j] = W[kt*32+(lane>>4)*8+j][ctl*16+(lane&15)]
__global__ void pack_w(const float* __restrict__ W, short* __restrict__ Wp,
                       int KT, int NCT_total, int ct_base, int nct_local, int ncols) {
    int idx = blockIdx.x * blockDim.x + threadIdx.x;
    int total = KT * nct_local * 512;
    if (idx >= total) return;
    int j = idx & 7;
    int l = (idx >> 3) & 63;
    int t = idx >> 9;                // kt*nct_local + ctl
    int ctl = t % nct_local;
    int kt = t / nct_local;
    int k = kt * 32 + (l >> 4) * 8 + j;
    int col = ctl * 16 + (l & 15);
    float v = (col < ncols) ? W[(size_t)k * ncols + col] : 0.f;
    Wp[(((size_t)kt * NCT_total + ct_base + ctl) * 64 + l) * 8 + j] = (short)f2bf(v);
}

// ---------------- MFMA GEMM ----------------
// Xb: M x (KT*32) bf16 row-major. Wp: packed fragments, NCT col-tiles of 16.
// Output: first NCT_A tiles -> XL (bf16, stride CoA, col<CoA guard),
//         remaining tiles   -> XB (f32, stride CoB).
template<int KT, int NCT, int NCT_A>
__global__ __launch_bounds__(256, 2) void mfma_gemm(const short* __restrict__ Xb,
                                                    const short* __restrict__ Wp,
                                                    short* __restrict__ XL,
                                                    float* __restrict__ XB,
                                                    int M, int CoA, int CoB) {
    const int K = KT * 32;
    int lane = threadIdx.x & 63;
    int wave = threadIdx.x >> 6;
    size_t row0 = ((size_t)blockIdx.x * 4 + wave) * 16;
    if (row0 >= (size_t)M) return;
    const short* arow = Xb + (row0 + (lane & 15)) * K + (lane >> 4) * 8;

    f32x4 acc[NCT];
#pragma unroll
    for (int ct = 0; ct < NCT; ++ct) {
        f32x4 z = {0.f, 0.f, 0.f, 0.f};
        acc[ct] = z;
    }

#pragma unroll 1
    for (int kt = 0; kt < KT; ++kt) {
        bf16x8 a = *reinterpret_cast<const bf16x8*>(arow + kt * 32);
        const short* wpk = Wp + ((size_t)kt * NCT * 64 + lane) * 8;
#pragma unroll
        for (int ct = 0; ct < NCT; ++ct) {
            bf16x8 b = *reinterpret_cast<const bf16x8*>(wpk + (size_t)ct * 512);
            acc[ct] = __builtin_amdgcn_mfma_f32_16x16x32_bf16(a, b, acc[ct], 0, 0, 0);
        }
    }

    int c0 = lane & 15;
    int r0 = (lane >> 4) * 4;
#pragma unroll
    for (int ct = 0; ct < NCT; ++ct) {
        int col = ct * 16 + c0;
#pragma unroll
        for (int j = 0; j < 4; ++j) {
            size_t row = row0 + r0 + j;
            if (ct < NCT_A) {
                if (col < CoA) XL[row * CoA + col] = (short)f2bf(acc[ct][j]);
            } else {
                XB[row * CoB + (col - NCT_A * 16)] = acc[ct][j];
            }
        }
    }
}

// ---------------- gather / normalize kernels ----------------

// mu[n] = mean over outgoing edges of x[dst]; also per-node L2 norm of mu.
// block = Fin threads, one node per block.
__global__ void mu_norm_bf(const short* __restrict__ Xb, const int* __restrict__ rp,
                           const int* __restrict__ cdst, float* __restrict__ MU,
                           float* __restrict__ NRM, int Fin) {
    __shared__ float red[256];
    int n = blockIdx.x;
    int f = threadIdx.x;
    int j0 = rp[n], j1 = rp[n + 1];
    float acc = 0.f;
    for (int j = j0; j < j1; ++j) {
        int d = cdst[j];
        acc += bf2f(Xb[(size_t)d * Fin + f]);
    }
    float m = acc / fmaxf((float)(j1 - j0), 1.f);
    MU[(size_t)n * Fin + f] = m;
    red[f] = m * m;
    __syncthreads();
    for (int s = Fin >> 1; s > 0; s >>= 1) {
        if (f < s) red[f] += red[f + s];
        __syncthreads();
    }
    if (f == 0) NRM[n] = sqrtf(red[0]);
}

// cosine-similarity attention per edge; one wave per edge, float4 loads
__global__ void alpha_kernel(const float* __restrict__ MU, const float* __restrict__ NRM,
                             const int* __restrict__ src, const int* __restrict__ dst,
                             float* __restrict__ ALPHA, int E, int Fin) {
    int wid = (blockIdx.x * blockDim.x + threadIdx.x) >> 6;
    int lane = threadIdx.x & 63;
    if (wid >= E) return;
    int s = src[wid], d = dst[wid];
    const float4* a = reinterpret_cast<const float4*>(MU + (size_t)s * Fin);
    const float4* c = reinterpret_cast<const float4*>(MU + (size_t)d * Fin);
    int nv = Fin >> 2;
    float acc = 0.f;
    for (int i = lane; i < nv; i += 64) {
        float4 av = a[i], cv = c[i];
        acc += av.x * cv.x + av.y * cv.y + av.z * cv.z + av.w * cv.w;
    }
    for (int msk = 32; msk > 0; msk >>= 1) acc += __shfl_xor(acc, msk, 64);
    if (lane == 0) ALPHA[wid] = acc / fmaxf(NRM[s] * NRM[d], COS_EPS);
}

// per-head LayerNorm in place on bf16; one wave per head, one row per block
__global__ void ln_kernel_bf(short* __restrict__ XL, const float* __restrict__ g,
                             const float* __restrict__ b, int H, int C) {
    int n = blockIdx.x;
    int h = threadIdx.x >> 6;
    int lane = threadIdx.x & 63;
    size_t idx = (size_t)n * H * C + (size_t)h * C + lane;
    float v = (lane < C) ? bf2f(XL[idx]) : 0.f;
    float s = v;
    for (int msk = 32; msk > 0; msk >>= 1) s += __shfl_xor(s, msk, 64);
    float mu_ = s / (float)C;
    float d = (lane < C) ? (v - mu_) : 0.f;
    float s2 = d * d;
    for (int msk = 32; msk > 0; msk >>= 1) s2 += __shfl_xor(s2, msk, 64);
    float var = s2 / (float)C;
    if (lane < C) {
        float y = (v - mu_) * rsqrtf(var + LN_EPS) * g[lane] + b[lane];
        XL[idx] = (short)f2bf(y);
    }
}

// S[n] = sum over incoming edges of xl_ln[src]*alpha + self-loop term;
// then (layers 0/1) out = ELU(S + XB + bb) -> bf16, or (layer 2) raw S -> f32.
__global__ void scatter_elu(const short* __restrict__ XLN, const float* __restrict__ ALPHA,
                            const int* __restrict__ rp_dst, const int* __restrict__ eid,
                            const int* __restrict__ src, const float* __restrict__ NRM,
                            const float* __restrict__ XB, const float* __restrict__ bb,
                            short* __restrict__ Yb, float* __restrict__ Yf, int Co) {
    int n = blockIdx.x;
    int f = threadIdx.x;
    if (f >= Co) return;
    int j0 = rp_dst[n], j1 = rp_dst[n + 1];
    float acc = 0.f;
    for (int j = j0; j < j1; ++j) {
        int e = eid[j];
        int sn = src[e];
        float a = ALPHA[e];
        acc += bf2f(XLN[(size_t)sn * Co + f]) * a;
    }
    float nn = NRM[n];
    float n2 = nn * nn;
    float aself = n2 / fmaxf(n2, COS_EPS);
    acc += bf2f(XLN[(size_t)n * Co + f]) * aself;
    if (XB) {
        float o = acc + XB[(size_t)n * Co + f] + bb[f];
        o = (o > 0.f) ? o : expm1f(o);
        Yb[(size_t)n * Co + f] = (short)f2bf(o);
    } else {
        Yf[(size_t)n * Co + f] = acc;
    }
}

// row-wise log_softmax; one wave per row
__global__ void logsoftmax_kernel(const float* __restrict__ S, float* __restrict__ OUT,
                                  int N, int C) {
    int wid = (blockIdx.x * blockDim.x + threadIdx.x) >> 6;
    int lane = threadIdx.x & 63;
    if (wid >= N) return;
    float v = (lane < C) ? S[(size_t)wid * C + lane] : -INFINITY;
    float mx = v;
    for (int msk = 32; msk > 0; msk >>= 1) mx = fmaxf(mx, __shfl_xor(mx, msk, 64));
    float ex = (lane < C) ? expf(v - mx) : 0.f;
    float se = ex;
    for (int msk = 32; msk > 0; msk >>= 1) se += __shfl_xor(se, msk, 64);
    if (lane < C) OUT[(size_t)wid * C + lane] = v - mx - logf(se);
}

extern "C" void kernel_launch(void* const* d_in, const int* in_sizes, int n_in,
                              void* d_out, int out_size, void* d_ws, size_t ws_size,
                              hipStream_t stream) {
    const float* x   = (const float*)d_in[0];
    const int*   ei  = (const int*)d_in[1];
    const float* W0  = (const float*)d_in[2];
    const float* g0  = (const float*)d_in[3];
    const float* b0  = (const float*)d_in[4];
    const float* B0  = (const float*)d_in[5];
    const float* bb0 = (const float*)d_in[6];
    const float* W1  = (const float*)d_in[7];
    const float* g1  = (const float*)d_in[8];
    const float* b1  = (const float*)d_in[9];
    const float* B1  = (const float*)d_in[10];
    const float* bb1 = (const float*)d_in[11];
    const float* W2  = (const float*)d_in[12];
    const float* g2  = (const float*)d_in[13];
    const float* b2  = (const float*)d_in[14];
    // d_in[15]/d_in[16] (B2 256x1, bb2): per-row constant shift, dead under log_softmax.
    float* out = (float*)d_out;

    const int N = in_sizes[0] / 128;
    const int E = in_sizes[1] / 2;
    const int* src = ei;
    const int* dst = ei + E;

    char* ws = (char*)d_ws;
    size_t off = 0;
    auto alloc = [&](size_t bytes) -> void* {
        void* p = ws + off;
        off += (bytes + 255) & ~(size_t)255;
        return p;
    };
    int* deg_src     = (int*)alloc((size_t)N * 4);
    int* deg_dst     = (int*)alloc((size_t)N * 4);
    int* rp_src      = (int*)alloc((size_t)(N + 1) * 4);
    int* rp_dst      = (int*)alloc((size_t)(N + 1) * 4);
    int* cur_src     = (int*)alloc((size_t)N * 4);
    int* cur_dst     = (int*)alloc((size_t)N * 4);
    int* csr_src_dst = (int*)alloc((size_t)E * 4);
    int* csr_dst_eid = (int*)alloc((size_t)E * 4);
    float* ALPHA     = (float*)alloc((size_t)E * 4);
    float* NRM       = (float*)alloc((size_t)N * 4);
    float* MU        = (float*)alloc((size_t)N * 256 * 4);  // also XB (f32) after alpha
    short* XLb       = (short*)alloc((size_t)N * 256 * 2);
    short* Xb_a      = (short*)alloc((size_t)N * 256 * 2);
    short* Xb_b      = (short*)alloc((size_t)N * 256 * 2);
    float* SOUT      = (float*)alloc((size_t)N * 40 * 4);
    short* Wp        = (short*)alloc((size_t)8 * 32 * 64 * 8 * 2);
    (void)ws_size;

    // ---- CSR build (graph static across layers) ----
    hipMemsetAsync(deg_src, 0, (size_t)N * 4, stream);
    hipMemsetAsync(deg_dst, 0, (size_t)N * 4, stream);
    int egrid = (E + 255) / 256;
    count_deg<<<egrid, 256, 0, stream>>>(src, dst, deg_src, deg_dst, E);
    scan_excl<<<1, 256, 0, stream>>>(deg_src, rp_src, cur_src, N);
    scan_excl<<<1, 256, 0, stream>>>(deg_dst, rp_dst, cur_dst, N);
    fill_csr<<<egrid, 256, 0, stream>>>(src, dst, cur_src, cur_dst,
                                        csr_src_dst, csr_dst_eid, E);

    // cast x -> bf16
    {
        int n4 = (N * 128) / 4;
        cast_bf16<<<(n4 + 255) / 256, 256, 0, stream>>>(x, Xb_a, n4);
    }

    int wgridN = (N * 64 + 255) / 256;  // one wave per node
    int wgridE = (E + 3) / 4;           // one wave per edge
    int ggrid  = (N + 63) / 64;         // 64 rows per GEMM block

    // ---------------- layer 0: Xb_a[N,128] -> Xb_b[N,256] ----------------
    mu_norm_bf<<<N, 128, 0, stream>>>(Xb_a, rp_src, csr_src_dst, MU, NRM, 128);
    alpha_kernel<<<wgridE, 256, 0, stream>>>(MU, NRM, src, dst, ALPHA, E, 128);
    {
        int tot = 4 * 16 * 512;
        pack_w<<<(tot + 255) / 256, 256, 0, stream>>>(W0, Wp, 4, 32, 0, 16, 256);
        pack_w<<<(tot + 255) / 256, 256, 0, stream>>>(B0, Wp, 4, 32, 16, 16, 256);
    }
    mfma_gemm<4, 32, 16><<<ggrid, 256, 0, stream>>>(Xb_a, Wp, XLb, MU, N, 256, 256);
    ln_kernel_bf<<<N, 256, 0, stream>>>(XLb, g0, b0, 4, 64);
    scatter_elu<<<N, 256, 0, stream>>>(XLb, ALPHA, rp_dst, csr_dst_eid, src, NRM,
                                       MU, bb0, Xb_b, nullptr, 256);

    // ---------------- layer 1: Xb_b[N,256] -> Xb_a[N,256] ----------------
    mu_norm_bf<<<N, 256, 0, stream>>>(Xb_b, rp_src, csr_src_dst, MU, NRM, 256);
    alpha_kernel<<<wgridE, 256, 0, stream>>>(MU, NRM, src, dst, ALPHA, E, 256);
    {
        int tot = 8 * 16 * 512;
        pack_w<<<(tot + 255) / 256, 256, 0, stream>>>(W1, Wp, 8, 32, 0, 16, 256);
        pack_w<<<(tot + 255) / 256, 256, 0, stream>>>(B1, Wp, 8, 32, 16, 16, 256);
    }
    mfma_gemm<8, 32, 16><<<ggrid, 256, 0, stream>>>(Xb_b, Wp, XLb, MU, N, 256, 256);
    ln_kernel_bf<<<N, 256, 0, stream>>>(XLb, g1, b1, 4, 64);
    scatter_elu<<<N, 256, 0, stream>>>(XLb, ALPHA, rp_dst, csr_dst_eid, src, NRM,
                                       MU, bb1, Xb_a, nullptr, 256);

    // ---------------- layer 2: Xb_a[N,256] -> SOUT[N,40] ----------------
    mu_norm_bf<<<N, 256, 0, stream>>>(Xb_a, rp_src, csr_src_dst, MU, NRM, 256);
    alpha_kernel<<<wgridE, 256, 0, stream>>>(MU, NRM, src, dst, ALPHA, E, 256);
    {
        int tot = 8 * 3 * 512;
        pack_w<<<(tot + 255) / 256, 256, 0, stream>>>(W2, Wp, 8, 3, 0, 3, 40);
    }
    mfma_gemm<8, 3, 3><<<ggrid, 256, 0, stream>>>(Xb_a, Wp, XLb, nullptr, N, 40, 0);
    ln_kernel_bf<<<N, 64, 0, stream>>>(XLb, g2, b2, 1, 40);
    scatter_elu<<<N, 64, 0, stream>>>(XLb, ALPHA, rp_dst, csr_dst_eid, src, NRM,
                                      nullptr, nullptr, nullptr, SOUT, 40);

    logsoftmax_kernel<<<wgridN, 256, 0, stream>>>(SOUT, out, N, 40);
}

// Round 4
// 1529.329 us; speedup vs baseline: 1.7881x; 1.3157x over previous
//
#include <hip/hip_runtime.h>
#include <math.h>

#define LN_EPS 1e-5f
#define COS_EPS 1e-8f

typedef short bf16x8 __attribute__((ext_vector_type(8)));
typedef float f32x4 __attribute__((ext_vector_type(4)));

static __device__ __forceinline__ unsigned short f2bf(float f) {
    unsigned u = __float_as_uint(f);
    u = u + 0x7FFFu + ((u >> 16) & 1u);   // round-to-nearest-even
    return (unsigned short)(u >> 16);
}
static __device__ __forceinline__ float bf2f(short s) {
    return __uint_as_float(((unsigned)(unsigned short)s) << 16);
}

// ---------------- CSR build ----------------
__global__ void count_deg(const int* __restrict__ src, const int* __restrict__ dst,
                          int* __restrict__ deg_src, int* __restrict__ deg_dst, int E) {
    int e = blockIdx.x * blockDim.x + threadIdx.x;
    if (e < E) {
        atomicAdd(&deg_src[src[e]], 1);
        atomicAdd(&deg_dst[dst[e]], 1);
    }
}

// hierarchical exclusive scan, both arrays fused per phase
__global__ void scan_phase1(const int* __restrict__ degA, const int* __restrict__ degB,
                            int* __restrict__ rpA, int* __restrict__ rpB,
                            int* __restrict__ bsA, int* __restrict__ bsB, int n, int nb) {
    __shared__ int sdata[256];
    int bid = blockIdx.x;
    const int* deg; int* rp; int* bs; int seg;
    if (bid < nb) { deg = degA; rp = rpA; bs = bsA; seg = bid; }
    else          { deg = degB; rp = rpB; bs = bsB; seg = bid - nb; }
    int i = seg * 256 + threadIdx.x;
    int v = (i < n) ? deg[i] : 0;
    sdata[threadIdx.x] = v;
    __syncthreads();
    for (int off = 1; off < 256; off <<= 1) {
        int t = (threadIdx.x >= off) ? sdata[threadIdx.x - off] : 0;
        __syncthreads();
        sdata[threadIdx.x] += t;
        __syncthreads();
    }
    if (i < n) rp[i] = sdata[threadIdx.x] - v;   // exclusive within block
    if (threadIdx.x == 255) bs[seg] = sdata[255];
}

__global__ void scan_phase2(int* __restrict__ bsA, int* __restrict__ bsB, int nb,
                            int* __restrict__ rpA, int* __restrict__ rpB, int n) {
    __shared__ int sdata[256];
    __shared__ int s_carry;
    for (int arr = 0; arr < 2; ++arr) {
        int* bs = arr ? bsB : bsA;
        int* rp = arr ? rpB : rpA;
        if (threadIdx.x == 0) s_carry = 0;
        __syncthreads();
        for (int base = 0; base < nb; base += 256) {
            int i = base + threadIdx.x;
            int v = (i < nb) ? bs[i] : 0;
            sdata[threadIdx.x] = v;
            __syncthreads();
            for (int off = 1; off < 256; off <<= 1) {
                int t = (threadIdx.x >= off) ? sdata[threadIdx.x - off] : 0;
                __syncthreads();
                sdata[threadIdx.x] += t;
                __syncthreads();
            }
            if (i < nb) bs[i] = s_carry + sdata[threadIdx.x] - v;
            __syncthreads();
            if (threadIdx.x == 255) s_carry += sdata[255];
            __syncthreads();
        }
        if (threadIdx.x == 0) rp[n] = s_carry;
        __syncthreads();
    }
}

__global__ void scan_phase3(int* __restrict__ rpA, int* __restrict__ rpB,
                            const int* __restrict__ bsA, const int* __restrict__ bsB,
                            int* __restrict__ curA, int* __restrict__ curB, int n, int nb) {
    int bid = blockIdx.x;
    if (bid < nb) {
        int i = bid * 256 + threadIdx.x;
        if (i < n) { int v = rpA[i] + bsA[bid]; rpA[i] = v; curA[i] = v; }
    } else {
        int seg = bid - nb;
        int i = seg * 256 + threadIdx.x;
        if (i < n) { int v = rpB[i] + bsB[seg]; rpB[i] = v; curB[i] = v; }
    }
}

__global__ void fill_csr(const int* __restrict__ src, const int* __restrict__ dst,
                         int* __restrict__ cur_src, int* __restrict__ cur_dst,
                         int* __restrict__ csr_src_dst, int* __restrict__ csr_dst_eid, int E) {
    int e = blockIdx.x * blockDim.x + threadIdx.x;
    if (e < E) {
        int s = src[e], d = dst[e];
        int p = atomicAdd(&cur_src[s], 1);
        csr_src_dst[p] = d;
        int q = atomicAdd(&cur_dst[d], 1);
        csr_dst_eid[q] = e;
    }
}

// ---------------- casts / packing ----------------
__global__ void cast_bf16(const float* __restrict__ X, short* __restrict__ Y, int n4) {
    int i = blockIdx.x * blockDim.x + threadIdx.x;
    if (i >= n4) return;
    float4 v = reinterpret_cast<const float4*>(X)[i];
    short4 o;
    o.x = (short)f2bf(v.x); o.y = (short)f2bf(v.y);
    o.z = (short)f2bf(v.z); o.w = (short)f2bf(v.w);
    reinterpret_cast<short4*>(Y)[i] = o;
}

// Pack W (K x ncols f32, row-major) into per-lane MFMA B-fragment layout
__global__ void pack_w(const float* __restrict__ W, short* __restrict__ Wp,
                       int KT, int NCT_total, int ct_base, int nct_local, int ncols) {
    int idx = blockIdx.x * blockDim.x + threadIdx.x;
    int total = KT * nct_local * 512;
    if (idx >= total) return;
    int j = idx & 7;
    int l = (idx >> 3) & 63;
    int t = idx >> 9;
    int ctl = t % nct_local;
    int kt = t / nct_local;
    int k = kt * 32 + (l >> 4) * 8 + j;
    int col = ctl * 16 + (l & 15);
    float v = (col < ncols) ? W[(size_t)k * ncols + col] : 0.f;
    Wp[(((size_t)kt * NCT_total + ct_base + ctl) * 64 + l) * 8 + j] = (short)f2bf(v);
}

// ---------------- MFMA GEMM ----------------
template<int KT, int NCT, int NCT_A>
__global__ __launch_bounds__(256, 2) void mfma_gemm(const short* __restrict__ Xb,
                                                    const short* __restrict__ Wp,
                                                    short* __restrict__ XL,
                                                    float* __restrict__ XB,
                                                    int M, int CoA, int CoB) {
    const int K = KT * 32;
    int lane = threadIdx.x & 63;
    int wave = threadIdx.x >> 6;
    size_t row0 = ((size_t)blockIdx.x * 4 + wave) * 16;
    if (row0 >= (size_t)M) return;
    const short* arow = Xb + (row0 + (lane & 15)) * K + (lane >> 4) * 8;

    f32x4 acc[NCT];
#pragma unroll
    for (int ct = 0; ct < NCT; ++ct) {
        f32x4 z = {0.f, 0.f, 0.f, 0.f};
        acc[ct] = z;
    }

#pragma unroll 1
    for (int kt = 0; kt < KT; ++kt) {
        bf16x8 a = *reinterpret_cast<const bf16x8*>(arow + kt * 32);
        const short* wpk = Wp + ((size_t)kt * NCT * 64 + lane) * 8;
#pragma unroll
        for (int ct = 0; ct < NCT; ++ct) {
            bf16x8 b = *reinterpret_cast<const bf16x8*>(wpk + (size_t)ct * 512);
            acc[ct] = __builtin_amdgcn_mfma_f32_16x16x32_bf16(a, b, acc[ct], 0, 0, 0);
        }
    }

    int c0 = lane & 15;
    int r0 = (lane >> 4) * 4;
#pragma unroll
    for (int ct = 0; ct < NCT; ++ct) {
        int col = ct * 16 + c0;
#pragma unroll
        for (int j = 0; j < 4; ++j) {
            size_t row = row0 + r0 + j;
            if (ct < NCT_A) {
                if (col < CoA) XL[row * CoA + col] = (short)f2bf(acc[ct][j]);
            } else {
                XB[row * CoB + (col - NCT_A * 16)] = acc[ct][j];
            }
        }
    }
}

// ---------------- gather / normalize kernels ----------------

// mu (bf16 out) + per-node L2 norm. block = Fin threads, one node per block.
__global__ void mu_norm_bf(const short* __restrict__ Xb, const int* __restrict__ rp,
                           const int* __restrict__ cdst, short* __restrict__ MUb,
                           float* __restrict__ NRM, int Fin) {
    __shared__ float red[256];
    int n = blockIdx.x;
    int f = threadIdx.x;
    int j0 = rp[n], j1 = rp[n + 1];
    float acc = 0.f;
    for (int j = j0; j < j1; ++j) {
        int d = cdst[j];
        acc += bf2f(Xb[(size_t)d * Fin + f]);
    }
    float m = acc / fmaxf((float)(j1 - j0), 1.f);
    MUb[(size_t)n * Fin + f] = (short)f2bf(m);
    red[f] = m * m;
    __syncthreads();
    for (int s = Fin >> 1; s > 0; s >>= 1) {
        if (f < s) red[f] += red[f + s];
        __syncthreads();
    }
    if (f == 0) NRM[n] = sqrtf(red[0]);
}

// cosine-similarity attention per edge; one wave per edge, bf16 mu rows
__global__ void alpha_kernel(const short* __restrict__ MUb, const float* __restrict__ NRM,
                             const int* __restrict__ src, const int* __restrict__ dst,
                             float* __restrict__ ALPHA, int E, int Fin) {
    int wid = (blockIdx.x * blockDim.x + threadIdx.x) >> 6;
    int lane = threadIdx.x & 63;
    if (wid >= E) return;
    int s = src[wid], d = dst[wid];
    const short2* a = reinterpret_cast<const short2*>(MUb + (size_t)s * Fin);
    const short2* c = reinterpret_cast<const short2*>(MUb + (size_t)d * Fin);
    int nv = Fin >> 1;
    float acc = 0.f;
    for (int i = lane; i < nv; i += 64) {
        short2 av = a[i], cv = c[i];
        acc += bf2f(av.x) * bf2f(cv.x) + bf2f(av.y) * bf2f(cv.y);
    }
    for (int msk = 32; msk > 0; msk >>= 1) acc += __shfl_xor(acc, msk, 64);
    if (lane == 0) ALPHA[wid] = acc / fmaxf(NRM[s] * NRM[d], COS_EPS);
}

// per-head LayerNorm in place on bf16; one wave per head, one row per block
__global__ void ln_kernel_bf(short* __restrict__ XL, const float* __restrict__ g,
                             const float* __restrict__ b, int H, int C) {
    int n = blockIdx.x;
    int h = threadIdx.x >> 6;
    int lane = threadIdx.x & 63;
    size_t idx = (size_t)n * H * C + (size_t)h * C + lane;
    float v = (lane < C) ? bf2f(XL[idx]) : 0.f;
    float s = v;
    for (int msk = 32; msk > 0; msk >>= 1) s += __shfl_xor(s, msk, 64);
    float mu_ = s / (float)C;
    float d = (lane < C) ? (v - mu_) : 0.f;
    float s2 = d * d;
    for (int msk = 32; msk > 0; msk >>= 1) s2 += __shfl_xor(s2, msk, 64);
    float var = s2 / (float)C;
    if (lane < C) {
        float y = (v - mu_) * rsqrtf(var + LN_EPS) * g[lane] + b[lane];
        XL[idx] = (short)f2bf(y);
    }
}

// S[n] = sum over incoming edges of xl_ln[src]*alpha + self-loop;
// layers 0/1: out = ELU(S + XB + bb) -> bf16; layer 2: raw S -> f32.
__global__ void scatter_elu(const short* __restrict__ XLN, const float* __restrict__ ALPHA,
                            const int* __restrict__ rp_dst, const int* __restrict__ eid,
                            const int* __restrict__ src, const float* __restrict__ NRM,
                            const float* __restrict__ XB, const float* __restrict__ bb,
                            short* __restrict__ Yb, float* __restrict__ Yf, int Co) {
    int n = blockIdx.x;
    int f = threadIdx.x;
    if (f >= Co) return;
    int j0 = rp_dst[n], j1 = rp_dst[n + 1];
    float acc = 0.f;
    for (int j = j0; j < j1; ++j) {
        int e = eid[j];
        int sn = src[e];
        float a = ALPHA[e];
        acc += bf2f(XLN[(size_t)sn * Co + f]) * a;
    }
    float nn = NRM[n];
    float n2 = nn * nn;
    float aself = n2 / fmaxf(n2, COS_EPS);
    acc += bf2f(XLN[(size_t)n * Co + f]) * aself;
    if (XB) {
        float o = acc + XB[(size_t)n * Co + f] + bb[f];
        o = (o > 0.f) ? o : expm1f(o);
        Yb[(size_t)n * Co + f] = (short)f2bf(o);
    } else {
        Yf[(size_t)n * Co + f] = acc;
    }
}

// row-wise log_softmax; one wave per row
__global__ void logsoftmax_kernel(const float* __restrict__ S, float* __restrict__ OUT,
                                  int N, int C) {
    int wid = (blockIdx.x * blockDim.x + threadIdx.x) >> 6;
    int lane = threadIdx.x & 63;
    if (wid >= N) return;
    float v = (lane < C) ? S[(size_t)wid * C + lane] : -INFINITY;
    float mx = v;
    for (int msk = 32; msk > 0; msk >>= 1) mx = fmaxf(mx, __shfl_xor(mx, msk, 64));
    float ex = (lane < C) ? expf(v - mx) : 0.f;
    float se = ex;
    for (int msk = 32; msk > 0; msk >>= 1) se += __shfl_xor(se, msk, 64);
    if (lane < C) OUT[(size_t)wid * C + lane] = v - mx - logf(se);
}

extern "C" void kernel_launch(void* const* d_in, const int* in_sizes, int n_in,
                              void* d_out, int out_size, void* d_ws, size_t ws_size,
                              hipStream_t stream) {
    const float* x   = (const float*)d_in[0];
    const int*   ei  = (const int*)d_in[1];
    const float* W0  = (const float*)d_in[2];
    const float* g0  = (const float*)d_in[3];
    const float* b0  = (const float*)d_in[4];
    const float* B0  = (const float*)d_in[5];
    const float* bb0 = (const float*)d_in[6];
    const float* W1  = (const float*)d_in[7];
    const float* g1  = (const float*)d_in[8];
    const float* b1  = (const float*)d_in[9];
    const float* B1  = (const float*)d_in[10];
    const float* bb1 = (const float*)d_in[11];
    const float* W2  = (const float*)d_in[12];
    const float* g2  = (const float*)d_in[13];
    const float* b2  = (const float*)d_in[14];
    // d_in[15]/d_in[16] (B2 256x1, bb2): per-row constant shift, dead under log_softmax.
    float* out = (float*)d_out;

    const int N = in_sizes[0] / 128;
    const int E = in_sizes[1] / 2;
    const int* src = ei;
    const int* dst = ei + E;

    char* ws = (char*)d_ws;
    size_t off = 0;
    auto alloc = [&](size_t bytes) -> void* {
        void* p = ws + off;
        off += (bytes + 255) & ~(size_t)255;
        return p;
    };
    int* deg_src     = (int*)alloc((size_t)N * 4);
    int* deg_dst     = (int*)alloc((size_t)N * 4);
    int* rp_src      = (int*)alloc((size_t)(N + 1) * 4);
    int* rp_dst      = (int*)alloc((size_t)(N + 1) * 4);
    int* cur_src     = (int*)alloc((size_t)N * 4);
    int* cur_dst     = (int*)alloc((size_t)N * 4);
    int* bs_src      = (int*)alloc((size_t)1024 * 4);
    int* bs_dst      = (int*)alloc((size_t)1024 * 4);
    int* csr_src_dst = (int*)alloc((size_t)E * 4);
    int* csr_dst_eid = (int*)alloc((size_t)E * 4);
    float* ALPHA     = (float*)alloc((size_t)E * 4);
    float* NRM       = (float*)alloc((size_t)N * 4);
    float* XBf       = (float*)alloc((size_t)N * 256 * 4);   // bias-path GEMM output
    short* MUb       = (short*)alloc((size_t)N * 256 * 2);   // bf16 neighborhood means
    short* XLb       = (short*)alloc((size_t)N * 256 * 2);
    short* Xb_a      = (short*)alloc((size_t)N * 256 * 2);
    short* Xb_b      = (short*)alloc((size_t)N * 256 * 2);
    float* SOUT      = (float*)alloc((size_t)N * 40 * 4);
    short* Wp        = (short*)alloc((size_t)8 * 32 * 64 * 8 * 2);
    (void)ws_size;

    // ---- CSR build (graph static across layers) ----
    hipMemsetAsync(deg_src, 0, (size_t)N * 4, stream);
    hipMemsetAsync(deg_dst, 0, (size_t)N * 4, stream);
    int egrid = (E + 255) / 256;
    count_deg<<<egrid, 256, 0, stream>>>(src, dst, deg_src, deg_dst, E);
    int nb = (N + 255) / 256;
    scan_phase1<<<2 * nb, 256, 0, stream>>>(deg_src, deg_dst, rp_src, rp_dst,
                                            bs_src, bs_dst, N, nb);
    scan_phase2<<<1, 256, 0, stream>>>(bs_src, bs_dst, nb, rp_src, rp_dst, N);
    scan_phase3<<<2 * nb, 256, 0, stream>>>(rp_src, rp_dst, bs_src, bs_dst,
                                            cur_src, cur_dst, N, nb);
    fill_csr<<<egrid, 256, 0, stream>>>(src, dst, cur_src, cur_dst,
                                        csr_src_dst, csr_dst_eid, E);

    // cast x -> bf16
    {
        int n4 = (N * 128) / 4;
        cast_bf16<<<(n4 + 255) / 256, 256, 0, stream>>>(x, Xb_a, n4);
    }

    int wgridN = (N * 64 + 255) / 256;  // one wave per node
    int wgridE = (E + 3) / 4;           // one wave per edge
    int ggrid  = (N + 63) / 64;         // 64 rows per GEMM block

    // ---------------- layer 0: Xb_a[N,128] -> Xb_b[N,256] ----------------
    mu_norm_bf<<<N, 128, 0, stream>>>(Xb_a, rp_src, csr_src_dst, MUb, NRM, 128);
    alpha_kernel<<<wgridE, 256, 0, stream>>>(MUb, NRM, src, dst, ALPHA, E, 128);
    {
        int tot = 4 * 16 * 512;
        pack_w<<<(tot + 255) / 256, 256, 0, stream>>>(W0, Wp, 4, 32, 0, 16, 256);
        pack_w<<<(tot + 255) / 256, 256, 0, stream>>>(B0, Wp, 4, 32, 16, 16, 256);
    }
    mfma_gemm<4, 32, 16><<<ggrid, 256, 0, stream>>>(Xb_a, Wp, XLb, XBf, N, 256, 256);
    ln_kernel_bf<<<N, 256, 0, stream>>>(XLb, g0, b0, 4, 64);
    scatter_elu<<<N, 256, 0, stream>>>(XLb, ALPHA, rp_dst, csr_dst_eid, src, NRM,
                                       XBf, bb0, Xb_b, nullptr, 256);

    // ---------------- layer 1: Xb_b[N,256] -> Xb_a[N,256] ----------------
    mu_norm_bf<<<N, 256, 0, stream>>>(Xb_b, rp_src, csr_src_dst, MUb, NRM, 256);
    alpha_kernel<<<wgridE, 256, 0, stream>>>(MUb, NRM, src, dst, ALPHA, E, 256);
    {
        int tot = 8 * 16 * 512;
        pack_w<<<(tot + 255) / 256, 256, 0, stream>>>(W1, Wp, 8, 32, 0, 16, 256);
        pack_w<<<(tot + 255) / 256, 256, 0, stream>>>(B1, Wp, 8, 32, 16, 16, 256);
    }
    mfma_gemm<8, 32, 16><<<ggrid, 256, 0, stream>>>(Xb_b, Wp, XLb, XBf, N, 256, 256);
    ln_kernel_bf<<<N, 256, 0, stream>>>(XLb, g1, b1, 4, 64);
    scatter_elu<<<N, 256, 0, stream>>>(XLb, ALPHA, rp_dst, csr_dst_eid, src, NRM,
                                       XBf, bb1, Xb_a, nullptr, 256);

    // ---------------- layer 2: Xb_a[N,256] -> SOUT[N,40] ----------------
    mu_norm_bf<<<N, 256, 0, stream>>>(Xb_a, rp_src, csr_src_dst, MUb, NRM, 256);
    alpha_kernel<<<wgridE, 256, 0, stream>>>(MUb, NRM, src, dst, ALPHA, E, 256);
    {
        int tot = 8 * 3 * 512;
        pack_w<<<(tot + 255) / 256, 256, 0, stream>>>(W2, Wp, 8, 3, 0, 3, 40);
    }
    mfma_gemm<8, 3, 3><<<ggrid, 256, 0, stream>>>(Xb_a, Wp, XLb, nullptr, N, 40, 0);
    ln_kernel_bf<<<N, 64, 0, stream>>>(XLb, g2, b2, 1, 40);
    scatter_elu<<<N, 64, 0, stream>>>(XLb, ALPHA, rp_dst, csr_dst_eid, src, NRM,
                                      nullptr, nullptr, nullptr, SOUT, 40);

    logsoftmax_kernel<<<wgridN, 256, 0, stream>>>(SOUT, out, N, 40);
}

// Round 6
// 856.893 us; speedup vs baseline: 3.1913x; 1.7847x over previous
//
#include <hip/hip_runtime.h>
#include <math.h>

#define LN_EPS 1e-5f
#define COS_EPS 1e-8f

typedef short bf16x8 __attribute__((ext_vector_type(8)));
typedef float f32x4 __attribute__((ext_vector_type(4)));

static __device__ __forceinline__ unsigned short f2bf(float f) {
    unsigned u = __float_as_uint(f);
    u = u + 0x7FFFu + ((u >> 16) & 1u);   // round-to-nearest-even
    return (unsigned short)(u >> 16);
}
static __device__ __forceinline__ float bf2f(short s) {
    return __uint_as_float(((unsigned)(unsigned short)s) << 16);
}

// load/store EPL bf16 elements per lane as one vector op
template<int EPL>
static __device__ __forceinline__ void loadrow(const short* __restrict__ p, float* r) {
    if constexpr (EPL == 4) {
        short4 v = *reinterpret_cast<const short4*>(p);
        r[0] = bf2f(v.x); r[1] = bf2f(v.y); r[2] = bf2f(v.z); r[3] = bf2f(v.w);
    } else {
        short2 v = *reinterpret_cast<const short2*>(p);
        r[0] = bf2f(v.x); r[1] = bf2f(v.y);
    }
}
template<int EPL>
static __device__ __forceinline__ void storerow(short* __restrict__ p, const float* m) {
    if constexpr (EPL == 4) {
        short4 v;
        v.x = (short)f2bf(m[0]); v.y = (short)f2bf(m[1]);
        v.z = (short)f2bf(m[2]); v.w = (short)f2bf(m[3]);
        *reinterpret_cast<short4*>(p) = v;
    } else {
        short2 v;
        v.x = (short)f2bf(m[0]); v.y = (short)f2bf(m[1]);
        *reinterpret_cast<short2*>(p) = v;
    }
}

// ---------------- CSR build ----------------
__global__ void count_deg(const int* __restrict__ src, const int* __restrict__ dst,
                          int* __restrict__ deg_src, int* __restrict__ deg_dst, int E) {
    int e = blockIdx.x * blockDim.x + threadIdx.x;
    if (e < E) {
        atomicAdd(&deg_src[src[e]], 1);
        atomicAdd(&deg_dst[dst[e]], 1);
    }
}

// hierarchical exclusive scan, both arrays fused per phase
__global__ void scan_phase1(const int* __restrict__ degA, const int* __restrict__ degB,
                            int* __restrict__ rpA, int* __restrict__ rpB,
                            int* __restrict__ bsA, int* __restrict__ bsB, int n, int nb) {
    __shared__ int sdata[256];
    int bid = blockIdx.x;
    const int* deg; int* rp; int* bs; int seg;
    if (bid < nb) { deg = degA; rp = rpA; bs = bsA; seg = bid; }
    else          { deg = degB; rp = rpB; bs = bsB; seg = bid - nb; }
    int i = seg * 256 + threadIdx.x;
    int v = (i < n) ? deg[i] : 0;
    sdata[threadIdx.x] = v;
    __syncthreads();
    for (int off = 1; off < 256; off <<= 1) {
        int t = (threadIdx.x >= off) ? sdata[threadIdx.x - off] : 0;
        __syncthreads();
        sdata[threadIdx.x] += t;
        __syncthreads();
    }
    if (i < n) rp[i] = sdata[threadIdx.x] - v;   // exclusive within block
    if (threadIdx.x == 255) bs[seg] = sdata[255];
}

__global__ void scan_phase2(int* __restrict__ bsA, int* __restrict__ bsB, int nb,
                            int* __restrict__ rpA, int* __restrict__ rpB, int n) {
    __shared__ int sdata[256];
    __shared__ int s_carry;
    for (int arr = 0; arr < 2; ++arr) {
        int* bs = arr ? bsB : bsA;
        int* rp = arr ? rpB : rpA;
        if (threadIdx.x == 0) s_carry = 0;
        __syncthreads();
        for (int base = 0; base < nb; base += 256) {
            int i = base + threadIdx.x;
            int v = (i < nb) ? bs[i] : 0;
            sdata[threadIdx.x] = v;
            __syncthreads();
            for (int off = 1; off < 256; off <<= 1) {
                int t = (threadIdx.x >= off) ? sdata[threadIdx.x - off] : 0;
                __syncthreads();
                sdata[threadIdx.x] += t;
                __syncthreads();
            }
            if (i < nb) bs[i] = s_carry + sdata[threadIdx.x] - v;
            __syncthreads();
            if (threadIdx.x == 255) s_carry += sdata[255];
            __syncthreads();
        }
        if (threadIdx.x == 0) rp[n] = s_carry;
        __syncthreads();
    }
}

__global__ void scan_phase3(int* __restrict__ rpA, int* __restrict__ rpB,
                            const int* __restrict__ bsA, const int* __restrict__ bsB,
                            int* __restrict__ curA, int* __restrict__ curB, int n, int nb) {
    int bid = blockIdx.x;
    if (bid < nb) {
        int i = bid * 256 + threadIdx.x;
        if (i < n) { int v = rpA[i] + bsA[bid]; rpA[i] = v; curA[i] = v; }
    } else {
        int seg = bid - nb;
        int i = seg * 256 + threadIdx.x;
        if (i < n) { int v = rpB[i] + bsB[seg]; rpB[i] = v; curB[i] = v; }
    }
}

// src-CSR: csr_src_dst[p]=dst, qslot[p]=dst-slot of same edge.
// dst-CSR: SRCd[q]=src. (no edge-id indirection anywhere downstream)
__global__ void fill_csr(const int* __restrict__ src, const int* __restrict__ dst,
                         int* __restrict__ cur_src, int* __restrict__ cur_dst,
                         int* __restrict__ csr_src_dst, int* __restrict__ qslot,
                         int* __restrict__ SRCd, int E) {
    int e = blockIdx.x * blockDim.x + threadIdx.x;
    if (e < E) {
        int s = src[e], d = dst[e];
        int p = atomicAdd(&cur_src[s], 1);
        int q = atomicAdd(&cur_dst[d], 1);
        csr_src_dst[p] = d;
        qslot[p] = q;
        SRCd[q] = s;
    }
}

// ---------------- casts / packing ----------------
__global__ void cast_bf16(const float* __restrict__ X, short* __restrict__ Y, int n4) {
    int i = blockIdx.x * blockDim.x + threadIdx.x;
    if (i >= n4) return;
    float4 v = reinterpret_cast<const float4*>(X)[i];
    short4 o;
    o.x = (short)f2bf(v.x); o.y = (short)f2bf(v.y);
    o.z = (short)f2bf(v.z); o.w = (short)f2bf(v.w);
    reinterpret_cast<short4*>(Y)[i] = o;
}

// Pack W (K x ncols f32, row-major) into per-lane MFMA B-fragment layout
__global__ void pack_w(const float* __restrict__ W, short* __restrict__ Wp,
                       int KT, int NCT_total, int ct_base, int nct_local, int ncols) {
    int idx = blockIdx.x * blockDim.x + threadIdx.x;
    int total = KT * nct_local * 512;
    if (idx >= total) return;
    int j = idx & 7;
    int l = (idx >> 3) & 63;
    int t = idx >> 9;
    int ctl = t % nct_local;
    int kt = t / nct_local;
    int k = kt * 32 + (l >> 4) * 8 + j;
    int col = ctl * 16 + (l & 15);
    float v = (col < ncols) ? W[(size_t)k * ncols + col] : 0.f;
    Wp[(((size_t)kt * NCT_total + ct_base + ctl) * 64 + l) * 8 + j] = (short)f2bf(v);
}

// ---------------- MFMA GEMM ----------------
template<int KT, int NCT, int NCT_A>
__global__ __launch_bounds__(256, 2) void mfma_gemm(const short* __restrict__ Xb,
                                                    const short* __restrict__ Wp,
                                                    short* __restrict__ XL,
                                                    float* __restrict__ XB,
                                                    int M, int CoA, int CoB) {
    const int K = KT * 32;
    int lane = threadIdx.x & 63;
    int wave = threadIdx.x >> 6;
    size_t row0 = ((size_t)blockIdx.x * 4 + wave) * 16;
    if (row0 >= (size_t)M) return;
    const short* arow = Xb + (row0 + (lane & 15)) * K + (lane >> 4) * 8;

    f32x4 acc[NCT];
#pragma unroll
    for (int ct = 0; ct < NCT; ++ct) {
        f32x4 z = {0.f, 0.f, 0.f, 0.f};
        acc[ct] = z;
    }

#pragma unroll 1
    for (int kt = 0; kt < KT; ++kt) {
        bf16x8 a = *reinterpret_cast<const bf16x8*>(arow + kt * 32);
        const short* wpk = Wp + ((size_t)kt * NCT * 64 + lane) * 8;
#pragma unroll
        for (int ct = 0; ct < NCT; ++ct) {
            bf16x8 b = *reinterpret_cast<const bf16x8*>(wpk + (size_t)ct * 512);
            acc[ct] = __builtin_amdgcn_mfma_f32_16x16x32_bf16(a, b, acc[ct], 0, 0, 0);
        }
    }

    int c0 = lane & 15;
    int r0 = (lane >> 4) * 4;
#pragma unroll
    for (int ct = 0; ct < NCT; ++ct) {
        int col = ct * 16 + c0;
#pragma unroll
        for (int j = 0; j < 4; ++j) {
            size_t row = row0 + r0 + j;
            if (ct < NCT_A) {
                if (col < CoA) XL[row * CoA + col] = (short)f2bf(acc[ct][j]);
            } else {
                XB[row * CoB + (col - NCT_A * 16)] = acc[ct][j];
            }
        }
    }
}

// ---------------- gather kernels: one WAVE per node, 4 rows in flight ----------------

// mu (bf16 out) + per-node L2 norm of mu
template<int EPL>
__global__ void mu_norm_v2(const short* __restrict__ Xb, const int* __restrict__ rp,
                           const int* __restrict__ cdst, short* __restrict__ MUb,
                           float* __restrict__ NRM, int N) {
    int n = (blockIdx.x * blockDim.x + threadIdx.x) >> 6;
    int lane = threadIdx.x & 63;
    if (n >= N) return;
    const int Fin = EPL * 64;
    int j0 = rp[n], j1 = rp[n + 1];
    float acc[EPL];
#pragma unroll
    for (int k = 0; k < EPL; ++k) acc[k] = 0.f;
    int j = j0;
    for (; j + 4 <= j1; j += 4) {
        int d0 = cdst[j], d1 = cdst[j + 1], d2 = cdst[j + 2], d3 = cdst[j + 3];
        float r0[EPL], r1[EPL], r2[EPL], r3[EPL];
        loadrow<EPL>(Xb + (size_t)d0 * Fin + lane * EPL, r0);
        loadrow<EPL>(Xb + (size_t)d1 * Fin + lane * EPL, r1);
        loadrow<EPL>(Xb + (size_t)d2 * Fin + lane * EPL, r2);
        loadrow<EPL>(Xb + (size_t)d3 * Fin + lane * EPL, r3);
#pragma unroll
        for (int k = 0; k < EPL; ++k) acc[k] += (r0[k] + r1[k]) + (r2[k] + r3[k]);
    }
    for (; j < j1; ++j) {
        int d = cdst[j];
        float r[EPL];
        loadrow<EPL>(Xb + (size_t)d * Fin + lane * EPL, r);
#pragma unroll
        for (int k = 0; k < EPL; ++k) acc[k] += r[k];
    }
    float inv = 1.f / fmaxf((float)(j1 - j0), 1.f);
    float m[EPL];
    float s = 0.f;
#pragma unroll
    for (int k = 0; k < EPL; ++k) { m[k] = acc[k] * inv; s += m[k] * m[k]; }
    storerow<EPL>(MUb + (size_t)n * Fin + lane * EPL, m);
    for (int msk = 32; msk > 0; msk >>= 1) s += __shfl_xor(s, msk, 64);
    if (lane == 0) NRM[n] = sqrtf(s);
}

// alpha iterated by SRC node: MU[src] row stays in registers (read once,
// sequential); only MU[dst] is a random gather. Writes ALPHAd in dst-slot order.
template<int EPL>
__global__ void alpha_src_v2(const short* __restrict__ MUb, const float* __restrict__ NRM,
                             const int* __restrict__ rp_src, const int* __restrict__ cdst,
                             const int* __restrict__ qslot, float* __restrict__ ALPHAd,
                             int N) {
    int sn = (blockIdx.x * blockDim.x + threadIdx.x) >> 6;
    int lane = threadIdx.x & 63;
    if (sn >= N) return;
    const int Fin = EPL * 64;
    float a[EPL];
    loadrow<EPL>(MUb + (size_t)sn * Fin + lane * EPL, a);
    float ns = NRM[sn];
    int j0 = rp_src[sn], j1 = rp_src[sn + 1];
    int j = j0;
    for (; j + 4 <= j1; j += 4) {
        int d0 = cdst[j], d1 = cdst[j + 1], d2 = cdst[j + 2], d3 = cdst[j + 3];
        int q0 = qslot[j], q1 = qslot[j + 1], q2 = qslot[j + 2], q3 = qslot[j + 3];
        float nd0 = NRM[d0], nd1 = NRM[d1], nd2 = NRM[d2], nd3 = NRM[d3];
        float c0[EPL], c1[EPL], c2[EPL], c3[EPL];
        loadrow<EPL>(MUb + (size_t)d0 * Fin + lane * EPL, c0);
        loadrow<EPL>(MUb + (size_t)d1 * Fin + lane * EPL, c1);
        loadrow<EPL>(MUb + (size_t)d2 * Fin + lane * EPL, c2);
        loadrow<EPL>(MUb + (size_t)d3 * Fin + lane * EPL, c3);
        float t0 = 0.f, t1 = 0.f, t2 = 0.f, t3 = 0.f;
#pragma unroll
        for (int k = 0; k < EPL; ++k) {
            t0 += a[k] * c0[k]; t1 += a[k] * c1[k];
            t2 += a[k] * c2[k]; t3 += a[k] * c3[k];
        }
        for (int msk = 32; msk > 0; msk >>= 1) {
            t0 += __shfl_xor(t0, msk, 64);
            t1 += __shfl_xor(t1, msk, 64);
            t2 += __shfl_xor(t2, msk, 64);
            t3 += __shfl_xor(t3, msk, 64);
        }
        if (lane == 0) {
            ALPHAd[q0] = t0 / fmaxf(ns * nd0, COS_EPS);
            ALPHAd[q1] = t1 / fmaxf(ns * nd1, COS_EPS);
            ALPHAd[q2] = t2 / fmaxf(ns * nd2, COS_EPS);
            ALPHAd[q3] = t3 / fmaxf(ns * nd3, COS_EPS);
        }
    }
    for (; j < j1; ++j) {
        int d = cdst[j], q = qslot[j];
        float nd = NRM[d];
        float c[EPL];
        loadrow<EPL>(MUb + (size_t)d * Fin + lane * EPL, c);
        float t = 0.f;
#pragma unroll
        for (int k = 0; k < EPL; ++k) t += a[k] * c[k];
        for (int msk = 32; msk > 0; msk >>= 1) t += __shfl_xor(t, msk, 64);
        if (lane == 0) ALPHAd[q] = t / fmaxf(ns * nd, COS_EPS);
    }
}

// per-head LayerNorm in place on bf16; one wave per head, one row per block
__global__ void ln_kernel_bf(short* __restrict__ XL, const float* __restrict__ g,
                             const float* __restrict__ b, int H, int C) {
    int n = blockIdx.x;
    int h = threadIdx.x >> 6;
    int lane = threadIdx.x & 63;
    size_t idx = (size_t)n * H * C + (size_t)h * C + lane;
    float v = (lane < C) ? bf2f(XL[idx]) : 0.f;
    float s = v;
    for (int msk = 32; msk > 0; msk >>= 1) s += __shfl_xor(s, msk, 64);
    float mu_ = s / (float)C;
    float d = (lane < C) ? (v - mu_) : 0.f;
    float s2 = d * d;
    for (int msk = 32; msk > 0; msk >>= 1) s2 += __shfl_xor(s2, msk, 64);
    float var = s2 / (float)C;
    if (lane < C) {
        float y = (v - mu_) * rsqrtf(var + LN_EPS) * g[lane] + b[lane];
        XL[idx] = (short)f2bf(y);
    }
}

// layers 0/1: one wave per dst node, Co=256 (4 bf16/lane).
// out = ELU(scatter + XB + bb) -> bf16
__global__ void scatter_elu_v2(const short* __restrict__ XLN, const float* __restrict__ ALPHAd,
                               const int* __restrict__ rp_dst, const int* __restrict__ SRCd,
                               const float* __restrict__ NRM,
                               const float* __restrict__ XB, const float* __restrict__ bb,
                               short* __restrict__ Yb, int N) {
    int n = (blockIdx.x * blockDim.x + threadIdx.x) >> 6;
    int lane = threadIdx.x & 63;
    if (n >= N) return;
    int j0 = rp_dst[n], j1 = rp_dst[n + 1];
    float acc[4] = {0.f, 0.f, 0.f, 0.f};
    int j = j0;
    for (; j + 4 <= j1; j += 4) {
        int s0 = SRCd[j], s1 = SRCd[j + 1], s2 = SRCd[j + 2], s3 = SRCd[j + 3];
        float a0 = ALPHAd[j], a1 = ALPHAd[j + 1], a2 = ALPHAd[j + 2], a3 = ALPHAd[j + 3];
        float r0[4], r1[4], r2[4], r3[4];
        loadrow<4>(XLN + (size_t)s0 * 256 + lane * 4, r0);
        loadrow<4>(XLN + (size_t)s1 * 256 + lane * 4, r1);
        loadrow<4>(XLN + (size_t)s2 * 256 + lane * 4, r2);
        loadrow<4>(XLN + (size_t)s3 * 256 + lane * 4, r3);
#pragma unroll
        for (int k = 0; k < 4; ++k)
            acc[k] += (r0[k] * a0 + r1[k] * a1) + (r2[k] * a2 + r3[k] * a3);
    }
    for (; j < j1; ++j) {
        int s = SRCd[j];
        float a = ALPHAd[j];
        float r[4];
        loadrow<4>(XLN + (size_t)s * 256 + lane * 4, r);
#pragma unroll
        for (int k = 0; k < 4; ++k) acc[k] += r[k] * a;
    }
    float nn = NRM[n], n2 = nn * nn;
    float aself = n2 / fmaxf(n2, COS_EPS);
    float rs[4];
    loadrow<4>(XLN + (size_t)n * 256 + lane * 4, rs);
#pragma unroll
    for (int k = 0; k < 4; ++k) acc[k] += rs[k] * aself;

    float4 xb = *reinterpret_cast<const float4*>(XB + (size_t)n * 256 + lane * 4);
    float4 bv = *reinterpret_cast<const float4*>(bb + lane * 4);
    float o[4] = {acc[0] + xb.x + bv.x, acc[1] + xb.y + bv.y,
                  acc[2] + xb.z + bv.z, acc[3] + xb.w + bv.w};
#pragma unroll
    for (int k = 0; k < 4; ++k) o[k] = (o[k] > 0.f) ? o[k] : expm1f(o[k]);
    storerow<4>(Yb + (size_t)n * 256 + lane * 4, o);
}

// layer 2: Co=40, one wave per dst node, raw scatter -> f32
__global__ void scatter_final(const short* __restrict__ XLN, const float* __restrict__ ALPHAd,
                              const int* __restrict__ rp_dst, const int* __restrict__ SRCd,
                              const float* __restrict__ NRM, float* __restrict__ Yf, int N) {
    int n = (blockIdx.x * blockDim.x + threadIdx.x) >> 6;
    int lane = threadIdx.x & 63;
    if (n >= N) return;
    bool act = lane < 40;
    int j0 = rp_dst[n], j1 = rp_dst[n + 1];
    float acc = 0.f;
    int j = j0;
    for (; j + 4 <= j1; j += 4) {
        int s0 = SRCd[j], s1 = SRCd[j + 1], s2 = SRCd[j + 2], s3 = SRCd[j + 3];
        float a0 = ALPHAd[j], a1 = ALPHAd[j + 1], a2 = ALPHAd[j + 2], a3 = ALPHAd[j + 3];
        float r0 = act ? bf2f(XLN[(size_t)s0 * 40 + lane]) : 0.f;
        float r1 = act ? bf2f(XLN[(size_t)s1 * 40 + lane]) : 0.f;
        float r2 = act ? bf2f(XLN[(size_t)s2 * 40 + lane]) : 0.f;
        float r3 = act ? bf2f(XLN[(size_t)s3 * 40 + lane]) : 0.f;
        acc += (r0 * a0 + r1 * a1) + (r2 * a2 + r3 * a3);
    }
    for (; j < j1; ++j) {
        int s = SRCd[j];
        float a = ALPHAd[j];
        float r = act ? bf2f(XLN[(size_t)s * 40 + lane]) : 0.f;
        acc += r * a;
    }
    float nn = NRM[n], n2 = nn * nn;
    float aself = n2 / fmaxf(n2, COS_EPS);
    if (act) {
        acc += bf2f(XLN[(size_t)n * 40 + lane]) * aself;
        Yf[(size_t)n * 40 + lane] = acc;
    }
}

// row-wise log_softmax; one wave per row
__global__ void logsoftmax_kernel(const float* __restrict__ S, float* __restrict__ OUT,
                                  int N, int C) {
    int wid = (blockIdx.x * blockDim.x + threadIdx.x) >> 6;
    int lane = threadIdx.x & 63;
    if (wid >= N) return;
    float v = (lane < C) ? S[(size_t)wid * C + lane] : -INFINITY;
    float mx = v;
    for (int msk = 32; msk > 0; msk >>= 1) mx = fmaxf(mx, __shfl_xor(mx, msk, 64));
    float ex = (lane < C) ? expf(v - mx) : 0.f;
    float se = ex;
    for (int msk = 32; msk > 0; msk >>= 1) se += __shfl_xor(se, msk, 64);
    if (lane < C) OUT[(size_t)wid * C + lane] = v - mx - logf(se);
}

extern "C" void kernel_launch(void* const* d_in, const int* in_sizes, int n_in,
                              void* d_out, int out_size, void* d_ws, size_t ws_size,
                              hipStream_t stream) {
    const float* x   = (const float*)d_in[0];
    const int*   ei  = (const int*)d_in[1];
    const float* W0  = (const float*)d_in[2];
    const float* g0  = (const float*)d_in[3];
    const float* b0  = (const float*)d_in[4];
    const float* B0  = (const float*)d_in[5];
    const float* bb0 = (const float*)d_in[6];
    const float* W1  = (const float*)d_in[7];
    const float* g1  = (const float*)d_in[8];
    const float* b1  = (const float*)d_in[9];
    const float* B1  = (const float*)d_in[10];
    const float* bb1 = (const float*)d_in[11];
    const float* W2  = (const float*)d_in[12];
    const float* g2  = (const float*)d_in[13];
    const float* b2  = (const float*)d_in[14];
    // d_in[15]/d_in[16] (B2 256x1, bb2): per-row constant shift, dead under log_softmax.
    float* out = (float*)d_out;

    const int N = in_sizes[0] / 128;
    const int E = in_sizes[1] / 2;
    const int* src = ei;
    const int* dst = ei + E;

    char* ws = (char*)d_ws;
    size_t off = 0;
    auto alloc = [&](size_t bytes) -> void* {
        void* p = ws + off;
        off += (bytes + 255) & ~(size_t)255;
        return p;
    };
    int* deg_src     = (int*)alloc((size_t)N * 4);
    int* deg_dst     = (int*)alloc((size_t)N * 4);
    int* rp_src      = (int*)alloc((size_t)(N + 1) * 4);
    int* rp_dst      = (int*)alloc((size_t)(N + 1) * 4);
    int* cur_src     = (int*)alloc((size_t)N * 4);
    int* cur_dst     = (int*)alloc((size_t)N * 4);
    int* bs_src      = (int*)alloc((size_t)1024 * 4);
    int* bs_dst      = (int*)alloc((size_t)1024 * 4);
    int* csr_src_dst = (int*)alloc((size_t)E * 4);
    int* qslot       = (int*)alloc((size_t)E * 4);
    int* SRCd        = (int*)alloc((size_t)E * 4);
    float* ALPHAd    = (float*)alloc((size_t)E * 4);
    float* NRM       = (float*)alloc((size_t)N * 4);
    float* XBf       = (float*)alloc((size_t)N * 256 * 4);   // bias-path GEMM output
    short* MUb       = (short*)alloc((size_t)N * 256 * 2);   // bf16 neighborhood means
    short* XLb       = (short*)alloc((size_t)N * 256 * 2);
    short* Xb_a      = (short*)alloc((size_t)N * 256 * 2);
    short* Xb_b      = (short*)alloc((size_t)N * 256 * 2);
    float* SOUT      = (float*)alloc((size_t)N * 40 * 4);
    short* Wp        = (short*)alloc((size_t)8 * 32 * 64 * 8 * 2);
    (void)ws_size;

    // ---- CSR build (graph static across layers) ----
    hipMemsetAsync(deg_src, 0, (size_t)N * 4, stream);
    hipMemsetAsync(deg_dst, 0, (size_t)N * 4, stream);
    int egrid = (E + 255) / 256;
    count_deg<<<egrid, 256, 0, stream>>>(src, dst, deg_src, deg_dst, E);
    int nb = (N + 255) / 256;
    scan_phase1<<<2 * nb, 256, 0, stream>>>(deg_src, deg_dst, rp_src, rp_dst,
                                            bs_src, bs_dst, N, nb);
    scan_phase2<<<1, 256, 0, stream>>>(bs_src, bs_dst, nb, rp_src, rp_dst, N);
    scan_phase3<<<2 * nb, 256, 0, stream>>>(rp_src, rp_dst, bs_src, bs_dst,
                                            cur_src, cur_dst, N, nb);
    fill_csr<<<egrid, 256, 0, stream>>>(src, dst, cur_src, cur_dst,
                                        csr_src_dst, qslot, SRCd, E);

    // cast x -> bf16
    {
        int n4 = (N * 128) / 4;
        cast_bf16<<<(n4 + 255) / 256, 256, 0, stream>>>(x, Xb_a, n4);
    }

    int wgridN = (N * 64 + 255) / 256;  // one wave per node, 4 waves/block
    int ggrid  = (N + 63) / 64;         // 64 rows per GEMM block

    // ---------------- layer 0: Xb_a[N,128] -> Xb_b[N,256] ----------------
    mu_norm_v2<2><<<wgridN, 256, 0, stream>>>(Xb_a, rp_src, csr_src_dst, MUb, NRM, N);
    alpha_src_v2<2><<<wgridN, 256, 0, stream>>>(MUb, NRM, rp_src, csr_src_dst,
                                                qslot, ALPHAd, N);
    {
        int tot = 4 * 16 * 512;
        pack_w<<<(tot + 255) / 256, 256, 0, stream>>>(W0, Wp, 4, 32, 0, 16, 256);
        pack_w<<<(tot + 255) / 256, 256, 0, stream>>>(B0, Wp, 4, 32, 16, 16, 256);
    }
    mfma_gemm<4, 32, 16><<<ggrid, 256, 0, stream>>>(Xb_a, Wp, XLb, XBf, N, 256, 256);
    ln_kernel_bf<<<N, 256, 0, stream>>>(XLb, g0, b0, 4, 64);
    scatter_elu_v2<<<wgridN, 256, 0, stream>>>(XLb, ALPHAd, rp_dst, SRCd, NRM,
                                               XBf, bb0, Xb_b, N);

    // ---------------- layer 1: Xb_b[N,256] -> Xb_a[N,256] ----------------
    mu_norm_v2<4><<<wgridN, 256, 0, stream>>>(Xb_b, rp_src, csr_src_dst, MUb, NRM, N);
    alpha_src_v2<4><<<wgridN, 256, 0, stream>>>(MUb, NRM, rp_src, csr_src_dst,
                                                qslot, ALPHAd, N);
    {
        int tot = 8 * 16 * 512;
        pack_w<<<(tot + 255) / 256, 256, 0, stream>>>(W1, Wp, 8, 32, 0, 16, 256);
        pack_w<<<(tot + 255) / 256, 256, 0, stream>>>(B1, Wp, 8, 32, 16, 16, 256);
    }
    mfma_gemm<8, 32, 16><<<ggrid, 256, 0, stream>>>(Xb_b, Wp, XLb, XBf, N, 256, 256);
    ln_kernel_bf<<<N, 256, 0, stream>>>(XLb, g1, b1, 4, 64);
    scatter_elu_v2<<<wgridN, 256, 0, stream>>>(XLb, ALPHAd, rp_dst, SRCd, NRM,
                                               XBf, bb1, Xb_a, N);

    // ---------------- layer 2: Xb_a[N,256] -> SOUT[N,40] ----------------
    mu_norm_v2<4><<<wgridN, 256, 0, stream>>>(Xb_a, rp_src, csr_src_dst, MUb, NRM, N);
    alpha_src_v2<4><<<wgridN, 256, 0, stream>>>(MUb, NRM, rp_src, csr_src_dst,
                                                qslot, ALPHAd, N);
    {
        int tot = 8 * 3 * 512;
        pack_w<<<(tot + 255) / 256, 256, 0, stream>>>(W2, Wp, 8, 3, 0, 3, 40);
    }
    mfma_gemm<8, 3, 3><<<ggrid, 256, 0, stream>>>(Xb_a, Wp, XLb, nullptr, N, 40, 0);
    ln_kernel_bf<<<N, 64, 0, stream>>>(XLb, g2, b2, 1, 40);
    scatter_final<<<wgridN, 256, 0, stream>>>(XLb, ALPHAd, rp_dst, SRCd, NRM, SOUT, N);

    logsoftmax_kernel<<<wgridN, 256, 0, stream>>>(SOUT, out, N, 40);
}

// Round 7
// 810.780 us; speedup vs baseline: 3.3728x; 1.0569x over previous
//
#include <hip/hip_runtime.h>
#include <math.h>

#define LN_EPS 1e-5f
#define COS_EPS 1e-8f

typedef short bf16x8 __attribute__((ext_vector_type(8)));
typedef float f32x4 __attribute__((ext_vector_type(4)));

static __device__ __forceinline__ unsigned short f2bf(float f) {
    unsigned u = __float_as_uint(f);
    u = u + 0x7FFFu + ((u >> 16) & 1u);   // round-to-nearest-even
    return (unsigned short)(u >> 16);
}
static __device__ __forceinline__ float bf2f(short s) {
    return __uint_as_float(((unsigned)(unsigned short)s) << 16);
}

// load/store EPL bf16 elements per lane as one vector op
template<int EPL>
static __device__ __forceinline__ void loadrow(const short* __restrict__ p, float* r) {
    if constexpr (EPL == 4) {
        short4 v = *reinterpret_cast<const short4*>(p);
        r[0] = bf2f(v.x); r[1] = bf2f(v.y); r[2] = bf2f(v.z); r[3] = bf2f(v.w);
    } else {
        short2 v = *reinterpret_cast<const short2*>(p);
        r[0] = bf2f(v.x); r[1] = bf2f(v.y);
    }
}
template<int EPL>
static __device__ __forceinline__ void storerow(short* __restrict__ p, const float* m) {
    if constexpr (EPL == 4) {
        short4 v;
        v.x = (short)f2bf(m[0]); v.y = (short)f2bf(m[1]);
        v.z = (short)f2bf(m[2]); v.w = (short)f2bf(m[3]);
        *reinterpret_cast<short4*>(p) = v;
    } else {
        short2 v;
        v.x = (short)f2bf(m[0]); v.y = (short)f2bf(m[1]);
        *reinterpret_cast<short2*>(p) = v;
    }
}

// ---------------- CSR build ----------------
__global__ void count_deg(const int* __restrict__ src, const int* __restrict__ dst,
                          int* __restrict__ deg_src, int* __restrict__ deg_dst, int E) {
    int e = blockIdx.x * blockDim.x + threadIdx.x;
    if (e < E) {
        atomicAdd(&deg_src[src[e]], 1);
        atomicAdd(&deg_dst[dst[e]], 1);
    }
}

// hierarchical exclusive scan, both arrays fused per phase
__global__ void scan_phase1(const int* __restrict__ degA, const int* __restrict__ degB,
                            int* __restrict__ rpA, int* __restrict__ rpB,
                            int* __restrict__ bsA, int* __restrict__ bsB, int n, int nb) {
    __shared__ int sdata[256];
    int bid = blockIdx.x;
    const int* deg; int* rp; int* bs; int seg;
    if (bid < nb) { deg = degA; rp = rpA; bs = bsA; seg = bid; }
    else          { deg = degB; rp = rpB; bs = bsB; seg = bid - nb; }
    int i = seg * 256 + threadIdx.x;
    int v = (i < n) ? deg[i] : 0;
    sdata[threadIdx.x] = v;
    __syncthreads();
    for (int off = 1; off < 256; off <<= 1) {
        int t = (threadIdx.x >= off) ? sdata[threadIdx.x - off] : 0;
        __syncthreads();
        sdata[threadIdx.x] += t;
        __syncthreads();
    }
    if (i < n) rp[i] = sdata[threadIdx.x] - v;   // exclusive within block
    if (threadIdx.x == 255) bs[seg] = sdata[255];
}

__global__ void scan_phase2(int* __restrict__ bsA, int* __restrict__ bsB, int nb,
                            int* __restrict__ rpA, int* __restrict__ rpB, int n) {
    __shared__ int sdata[256];
    __shared__ int s_carry;
    for (int arr = 0; arr < 2; ++arr) {
        int* bs = arr ? bsB : bsA;
        int* rp = arr ? rpB : rpA;
        if (threadIdx.x == 0) s_carry = 0;
        __syncthreads();
        for (int base = 0; base < nb; base += 256) {
            int i = base + threadIdx.x;
            int v = (i < nb) ? bs[i] : 0;
            sdata[threadIdx.x] = v;
            __syncthreads();
            for (int off = 1; off < 256; off <<= 1) {
                int t = (threadIdx.x >= off) ? sdata[threadIdx.x - off] : 0;
                __syncthreads();
                sdata[threadIdx.x] += t;
                __syncthreads();
            }
            if (i < nb) bs[i] = s_carry + sdata[threadIdx.x] - v;
            __syncthreads();
            if (threadIdx.x == 255) s_carry += sdata[255];
            __syncthreads();
        }
        if (threadIdx.x == 0) rp[n] = s_carry;
        __syncthreads();
    }
}

__global__ void scan_phase3(int* __restrict__ rpA, int* __restrict__ rpB,
                            const int* __restrict__ bsA, const int* __restrict__ bsB,
                            int* __restrict__ curA, int* __restrict__ curB, int n, int nb) {
    int bid = blockIdx.x;
    if (bid < nb) {
        int i = bid * 256 + threadIdx.x;
        if (i < n) { int v = rpA[i] + bsA[bid]; rpA[i] = v; curA[i] = v; }
    } else {
        int seg = bid - nb;
        int i = seg * 256 + threadIdx.x;
        if (i < n) { int v = rpB[i] + bsB[seg]; rpB[i] = v; curB[i] = v; }
    }
}

// src-CSR: csr_src_dst[p]=dst, qslot[p]=dst-slot of same edge.
// dst-CSR: SRCd[q]=src. (no edge-id indirection anywhere downstream)
__global__ void fill_csr(const int* __restrict__ src, const int* __restrict__ dst,
                         int* __restrict__ cur_src, int* __restrict__ cur_dst,
                         int* __restrict__ csr_src_dst, int* __restrict__ qslot,
                         int* __restrict__ SRCd, int E) {
    int e = blockIdx.x * blockDim.x + threadIdx.x;
    if (e < E) {
        int s = src[e], d = dst[e];
        int p = atomicAdd(&cur_src[s], 1);
        int q = atomicAdd(&cur_dst[d], 1);
        csr_src_dst[p] = d;
        qslot[p] = q;
        SRCd[q] = s;
    }
}

// ---------------- casts / packing ----------------
__global__ void cast_bf16(const float* __restrict__ X, short* __restrict__ Y, int n4) {
    int i = blockIdx.x * blockDim.x + threadIdx.x;
    if (i >= n4) return;
    float4 v = reinterpret_cast<const float4*>(X)[i];
    short4 o;
    o.x = (short)f2bf(v.x); o.y = (short)f2bf(v.y);
    o.z = (short)f2bf(v.z); o.w = (short)f2bf(v.w);
    reinterpret_cast<short4*>(Y)[i] = o;
}

// Pack W (K x ncols f32, row-major) into per-lane MFMA B-fragment layout
__global__ void pack_w(const float* __restrict__ W, short* __restrict__ Wp,
                       int KT, int NCT_total, int ct_base, int nct_local, int ncols) {
    int idx = blockIdx.x * blockDim.x + threadIdx.x;
    int total = KT * nct_local * 512;
    if (idx >= total) return;
    int j = idx & 7;
    int l = (idx >> 3) & 63;
    int t = idx >> 9;
    int ctl = t % nct_local;
    int kt = t / nct_local;
    int k = kt * 32 + (l >> 4) * 8 + j;
    int col = ctl * 16 + (l & 15);
    float v = (col < ncols) ? W[(size_t)k * ncols + col] : 0.f;
    Wp[(((size_t)kt * NCT_total + ct_base + ctl) * 64 + l) * 8 + j] = (short)f2bf(v);
}

// ---------------- MFMA GEMM v3: 8 waves/block, B staged through LDS ----------------
// Block = 512 threads = 8 waves, 16 rows/wave = 128 rows/block.
// Per kt-step the block cooperatively stages the NCT-fragment strip of Wp into
// LDS (linear copy, layout-preserving), then each wave does NCT ds_read_b128 +
// NCT MFMA. Output: first NCT_A tiles -> XL (bf16, col<CoA guard), rest -> XBb
// (bf16). Requires M % 16 == 0 for the wave-level tail guard.
template<int KT, int NCT, int NCT_A>
__global__ __launch_bounds__(512) void mfma_gemm_v3(const short* __restrict__ Xb,
                                                    const short* __restrict__ Wp,
                                                    short* __restrict__ XL,
                                                    short* __restrict__ XBb,
                                                    int M, int CoA) {
    __shared__ short bsm[NCT * 512];
    const int K = KT * 32;
    int lane = threadIdx.x & 63;
    int wave = threadIdx.x >> 6;
    size_t row0 = ((size_t)blockIdx.x * 8 + wave) * 16;
    bool active = row0 < (size_t)M;
    const short* arow = Xb + (row0 + (lane & 15)) * K + (lane >> 4) * 8;

    f32x4 acc[NCT];
#pragma unroll
    for (int ct = 0; ct < NCT; ++ct) {
        f32x4 z = {0.f, 0.f, 0.f, 0.f};
        acc[ct] = z;
    }

#pragma unroll 1
    for (int kt = 0; kt < KT; ++kt) {
        __syncthreads();   // previous kt's LDS reads complete
        const int4* wsrc = reinterpret_cast<const int4*>(Wp + (size_t)kt * NCT * 512);
        int4* wdst = reinterpret_cast<int4*>(bsm);
        for (int i = threadIdx.x; i < NCT * 64; i += 512) wdst[i] = wsrc[i];
        __syncthreads();
        if (active) {
            bf16x8 a = *reinterpret_cast<const bf16x8*>(arow + kt * 32);
#pragma unroll
            for (int ct = 0; ct < NCT; ++ct) {
                bf16x8 b = *reinterpret_cast<const bf16x8*>(bsm + ct * 512 + lane * 8);
                acc[ct] = __builtin_amdgcn_mfma_f32_16x16x32_bf16(a, b, acc[ct], 0, 0, 0);
            }
        }
    }
    if (!active) return;

    int c0 = lane & 15;
    int r0 = (lane >> 4) * 4;
#pragma unroll
    for (int ct = 0; ct < NCT; ++ct) {
        int col = ct * 16 + c0;
#pragma unroll
        for (int j = 0; j < 4; ++j) {
            size_t row = row0 + r0 + j;
            if (ct < NCT_A) {
                if (col < CoA) XL[row * CoA + col] = (short)f2bf(acc[ct][j]);
            } else {
                XBb[row * 256 + (col - NCT_A * 16)] = (short)f2bf(acc[ct][j]);
            }
        }
    }
}

// ---------------- gather kernels: one WAVE per node, 4 rows in flight ----------------

// mu (bf16 out) + per-node L2 norm of mu
template<int EPL>
__global__ void mu_norm_v2(const short* __restrict__ Xb, const int* __restrict__ rp,
                           const int* __restrict__ cdst, short* __restrict__ MUb,
                           float* __restrict__ NRM, int N) {
    int n = (blockIdx.x * blockDim.x + threadIdx.x) >> 6;
    int lane = threadIdx.x & 63;
    if (n >= N) return;
    const int Fin = EPL * 64;
    int j0 = rp[n], j1 = rp[n + 1];
    float acc[EPL];
#pragma unroll
    for (int k = 0; k < EPL; ++k) acc[k] = 0.f;
    int j = j0;
    for (; j + 4 <= j1; j += 4) {
        int d0 = cdst[j], d1 = cdst[j + 1], d2 = cdst[j + 2], d3 = cdst[j + 3];
        float r0[EPL], r1[EPL], r2[EPL], r3[EPL];
        loadrow<EPL>(Xb + (size_t)d0 * Fin + lane * EPL, r0);
        loadrow<EPL>(Xb + (size_t)d1 * Fin + lane * EPL, r1);
        loadrow<EPL>(Xb + (size_t)d2 * Fin + lane * EPL, r2);
        loadrow<EPL>(Xb + (size_t)d3 * Fin + lane * EPL, r3);
#pragma unroll
        for (int k = 0; k < EPL; ++k) acc[k] += (r0[k] + r1[k]) + (r2[k] + r3[k]);
    }
    for (; j < j1; ++j) {
        int d = cdst[j];
        float r[EPL];
        loadrow<EPL>(Xb + (size_t)d * Fin + lane * EPL, r);
#pragma unroll
        for (int k = 0; k < EPL; ++k) acc[k] += r[k];
    }
    float inv = 1.f / fmaxf((float)(j1 - j0), 1.f);
    float m[EPL];
    float s = 0.f;
#pragma unroll
    for (int k = 0; k < EPL; ++k) { m[k] = acc[k] * inv; s += m[k] * m[k]; }
    storerow<EPL>(MUb + (size_t)n * Fin + lane * EPL, m);
    for (int msk = 32; msk > 0; msk >>= 1) s += __shfl_xor(s, msk, 64);
    if (lane == 0) NRM[n] = sqrtf(s);
}

// alpha iterated by SRC node: MU[src] row stays in registers (read once,
// sequential); only MU[dst] is a random gather. Writes ALPHAd in dst-slot order.
template<int EPL>
__global__ void alpha_src_v2(const short* __restrict__ MUb, const float* __restrict__ NRM,
                             const int* __restrict__ rp_src, const int* __restrict__ cdst,
                             const int* __restrict__ qslot, float* __restrict__ ALPHAd,
                             int N) {
    int sn = (blockIdx.x * blockDim.x + threadIdx.x) >> 6;
    int lane = threadIdx.x & 63;
    if (sn >= N) return;
    const int Fin = EPL * 64;
    float a[EPL];
    loadrow<EPL>(MUb + (size_t)sn * Fin + lane * EPL, a);
    float ns = NRM[sn];
    int j0 = rp_src[sn], j1 = rp_src[sn + 1];
    int j = j0;
    for (; j + 4 <= j1; j += 4) {
        int d0 = cdst[j], d1 = cdst[j + 1], d2 = cdst[j + 2], d3 = cdst[j + 3];
        int q0 = qslot[j], q1 = qslot[j + 1], q2 = qslot[j + 2], q3 = qslot[j + 3];
        float nd0 = NRM[d0], nd1 = NRM[d1], nd2 = NRM[d2], nd3 = NRM[d3];
        float c0[EPL], c1[EPL], c2[EPL], c3[EPL];
        loadrow<EPL>(MUb + (size_t)d0 * Fin + lane * EPL, c0);
        loadrow<EPL>(MUb + (size_t)d1 * Fin + lane * EPL, c1);
        loadrow<EPL>(MUb + (size_t)d2 * Fin + lane * EPL, c2);
        loadrow<EPL>(MUb + (size_t)d3 * Fin + lane * EPL, c3);
        float t0 = 0.f, t1 = 0.f, t2 = 0.f, t3 = 0.f;
#pragma unroll
        for (int k = 0; k < EPL; ++k) {
            t0 += a[k] * c0[k]; t1 += a[k] * c1[k];
            t2 += a[k] * c2[k]; t3 += a[k] * c3[k];
        }
        for (int msk = 32; msk > 0; msk >>= 1) {
            t0 += __shfl_xor(t0, msk, 64);
            t1 += __shfl_xor(t1, msk, 64);
            t2 += __shfl_xor(t2, msk, 64);
            t3 += __shfl_xor(t3, msk, 64);
        }
        if (lane == 0) {
            ALPHAd[q0] = t0 / fmaxf(ns * nd0, COS_EPS);
            ALPHAd[q1] = t1 / fmaxf(ns * nd1, COS_EPS);
            ALPHAd[q2] = t2 / fmaxf(ns * nd2, COS_EPS);
            ALPHAd[q3] = t3 / fmaxf(ns * nd3, COS_EPS);
        }
    }
    for (; j < j1; ++j) {
        int d = cdst[j], q = qslot[j];
        float nd = NRM[d];
        float c[EPL];
        loadrow<EPL>(MUb + (size_t)d * Fin + lane * EPL, c);
        float t = 0.f;
#pragma unroll
        for (int k = 0; k < EPL; ++k) t += a[k] * c[k];
        for (int msk = 32; msk > 0; msk >>= 1) t += __shfl_xor(t, msk, 64);
        if (lane == 0) ALPHAd[q] = t / fmaxf(ns * nd, COS_EPS);
    }
}

// per-head LayerNorm in place on bf16; one wave per head, one row per block
__global__ void ln_kernel_bf(short* __restrict__ XL, const float* __restrict__ g,
                             const float* __restrict__ b, int H, int C) {
    int n = blockIdx.x;
    int h = threadIdx.x >> 6;
    int lane = threadIdx.x & 63;
    size_t idx = (size_t)n * H * C + (size_t)h * C + lane;
    float v = (lane < C) ? bf2f(XL[idx]) : 0.f;
    float s = v;
    for (int msk = 32; msk > 0; msk >>= 1) s += __shfl_xor(s, msk, 64);
    float mu_ = s / (float)C;
    float d = (lane < C) ? (v - mu_) : 0.f;
    float s2 = d * d;
    for (int msk = 32; msk > 0; msk >>= 1) s2 += __shfl_xor(s2, msk, 64);
    float var = s2 / (float)C;
    if (lane < C) {
        float y = (v - mu_) * rsqrtf(var + LN_EPS) * g[lane] + b[lane];
        XL[idx] = (short)f2bf(y);
    }
}

// layers 0/1: one wave per dst node, Co=256 (4 bf16/lane).
// out = ELU(scatter + XB + bb) -> bf16   (XB now bf16)
__global__ void scatter_elu_v2(const short* __restrict__ XLN, const float* __restrict__ ALPHAd,
                               const int* __restrict__ rp_dst, const int* __restrict__ SRCd,
                               const float* __restrict__ NRM,
                               const short* __restrict__ XB, const float* __restrict__ bb,
                               short* __restrict__ Yb, int N) {
    int n = (blockIdx.x * blockDim.x + threadIdx.x) >> 6;
    int lane = threadIdx.x & 63;
    if (n >= N) return;
    int j0 = rp_dst[n], j1 = rp_dst[n + 1];
    float acc[4] = {0.f, 0.f, 0.f, 0.f};
    int j = j0;
    for (; j + 4 <= j1; j += 4) {
        int s0 = SRCd[j], s1 = SRCd[j + 1], s2 = SRCd[j + 2], s3 = SRCd[j + 3];
        float a0 = ALPHAd[j], a1 = ALPHAd[j + 1], a2 = ALPHAd[j + 2], a3 = ALPHAd[j + 3];
        float r0[4], r1[4], r2[4], r3[4];
        loadrow<4>(XLN + (size_t)s0 * 256 + lane * 4, r0);
        loadrow<4>(XLN + (size_t)s1 * 256 + lane * 4, r1);
        loadrow<4>(XLN + (size_t)s2 * 256 + lane * 4, r2);
        loadrow<4>(XLN + (size_t)s3 * 256 + lane * 4, r3);
#pragma unroll
        for (int k = 0; k < 4; ++k)
            acc[k] += (r0[k] * a0 + r1[k] * a1) + (r2[k] * a2 + r3[k] * a3);
    }
    for (; j < j1; ++j) {
        int s = SRCd[j];
        float a = ALPHAd[j];
        float r[4];
        loadrow<4>(XLN + (size_t)s * 256 + lane * 4, r);
#pragma unroll
        for (int k = 0; k < 4; ++k) acc[k] += r[k] * a;
    }
    float nn = NRM[n], n2 = nn * nn;
    float aself = n2 / fmaxf(n2, COS_EPS);
    float rs[4];
    loadrow<4>(XLN + (size_t)n * 256 + lane * 4, rs);
#pragma unroll
    for (int k = 0; k < 4; ++k) acc[k] += rs[k] * aself;

    float xb[4], o[4];
    loadrow<4>(XB + (size_t)n * 256 + lane * 4, xb);
    float4 bv = *reinterpret_cast<const float4*>(bb + lane * 4);
    o[0] = acc[0] + xb[0] + bv.x; o[1] = acc[1] + xb[1] + bv.y;
    o[2] = acc[2] + xb[2] + bv.z; o[3] = acc[3] + xb[3] + bv.w;
#pragma unroll
    for (int k = 0; k < 4; ++k) o[k] = (o[k] > 0.f) ? o[k] : expm1f(o[k]);
    storerow<4>(Yb + (size_t)n * 256 + lane * 4, o);
}

// layer 2: Co=40, one wave per dst node, raw scatter -> f32
__global__ void scatter_final(const short* __restrict__ XLN, const float* __restrict__ ALPHAd,
                              const int* __restrict__ rp_dst, const int* __restrict__ SRCd,
                              const float* __restrict__ NRM, float* __restrict__ Yf, int N) {
    int n = (blockIdx.x * blockDim.x + threadIdx.x) >> 6;
    int lane = threadIdx.x & 63;
    if (n >= N) return;
    bool act = lane < 40;
    int j0 = rp_dst[n], j1 = rp_dst[n + 1];
    float acc = 0.f;
    int j = j0;
    for (; j + 4 <= j1; j += 4) {
        int s0 = SRCd[j], s1 = SRCd[j + 1], s2 = SRCd[j + 2], s3 = SRCd[j + 3];
        float a0 = ALPHAd[j], a1 = ALPHAd[j + 1], a2 = ALPHAd[j + 2], a3 = ALPHAd[j + 3];
        float r0 = act ? bf2f(XLN[(size_t)s0 * 40 + lane]) : 0.f;
        float r1 = act ? bf2f(XLN[(size_t)s1 * 40 + lane]) : 0.f;
        float r2 = act ? bf2f(XLN[(size_t)s2 * 40 + lane]) : 0.f;
        float r3 = act ? bf2f(XLN[(size_t)s3 * 40 + lane]) : 0.f;
        acc += (r0 * a0 + r1 * a1) + (r2 * a2 + r3 * a3);
    }
    for (; j < j1; ++j) {
        int s = SRCd[j];
        float a = ALPHAd[j];
        float r = act ? bf2f(XLN[(size_t)s * 40 + lane]) : 0.f;
        acc += r * a;
    }
    float nn = NRM[n], n2 = nn * nn;
    float aself = n2 / fmaxf(n2, COS_EPS);
    if (act) {
        acc += bf2f(XLN[(size_t)n * 40 + lane]) * aself;
        Yf[(size_t)n * 40 + lane] = acc;
    }
}

// row-wise log_softmax; one wave per row
__global__ void logsoftmax_kernel(const float* __restrict__ S, float* __restrict__ OUT,
                                  int N, int C) {
    int wid = (blockIdx.x * blockDim.x + threadIdx.x) >> 6;
    int lane = threadIdx.x & 63;
    if (wid >= N) return;
    float v = (lane < C) ? S[(size_t)wid * C + lane] : -INFINITY;
    float mx = v;
    for (int msk = 32; msk > 0; msk >>= 1) mx = fmaxf(mx, __shfl_xor(mx, msk, 64));
    float ex = (lane < C) ? expf(v - mx) : 0.f;
    float se = ex;
    for (int msk = 32; msk > 0; msk >>= 1) se += __shfl_xor(se, msk, 64);
    if (lane < C) OUT[(size_t)wid * C + lane] = v - mx - logf(se);
}

extern "C" void kernel_launch(void* const* d_in, const int* in_sizes, int n_in,
                              void* d_out, int out_size, void* d_ws, size_t ws_size,
                              hipStream_t stream) {
    const float* x   = (const float*)d_in[0];
    const int*   ei  = (const int*)d_in[1];
    const float* W0  = (const float*)d_in[2];
    const float* g0  = (const float*)d_in[3];
    const float* b0  = (const float*)d_in[4];
    const float* B0  = (const float*)d_in[5];
    const float* bb0 = (const float*)d_in[6];
    const float* W1  = (const float*)d_in[7];
    const float* g1  = (const float*)d_in[8];
    const float* b1  = (const float*)d_in[9];
    const float* B1  = (const float*)d_in[10];
    const float* bb1 = (const float*)d_in[11];
    const float* W2  = (const float*)d_in[12];
    const float* g2  = (const float*)d_in[13];
    const float* b2  = (const float*)d_in[14];
    // d_in[15]/d_in[16] (B2 256x1, bb2): per-row constant shift, dead under log_softmax.
    float* out = (float*)d_out;

    const int N = in_sizes[0] / 128;
    const int E = in_sizes[1] / 2;
    const int* src = ei;
    const int* dst = ei + E;

    char* ws = (char*)d_ws;
    size_t off = 0;
    auto alloc = [&](size_t bytes) -> void* {
        void* p = ws + off;
        off += (bytes + 255) & ~(size_t)255;
        return p;
    };
    int* deg_src     = (int*)alloc((size_t)N * 4);
    int* deg_dst     = (int*)alloc((size_t)N * 4);
    int* rp_src      = (int*)alloc((size_t)(N + 1) * 4);
    int* rp_dst      = (int*)alloc((size_t)(N + 1) * 4);
    int* cur_src     = (int*)alloc((size_t)N * 4);
    int* cur_dst     = (int*)alloc((size_t)N * 4);
    int* bs_src      = (int*)alloc((size_t)1024 * 4);
    int* bs_dst      = (int*)alloc((size_t)1024 * 4);
    int* csr_src_dst = (int*)alloc((size_t)E * 4);
    int* qslot       = (int*)alloc((size_t)E * 4);
    int* SRCd        = (int*)alloc((size_t)E * 4);
    float* ALPHAd    = (float*)alloc((size_t)E * 4);
    float* NRM       = (float*)alloc((size_t)N * 4);
    short* XBb       = (short*)alloc((size_t)N * 256 * 2);   // bias-path GEMM output (bf16)
    short* MUb       = (short*)alloc((size_t)N * 256 * 2);   // bf16 neighborhood means
    short* XLb       = (short*)alloc((size_t)N * 256 * 2);
    short* Xb_a      = (short*)alloc((size_t)N * 256 * 2);
    short* Xb_b      = (short*)alloc((size_t)N * 256 * 2);
    float* SOUT      = (float*)alloc((size_t)N * 40 * 4);
    short* Wp        = (short*)alloc((size_t)8 * 32 * 64 * 8 * 2);
    (void)ws_size;

    // ---- CSR build (graph static across layers) ----
    hipMemsetAsync(deg_src, 0, (size_t)N * 4, stream);
    hipMemsetAsync(deg_dst, 0, (size_t)N * 4, stream);
    int egrid = (E + 255) / 256;
    count_deg<<<egrid, 256, 0, stream>>>(src, dst, deg_src, deg_dst, E);
    int nb = (N + 255) / 256;
    scan_phase1<<<2 * nb, 256, 0, stream>>>(deg_src, deg_dst, rp_src, rp_dst,
                                            bs_src, bs_dst, N, nb);
    scan_phase2<<<1, 256, 0, stream>>>(bs_src, bs_dst, nb, rp_src, rp_dst, N);
    scan_phase3<<<2 * nb, 256, 0, stream>>>(rp_src, rp_dst, bs_src, bs_dst,
                                            cur_src, cur_dst, N, nb);
    fill_csr<<<egrid, 256, 0, stream>>>(src, dst, cur_src, cur_dst,
                                        csr_src_dst, qslot, SRCd, E);

    // cast x -> bf16
    {
        int n4 = (N * 128) / 4;
        cast_bf16<<<(n4 + 255) / 256, 256, 0, stream>>>(x, Xb_a, n4);
    }

    int wgridN = (N * 64 + 255) / 256;  // one wave per node, 4 waves/block
    int ggrid  = (N + 127) / 128;       // 128 rows per GEMM block (8 waves)

    // ---------------- layer 0: Xb_a[N,128] -> Xb_b[N,256] ----------------
    mu_norm_v2<2><<<wgridN, 256, 0, stream>>>(Xb_a, rp_src, csr_src_dst, MUb, NRM, N);
    alpha_src_v2<2><<<wgridN, 256, 0, stream>>>(MUb, NRM, rp_src, csr_src_dst,
                                                qslot, ALPHAd, N);
    {
        int tot = 4 * 16 * 512;
        pack_w<<<(tot + 255) / 256, 256, 0, stream>>>(W0, Wp, 4, 32, 0, 16, 256);
        pack_w<<<(tot + 255) / 256, 256, 0, stream>>>(B0, Wp, 4, 32, 16, 16, 256);
    }
    mfma_gemm_v3<4, 32, 16><<<ggrid, 512, 0, stream>>>(Xb_a, Wp, XLb, XBb, N, 256);
    ln_kernel_bf<<<N, 256, 0, stream>>>(XLb, g0, b0, 4, 64);
    scatter_elu_v2<<<wgridN, 256, 0, stream>>>(XLb, ALPHAd, rp_dst, SRCd, NRM,
                                               XBb, bb0, Xb_b, N);

    // ---------------- layer 1: Xb_b[N,256] -> Xb_a[N,256] ----------------
    mu_norm_v2<4><<<wgridN, 256, 0, stream>>>(Xb_b, rp_src, csr_src_dst, MUb, NRM, N);
    alpha_src_v2<4><<<wgridN, 256, 0, stream>>>(MUb, NRM, rp_src, csr_src_dst,
                                                qslot, ALPHAd, N);
    {
        int tot = 8 * 16 * 512;
        pack_w<<<(tot + 255) / 256, 256, 0, stream>>>(W1, Wp, 8, 32, 0, 16, 256);
        pack_w<<<(tot + 255) / 256, 256, 0, stream>>>(B1, Wp, 8, 32, 16, 16, 256);
    }
    mfma_gemm_v3<8, 32, 16><<<ggrid, 512, 0, stream>>>(Xb_b, Wp, XLb, XBb, N, 256);
    ln_kernel_bf<<<N, 256, 0, stream>>>(XLb, g1, b1, 4, 64);
    scatter_elu_v2<<<wgridN, 256, 0, stream>>>(XLb, ALPHAd, rp_dst, SRCd, NRM,
                                               XBb, bb1, Xb_a, N);

    // ---------------- layer 2: Xb_a[N,256] -> SOUT[N,40] ----------------
    mu_norm_v2<4><<<wgridN, 256, 0, stream>>>(Xb_a, rp_src, csr_src_dst, MUb, NRM, N);
    alpha_src_v2<4><<<wgridN, 256, 0, stream>>>(MUb, NRM, rp_src, csr_src_dst,
                                                qslot, ALPHAd, N);
    {
        int tot = 8 * 3 * 512;
        pack_w<<<(tot + 255) / 256, 256, 0, stream>>>(W2, Wp, 8, 3, 0, 3, 40);
    }
    mfma_gemm_v3<8, 3, 3><<<ggrid, 512, 0, stream>>>(Xb_a, Wp, XLb, nullptr, N, 40);
    ln_kernel_bf<<<N, 64, 0, stream>>>(XLb, g2, b2, 1, 40);
    scatter_final<<<wgridN, 256, 0, stream>>>(XLb, ALPHAd, rp_dst, SRCd, NRM, SOUT, N);

    logsoftmax_kernel<<<wgridN, 256, 0, stream>>>(SOUT, out, N, 40);
}

// Round 8
// 764.885 us; speedup vs baseline: 3.5752x; 1.0600x over previous
//
#include <hip/hip_runtime.h>
#include <math.h>

#define LN_EPS 1e-5f
#define COS_EPS 1e-8f

typedef short bf16x8 __attribute__((ext_vector_type(8)));
typedef float f32x4 __attribute__((ext_vector_type(4)));

static __device__ __forceinline__ unsigned short f2bf(float f) {
    unsigned u = __float_as_uint(f);
    u = u + 0x7FFFu + ((u >> 16) & 1u);   // round-to-nearest-even
    return (unsigned short)(u >> 16);
}
static __device__ __forceinline__ float bf2f(short s) {
    return __uint_as_float(((unsigned)(unsigned short)s) << 16);
}

// load/store EPL bf16 elements per lane as one vector op
template<int EPL>
static __device__ __forceinline__ void loadrow(const short* __restrict__ p, float* r) {
    if constexpr (EPL == 4) {
        short4 v = *reinterpret_cast<const short4*>(p);
        r[0] = bf2f(v.x); r[1] = bf2f(v.y); r[2] = bf2f(v.z); r[3] = bf2f(v.w);
    } else {
        short2 v = *reinterpret_cast<const short2*>(p);
        r[0] = bf2f(v.x); r[1] = bf2f(v.y);
    }
}
template<int EPL>
static __device__ __forceinline__ void storerow(short* __restrict__ p, const float* m) {
    if constexpr (EPL == 4) {
        short4 v;
        v.x = (short)f2bf(m[0]); v.y = (short)f2bf(m[1]);
        v.z = (short)f2bf(m[2]); v.w = (short)f2bf(m[3]);
        *reinterpret_cast<short4*>(p) = v;
    } else {
        short2 v;
        v.x = (short)f2bf(m[0]); v.y = (short)f2bf(m[1]);
        *reinterpret_cast<short2*>(p) = v;
    }
}

// ---------------- CSR build ----------------
__global__ void count_deg(const int* __restrict__ src, const int* __restrict__ dst,
                          int* __restrict__ deg_src, int* __restrict__ deg_dst, int E) {
    int e = blockIdx.x * blockDim.x + threadIdx.x;
    if (e < E) {
        atomicAdd(&deg_src[src[e]], 1);
        atomicAdd(&deg_dst[dst[e]], 1);
    }
}

// hierarchical exclusive scan, both arrays fused per phase
__global__ void scan_phase1(const int* __restrict__ degA, const int* __restrict__ degB,
                            int* __restrict__ rpA, int* __restrict__ rpB,
                            int* __restrict__ bsA, int* __restrict__ bsB, int n, int nb) {
    __shared__ int sdata[256];
    int bid = blockIdx.x;
    const int* deg; int* rp; int* bs; int seg;
    if (bid < nb) { deg = degA; rp = rpA; bs = bsA; seg = bid; }
    else          { deg = degB; rp = rpB; bs = bsB; seg = bid - nb; }
    int i = seg * 256 + threadIdx.x;
    int v = (i < n) ? deg[i] : 0;
    sdata[threadIdx.x] = v;
    __syncthreads();
    for (int off = 1; off < 256; off <<= 1) {
        int t = (threadIdx.x >= off) ? sdata[threadIdx.x - off] : 0;
        __syncthreads();
        sdata[threadIdx.x] += t;
        __syncthreads();
    }
    if (i < n) rp[i] = sdata[threadIdx.x] - v;   // exclusive within block
    if (threadIdx.x == 255) bs[seg] = sdata[255];
}

__global__ void scan_phase2(int* __restrict__ bsA, int* __restrict__ bsB, int nb,
                            int* __restrict__ rpA, int* __restrict__ rpB, int n) {
    __shared__ int sdata[256];
    __shared__ int s_carry;
    for (int arr = 0; arr < 2; ++arr) {
        int* bs = arr ? bsB : bsA;
        int* rp = arr ? rpB : rpA;
        if (threadIdx.x == 0) s_carry = 0;
        __syncthreads();
        for (int base = 0; base < nb; base += 256) {
            int i = base + threadIdx.x;
            int v = (i < nb) ? bs[i] : 0;
            sdata[threadIdx.x] = v;
            __syncthreads();
            for (int off = 1; off < 256; off <<= 1) {
                int t = (threadIdx.x >= off) ? sdata[threadIdx.x - off] : 0;
                __syncthreads();
                sdata[threadIdx.x] += t;
                __syncthreads();
            }
            if (i < nb) bs[i] = s_carry + sdata[threadIdx.x] - v;
            __syncthreads();
            if (threadIdx.x == 255) s_carry += sdata[255];
            __syncthreads();
        }
        if (threadIdx.x == 0) rp[n] = s_carry;
        __syncthreads();
    }
}

__global__ void scan_phase3(int* __restrict__ rpA, int* __restrict__ rpB,
                            const int* __restrict__ bsA, const int* __restrict__ bsB,
                            int* __restrict__ curA, int* __restrict__ curB, int n, int nb) {
    int bid = blockIdx.x;
    if (bid < nb) {
        int i = bid * 256 + threadIdx.x;
        if (i < n) { int v = rpA[i] + bsA[bid]; rpA[i] = v; curA[i] = v; }
    } else {
        int seg = bid - nb;
        int i = seg * 256 + threadIdx.x;
        if (i < n) { int v = rpB[i] + bsB[seg]; rpB[i] = v; curB[i] = v; }
    }
}

// src-CSR: CSRS[p] = (dst | q<<32), packed 8B non-temporal write.
// dst-CSR: SRCd[q] = src, non-temporal. (random scatters; nt avoids L2
// line writeback amplification — round-7 profile: 88MB written for 6MB logical)
__global__ void fill_csr(const int* __restrict__ src, const int* __restrict__ dst,
                         int* __restrict__ cur_src, int* __restrict__ cur_dst,
                         long long* __restrict__ CSRS, int* __restrict__ SRCd, int E) {
    int e = blockIdx.x * blockDim.x + threadIdx.x;
    if (e < E) {
        int s = src[e], d = dst[e];
        int p = atomicAdd(&cur_src[s], 1);
        int q = atomicAdd(&cur_dst[d], 1);
        long long packed = (((long long)q) << 32) | (unsigned)d;
        __builtin_nontemporal_store(packed, CSRS + p);
        __builtin_nontemporal_store(s, SRCd + q);
    }
}

// ---------------- casts / packing ----------------
__global__ void cast_bf16(const float* __restrict__ X, short* __restrict__ Y, int n4) {
    int i = blockIdx.x * blockDim.x + threadIdx.x;
    if (i >= n4) return;
    float4 v = reinterpret_cast<const float4*>(X)[i];
    short4 o;
    o.x = (short)f2bf(v.x); o.y = (short)f2bf(v.y);
    o.z = (short)f2bf(v.z); o.w = (short)f2bf(v.w);
    reinterpret_cast<short4*>(Y)[i] = o;
}

// Pack W (K x ncols f32, row-major) into per-lane MFMA B-fragment layout
__global__ void pack_w(const float* __restrict__ W, short* __restrict__ Wp,
                       int KT, int NCT_total, int ct_base, int nct_local, int ncols) {
    int idx = blockIdx.x * blockDim.x + threadIdx.x;
    int total = KT * nct_local * 512;
    if (idx >= total) return;
    int j = idx & 7;
    int l = (idx >> 3) & 63;
    int t = idx >> 9;
    int ctl = t % nct_local;
    int kt = t / nct_local;
    int k = kt * 32 + (l >> 4) * 8 + j;
    int col = ctl * 16 + (l & 15);
    float v = (col < ncols) ? W[(size_t)k * ncols + col] : 0.f;
    Wp[(((size_t)kt * NCT_total + ct_base + ctl) * 64 + l) * 8 + j] = (short)f2bf(v);
}

// ---------------- MFMA GEMM v4: 8 waves/block, B staged via LDS, fused LN ----------------
// LNF=true (layers 0/1): per-head LayerNorm (H=NCT_A/4 heads of 64 cols) applied
// to the f32 accumulators via 4-step shfl_xor reduce within 16-lane col groups.
template<int KT, int NCT, int NCT_A, bool LNF>
__global__ __launch_bounds__(512) void mfma_gemm_v4(const short* __restrict__ Xb,
                                                    const short* __restrict__ Wp,
                                                    short* __restrict__ XL,
                                                    short* __restrict__ XBb,
                                                    const float* __restrict__ g,
                                                    const float* __restrict__ b,
                                                    int M, int CoA) {
    __shared__ short bsm[NCT * 512];
    const int K = KT * 32;
    int lane = threadIdx.x & 63;
    int wave = threadIdx.x >> 6;
    size_t row0 = ((size_t)blockIdx.x * 8 + wave) * 16;
    bool active = row0 < (size_t)M;
    const short* arow = Xb + (row0 + (lane & 15)) * K + (lane >> 4) * 8;

    f32x4 acc[NCT];
#pragma unroll
    for (int ct = 0; ct < NCT; ++ct) {
        f32x4 z = {0.f, 0.f, 0.f, 0.f};
        acc[ct] = z;
    }

#pragma unroll 1
    for (int kt = 0; kt < KT; ++kt) {
        __syncthreads();   // previous kt's LDS reads complete
        const int4* wsrc = reinterpret_cast<const int4*>(Wp + (size_t)kt * NCT * 512);
        int4* wdst = reinterpret_cast<int4*>(bsm);
        for (int i = threadIdx.x; i < NCT * 64; i += 512) wdst[i] = wsrc[i];
        __syncthreads();
        if (active) {
            bf16x8 a = *reinterpret_cast<const bf16x8*>(arow + kt * 32);
#pragma unroll
            for (int ct = 0; ct < NCT; ++ct) {
                bf16x8 bv = *reinterpret_cast<const bf16x8*>(bsm + ct * 512 + lane * 8);
                acc[ct] = __builtin_amdgcn_mfma_f32_16x16x32_bf16(a, bv, acc[ct], 0, 0, 0);
            }
        }
    }
    if (!active) return;

    int c0 = lane & 15;
    int r0 = (lane >> 4) * 4;
    if constexpr (LNF) {
        float gg[4], bv[4];
#pragma unroll
        for (int m = 0; m < 4; ++m) {
            gg[m] = g[m * 16 + c0];
            bv[m] = b[m * 16 + c0];
        }
#pragma unroll
        for (int h = 0; h < NCT_A / 4; ++h) {
#pragma unroll
            for (int j = 0; j < 4; ++j) {
                float s = acc[4*h+0][j] + acc[4*h+1][j] + acc[4*h+2][j] + acc[4*h+3][j];
                s += __shfl_xor(s, 1, 64); s += __shfl_xor(s, 2, 64);
                s += __shfl_xor(s, 4, 64); s += __shfl_xor(s, 8, 64);
                float mu_ = s * 0.015625f;                 // /64
                float d0 = acc[4*h+0][j] - mu_, d1 = acc[4*h+1][j] - mu_;
                float d2 = acc[4*h+2][j] - mu_, d3 = acc[4*h+3][j] - mu_;
                float s2 = d0*d0 + d1*d1 + d2*d2 + d3*d3;
                s2 += __shfl_xor(s2, 1, 64); s2 += __shfl_xor(s2, 2, 64);
                s2 += __shfl_xor(s2, 4, 64); s2 += __shfl_xor(s2, 8, 64);
                float rs = rsqrtf(s2 * 0.015625f + LN_EPS);
                size_t row = row0 + r0 + j;
                short* rowp = XL + row * 256 + c0;
                rowp[(4*h+0)*16] = (short)f2bf(d0 * rs * gg[0] + bv[0]);
                rowp[(4*h+1)*16] = (short)f2bf(d1 * rs * gg[1] + bv[1]);
                rowp[(4*h+2)*16] = (short)f2bf(d2 * rs * gg[2] + bv[2]);
                rowp[(4*h+3)*16] = (short)f2bf(d3 * rs * gg[3] + bv[3]);
            }
        }
#pragma unroll
        for (int ct = NCT_A; ct < NCT; ++ct) {
#pragma unroll
            for (int j = 0; j < 4; ++j) {
                size_t row = row0 + r0 + j;
                XBb[row * 256 + (ct - NCT_A) * 16 + c0] = (short)f2bf(acc[ct][j]);
            }
        }
    } else {
#pragma unroll
        for (int ct = 0; ct < NCT; ++ct) {
            int col = ct * 16 + c0;
#pragma unroll
            for (int j = 0; j < 4; ++j) {
                size_t row = row0 + r0 + j;
                if (ct < NCT_A) {
                    if (col < CoA) XL[row * CoA + col] = (short)f2bf(acc[ct][j]);
                } else {
                    XBb[row * 256 + (col - NCT_A * 16)] = (short)f2bf(acc[ct][j]);
                }
            }
        }
    }
}

// ---------------- gather kernels: one WAVE per node, 8 rows in flight ----------------

// mu + normalize: MUn[n] = mu[n]/max(||mu[n]||, 1e-8) in bf16; NRM[n] = ||mu[n]||.
template<int EPL>
__global__ void mu_norm_v3(const short* __restrict__ Xb, const int* __restrict__ rp,
                           const long long* __restrict__ CSRS, short* __restrict__ MUn,
                           float* __restrict__ NRM, int N) {
    int n = (blockIdx.x * blockDim.x + threadIdx.x) >> 6;
    int lane = threadIdx.x & 63;
    if (n >= N) return;
    const int Fin = EPL * 64;
    int j0 = rp[n], j1 = rp[n + 1];
    float acc[EPL];
#pragma unroll
    for (int k = 0; k < EPL; ++k) acc[k] = 0.f;
    int j = j0;
    for (; j + 8 <= j1; j += 8) {
        int dd[8];
#pragma unroll
        for (int u = 0; u < 8; ++u) dd[u] = (int)CSRS[j + u];
        float r[8][EPL];
#pragma unroll
        for (int u = 0; u < 8; ++u)
            loadrow<EPL>(Xb + (size_t)dd[u] * Fin + lane * EPL, r[u]);
#pragma unroll
        for (int u = 0; u < 8; ++u)
#pragma unroll
            for (int k = 0; k < EPL; ++k) acc[k] += r[u][k];
    }
    for (; j < j1; ++j) {
        int d = (int)CSRS[j];
        float r[EPL];
        loadrow<EPL>(Xb + (size_t)d * Fin + lane * EPL, r);
#pragma unroll
        for (int k = 0; k < EPL; ++k) acc[k] += r[k];
    }
    float inv = 1.f / fmaxf((float)(j1 - j0), 1.f);
    float m[EPL];
    float s = 0.f;
#pragma unroll
    for (int k = 0; k < EPL; ++k) { m[k] = acc[k] * inv; s += m[k] * m[k]; }
    for (int msk = 32; msk > 0; msk >>= 1) s += __shfl_xor(s, msk, 64);
    float nrm = sqrtf(s);
    float innv = 1.f / fmaxf(nrm, 1e-8f);
#pragma unroll
    for (int k = 0; k < EPL; ++k) m[k] *= innv;
    storerow<EPL>(MUn + (size_t)n * Fin + lane * EPL, m);
    if (lane == 0) NRM[n] = nrm;
}

// alpha = dot(MUn[src], MUn[dst]) — normalized rows, no NRM gathers, no divide.
// Iterated by src (row in regs); writes ALPHAd[q] non-temporal (random scatter).
template<int EPL>
__global__ void alpha_v3(const short* __restrict__ MUn, const long long* __restrict__ CSRS,
                         const int* __restrict__ rp_src, float* __restrict__ ALPHAd, int N) {
    int sn = (blockIdx.x * blockDim.x + threadIdx.x) >> 6;
    int lane = threadIdx.x & 63;
    if (sn >= N) return;
    const int Fin = EPL * 64;
    float a[EPL];
    loadrow<EPL>(MUn + (size_t)sn * Fin + lane * EPL, a);
    int j0 = rp_src[sn], j1 = rp_src[sn + 1];
    int j = j0;
    for (; j + 8 <= j1; j += 8) {
        int dd[8], qq[8];
#pragma unroll
        for (int u = 0; u < 8; ++u) {
            long long c = CSRS[j + u];
            dd[u] = (int)c;
            qq[u] = (int)(c >> 32);
        }
        float cr[8][EPL];
#pragma unroll
        for (int u = 0; u < 8; ++u)
            loadrow<EPL>(MUn + (size_t)dd[u] * Fin + lane * EPL, cr[u]);
        float t[8];
#pragma unroll
        for (int u = 0; u < 8; ++u) {
            float tt = 0.f;
#pragma unroll
            for (int k = 0; k < EPL; ++k) tt += a[k] * cr[u][k];
            t[u] = tt;
        }
#pragma unroll
        for (int u = 0; u < 8; ++u)
            for (int msk = 32; msk > 0; msk >>= 1) t[u] += __shfl_xor(t[u], msk, 64);
        if (lane == 0) {
#pragma unroll
            for (int u = 0; u < 8; ++u)
                __builtin_nontemporal_store(t[u], ALPHAd + qq[u]);
        }
    }
    for (; j < j1; ++j) {
        long long c = CSRS[j];
        int d = (int)c, q = (int)(c >> 32);
        float cr[EPL];
        loadrow<EPL>(MUn + (size_t)d * Fin + lane * EPL, cr);
        float t = 0.f;
#pragma unroll
        for (int k = 0; k < EPL; ++k) t += a[k] * cr[k];
        for (int msk = 32; msk > 0; msk >>= 1) t += __shfl_xor(t, msk, 64);
        if (lane == 0) __builtin_nontemporal_store(t, ALPHAd + q);
    }
}

// per-head LayerNorm in place on bf16 (layer 2 only: H=1, C=40)
__global__ void ln_kernel_bf(short* __restrict__ XL, const float* __restrict__ g,
                             const float* __restrict__ b, int H, int C) {
    int n = blockIdx.x;
    int h = threadIdx.x >> 6;
    int lane = threadIdx.x & 63;
    size_t idx = (size_t)n * H * C + (size_t)h * C + lane;
    float v = (lane < C) ? bf2f(XL[idx]) : 0.f;
    float s = v;
    for (int msk = 32; msk > 0; msk >>= 1) s += __shfl_xor(s, msk, 64);
    float mu_ = s / (float)C;
    float d = (lane < C) ? (v - mu_) : 0.f;
    float s2 = d * d;
    for (int msk = 32; msk > 0; msk >>= 1) s2 += __shfl_xor(s2, msk, 64);
    float var = s2 / (float)C;
    if (lane < C) {
        float y = (v - mu_) * rsqrtf(var + LN_EPS) * g[lane] + b[lane];
        XL[idx] = (short)f2bf(y);
    }
}

// layers 0/1: one wave per dst node, Co=256 (4 bf16/lane), 8 rows in flight.
// out = ELU(scatter + XB + bb) -> bf16
__global__ void scatter_elu_v3(const short* __restrict__ XLN, const float* __restrict__ ALPHAd,
                               const int* __restrict__ rp_dst, const int* __restrict__ SRCd,
                               const float* __restrict__ NRM,
                               const short* __restrict__ XB, const float* __restrict__ bb,
                               short* __restrict__ Yb, int N) {
    int n = (blockIdx.x * blockDim.x + threadIdx.x) >> 6;
    int lane = threadIdx.x & 63;
    if (n >= N) return;
    int j0 = rp_dst[n], j1 = rp_dst[n + 1];
    float acc[4] = {0.f, 0.f, 0.f, 0.f};
    int j = j0;
    for (; j + 8 <= j1; j += 8) {
        int ss[8];
        float aa[8];
#pragma unroll
        for (int u = 0; u < 8; ++u) { ss[u] = SRCd[j + u]; aa[u] = ALPHAd[j + u]; }
        float r[8][4];
#pragma unroll
        for (int u = 0; u < 8; ++u)
            loadrow<4>(XLN + (size_t)ss[u] * 256 + lane * 4, r[u]);
#pragma unroll
        for (int u = 0; u < 8; ++u)
#pragma unroll
            for (int k = 0; k < 4; ++k) acc[k] += r[u][k] * aa[u];
    }
    for (; j < j1; ++j) {
        int s = SRCd[j];
        float a = ALPHAd[j];
        float r[4];
        loadrow<4>(XLN + (size_t)s * 256 + lane * 4, r);
#pragma unroll
        for (int k = 0; k < 4; ++k) acc[k] += r[k] * a;
    }
    float nn = NRM[n], n2 = nn * nn;
    float aself = n2 / fmaxf(n2, COS_EPS);
    float rs[4];
    loadrow<4>(XLN + (size_t)n * 256 + lane * 4, rs);
#pragma unroll
    for (int k = 0; k < 4; ++k) acc[k] += rs[k] * aself;

    float xb[4], o[4];
    loadrow<4>(XB + (size_t)n * 256 + lane * 4, xb);
    float4 bv = *reinterpret_cast<const float4*>(bb + lane * 4);
    o[0] = acc[0] + xb[0] + bv.x; o[1] = acc[1] + xb[1] + bv.y;
    o[2] = acc[2] + xb[2] + bv.z; o[3] = acc[3] + xb[3] + bv.w;
#pragma unroll
    for (int k = 0; k < 4; ++k) o[k] = (o[k] > 0.f) ? o[k] : expm1f(o[k]);
    storerow<4>(Yb + (size_t)n * 256 + lane * 4, o);
}

// layer 2: Co=40, one wave per dst node, fused log_softmax -> OUT (f32)
__global__ void scatter_final_ls(const short* __restrict__ XLN, const float* __restrict__ ALPHAd,
                                 const int* __restrict__ rp_dst, const int* __restrict__ SRCd,
                                 const float* __restrict__ NRM, float* __restrict__ OUT, int N) {
    int n = (blockIdx.x * blockDim.x + threadIdx.x) >> 6;
    int lane = threadIdx.x & 63;
    if (n >= N) return;
    bool act = lane < 40;
    int j0 = rp_dst[n], j1 = rp_dst[n + 1];
    float acc = 0.f;
    int j = j0;
    for (; j + 8 <= j1; j += 8) {
        int ss[8];
        float aa[8];
#pragma unroll
        for (int u = 0; u < 8; ++u) { ss[u] = SRCd[j + u]; aa[u] = ALPHAd[j + u]; }
        float r[8];
#pragma unroll
        for (int u = 0; u < 8; ++u)
            r[u] = act ? bf2f(XLN[(size_t)ss[u] * 40 + lane]) : 0.f;
#pragma unroll
        for (int u = 0; u < 8; ++u) acc += r[u] * aa[u];
    }
    for (; j < j1; ++j) {
        int s = SRCd[j];
        float a = ALPHAd[j];
        float r = act ? bf2f(XLN[(size_t)s * 40 + lane]) : 0.f;
        acc += r * a;
    }
    float nn = NRM[n], n2 = nn * nn;
    float aself = n2 / fmaxf(n2, COS_EPS);
    acc += (act ? bf2f(XLN[(size_t)n * 40 + lane]) : 0.f) * aself;

    float v = act ? acc : -INFINITY;
    float mx = v;
    for (int msk = 32; msk > 0; msk >>= 1) mx = fmaxf(mx, __shfl_xor(mx, msk, 64));
    float ex = act ? expf(v - mx) : 0.f;
    float se = ex;
    for (int msk = 32; msk > 0; msk >>= 1) se += __shfl_xor(se, msk, 64);
    if (act) OUT[(size_t)n * 40 + lane] = v - mx - logf(se);
}

extern "C" void kernel_launch(void* const* d_in, const int* in_sizes, int n_in,
                              void* d_out, int out_size, void* d_ws, size_t ws_size,
                              hipStream_t stream) {
    const float* x   = (const float*)d_in[0];
    const int*   ei  = (const int*)d_in[1];
    const float* W0  = (const float*)d_in[2];
    const float* g0  = (const float*)d_in[3];
    const float* b0  = (const float*)d_in[4];
    const float* B0  = (const float*)d_in[5];
    const float* bb0 = (const float*)d_in[6];
    const float* W1  = (const float*)d_in[7];
    const float* g1  = (const float*)d_in[8];
    const float* b1  = (const float*)d_in[9];
    const float* B1  = (const float*)d_in[10];
    const float* bb1 = (const float*)d_in[11];
    const float* W2  = (const float*)d_in[12];
    const float* g2  = (const float*)d_in[13];
    const float* b2  = (const float*)d_in[14];
    // d_in[15]/d_in[16] (B2 256x1, bb2): per-row constant shift, dead under log_softmax.
    float* out = (float*)d_out;

    const int N = in_sizes[0] / 128;
    const int E = in_sizes[1] / 2;
    const int* src = ei;
    const int* dst = ei + E;

    char* ws = (char*)d_ws;
    size_t off = 0;
    auto alloc = [&](size_t bytes) -> void* {
        void* p = ws + off;
        off += (bytes + 255) & ~(size_t)255;
        return p;
    };
    int* deg_src     = (int*)alloc((size_t)N * 4);
    int* deg_dst     = (int*)alloc((size_t)N * 4);
    int* rp_src      = (int*)alloc((size_t)(N + 1) * 4);
    int* rp_dst      = (int*)alloc((size_t)(N + 1) * 4);
    int* cur_src     = (int*)alloc((size_t)N * 4);
    int* cur_dst     = (int*)alloc((size_t)N * 4);
    int* bs_src      = (int*)alloc((size_t)1024 * 4);
    int* bs_dst      = (int*)alloc((size_t)1024 * 4);
    long long* CSRS  = (long long*)alloc((size_t)E * 8);
    int* SRCd        = (int*)alloc((size_t)E * 4);
    float* ALPHAd    = (float*)alloc((size_t)E * 4);
    float* NRM       = (float*)alloc((size_t)N * 4);
    short* XBb       = (short*)alloc((size_t)N * 256 * 2);   // bias-path GEMM output (bf16)
    short* MUn       = (short*)alloc((size_t)N * 256 * 2);   // normalized neighborhood means
    short* XLb       = (short*)alloc((size_t)N * 256 * 2);
    short* Xb_a      = (short*)alloc((size_t)N * 256 * 2);
    short* Xb_b      = (short*)alloc((size_t)N * 256 * 2);
    short* Wp        = (short*)alloc((size_t)8 * 32 * 64 * 8 * 2);
    (void)ws_size;

    // ---- CSR build (graph static across layers) ----
    hipMemsetAsync(deg_src, 0, (size_t)N * 4, stream);
    hipMemsetAsync(deg_dst, 0, (size_t)N * 4, stream);
    int egrid = (E + 255) / 256;
    count_deg<<<egrid, 256, 0, stream>>>(src, dst, deg_src, deg_dst, E);
    int nb = (N + 255) / 256;
    scan_phase1<<<2 * nb, 256, 0, stream>>>(deg_src, deg_dst, rp_src, rp_dst,
                                            bs_src, bs_dst, N, nb);
    scan_phase2<<<1, 256, 0, stream>>>(bs_src, bs_dst, nb, rp_src, rp_dst, N);
    scan_phase3<<<2 * nb, 256, 0, stream>>>(rp_src, rp_dst, bs_src, bs_dst,
                                            cur_src, cur_dst, N, nb);
    fill_csr<<<egrid, 256, 0, stream>>>(src, dst, cur_src, cur_dst, CSRS, SRCd, E);

    // cast x -> bf16
    {
        int n4 = (N * 128) / 4;
        cast_bf16<<<(n4 + 255) / 256, 256, 0, stream>>>(x, Xb_a, n4);
    }

    int wgridN = (N * 64 + 255) / 256;  // one wave per node, 4 waves/block
    int ggrid  = (N + 127) / 128;       // 128 rows per GEMM block (8 waves)

    // ---------------- layer 0: Xb_a[N,128] -> Xb_b[N,256] ----------------
    mu_norm_v3<2><<<wgridN, 256, 0, stream>>>(Xb_a, rp_src, CSRS, MUn, NRM, N);
    alpha_v3<2><<<wgridN, 256, 0, stream>>>(MUn, CSRS, rp_src, ALPHAd, N);
    {
        int tot = 4 * 16 * 512;
        pack_w<<<(tot + 255) / 256, 256, 0, stream>>>(W0, Wp, 4, 32, 0, 16, 256);
        pack_w<<<(tot + 255) / 256, 256, 0, stream>>>(B0, Wp, 4, 32, 16, 16, 256);
    }
    mfma_gemm_v4<4, 32, 16, true><<<ggrid, 512, 0, stream>>>(Xb_a, Wp, XLb, XBb,
                                                             g0, b0, N, 256);
    scatter_elu_v3<<<wgridN, 256, 0, stream>>>(XLb, ALPHAd, rp_dst, SRCd, NRM,
                                               XBb, bb0, Xb_b, N);

    // ---------------- layer 1: Xb_b[N,256] -> Xb_a[N,256] ----------------
    mu_norm_v3<4><<<wgridN, 256, 0, stream>>>(Xb_b, rp_src, CSRS, MUn, NRM, N);
    alpha_v3<4><<<wgridN, 256, 0, stream>>>(MUn, CSRS, rp_src, ALPHAd, N);
    {
        int tot = 8 * 16 * 512;
        pack_w<<<(tot + 255) / 256, 256, 0, stream>>>(W1, Wp, 8, 32, 0, 16, 256);
        pack_w<<<(tot + 255) / 256, 256, 0, stream>>>(B1, Wp, 8, 32, 16, 16, 256);
    }
    mfma_gemm_v4<8, 32, 16, true><<<ggrid, 512, 0, stream>>>(Xb_b, Wp, XLb, XBb,
                                                             g1, b1, N, 256);
    scatter_elu_v3<<<wgridN, 256, 0, stream>>>(XLb, ALPHAd, rp_dst, SRCd, NRM,
                                               XBb, bb1, Xb_a, N);

    // ---------------- layer 2: Xb_a[N,256] -> out (fused log_softmax) ----------------
    mu_norm_v3<4><<<wgridN, 256, 0, stream>>>(Xb_a, rp_src, CSRS, MUn, NRM, N);
    alpha_v3<4><<<wgridN, 256, 0, stream>>>(MUn, CSRS, rp_src, ALPHAd, N);
    {
        int tot = 8 * 3 * 512;
        pack_w<<<(tot + 255) / 256, 256, 0, stream>>>(W2, Wp, 8, 3, 0, 3, 40);
    }
    mfma_gemm_v4<8, 3, 3, false><<<ggrid, 512, 0, stream>>>(Xb_a, Wp, XLb, nullptr,
                                                            nullptr, nullptr, N, 40);
    ln_kernel_bf<<<N, 64, 0, stream>>>(XLb, g2, b2, 1, 40);
    scatter_final_ls<<<wgridN, 256, 0, stream>>>(XLb, ALPHAd, rp_dst, SRCd, NRM, out, N);
}

// Round 9
// 681.731 us; speedup vs baseline: 4.0113x; 1.1220x over previous
//
#include <hip/hip_runtime.h>
#include <math.h>

#define LN_EPS 1e-5f
#define COS_EPS 1e-8f

typedef short bf16x8 __attribute__((ext_vector_type(8)));
typedef float f32x4 __attribute__((ext_vector_type(4)));

static __device__ __forceinline__ unsigned short f2bf(float f) {
    unsigned u = __float_as_uint(f);
    u = u + 0x7FFFu + ((u >> 16) & 1u);   // round-to-nearest-even
    return (unsigned short)(u >> 16);
}
static __device__ __forceinline__ float bf2f(short s) {
    return __uint_as_float(((unsigned)(unsigned short)s) << 16);
}

// load/store EPL bf16 elements per lane as one vector op
template<int EPL>
static __device__ __forceinline__ void loadrow(const short* __restrict__ p, float* r) {
    if constexpr (EPL == 4) {
        short4 v = *reinterpret_cast<const short4*>(p);
        r[0] = bf2f(v.x); r[1] = bf2f(v.y); r[2] = bf2f(v.z); r[3] = bf2f(v.w);
    } else {
        short2 v = *reinterpret_cast<const short2*>(p);
        r[0] = bf2f(v.x); r[1] = bf2f(v.y);
    }
}
template<int EPL>
static __device__ __forceinline__ void storerow(short* __restrict__ p, const float* m) {
    if constexpr (EPL == 4) {
        short4 v;
        v.x = (short)f2bf(m[0]); v.y = (short)f2bf(m[1]);
        v.z = (short)f2bf(m[2]); v.w = (short)f2bf(m[3]);
        *reinterpret_cast<short4*>(p) = v;
    } else {
        short2 v;
        v.x = (short)f2bf(m[0]); v.y = (short)f2bf(m[1]);
        *reinterpret_cast<short2*>(p) = v;
    }
}

// ---------------- CSR build ----------------
__global__ void count_deg(const int* __restrict__ src, const int* __restrict__ dst,
                          int* __restrict__ deg_src, int* __restrict__ deg_dst, int E) {
    int e = blockIdx.x * blockDim.x + threadIdx.x;
    if (e < E) {
        atomicAdd(&deg_src[src[e]], 1);
        atomicAdd(&deg_dst[dst[e]], 1);
    }
}

// hierarchical exclusive scan, both arrays fused per phase
__global__ void scan_phase1(const int* __restrict__ degA, const int* __restrict__ degB,
                            int* __restrict__ rpA, int* __restrict__ rpB,
                            int* __restrict__ bsA, int* __restrict__ bsB, int n, int nb) {
    __shared__ int sdata[256];
    int bid = blockIdx.x;
    const int* deg; int* rp; int* bs; int seg;
    if (bid < nb) { deg = degA; rp = rpA; bs = bsA; seg = bid; }
    else          { deg = degB; rp = rpB; bs = bsB; seg = bid - nb; }
    int i = seg * 256 + threadIdx.x;
    int v = (i < n) ? deg[i] : 0;
    sdata[threadIdx.x] = v;
    __syncthreads();
    for (int off = 1; off < 256; off <<= 1) {
        int t = (threadIdx.x >= off) ? sdata[threadIdx.x - off] : 0;
        __syncthreads();
        sdata[threadIdx.x] += t;
        __syncthreads();
    }
    if (i < n) rp[i] = sdata[threadIdx.x] - v;   // exclusive within block
    if (threadIdx.x == 255) bs[seg] = sdata[255];
}

__global__ void scan_phase2(int* __restrict__ bsA, int* __restrict__ bsB, int nb,
                            int* __restrict__ rpA, int* __restrict__ rpB, int n) {
    __shared__ int sdata[256];
    __shared__ int s_carry;
    for (int arr = 0; arr < 2; ++arr) {
        int* bs = arr ? bsB : bsA;
        int* rp = arr ? rpB : rpA;
        if (threadIdx.x == 0) s_carry = 0;
        __syncthreads();
        for (int base = 0; base < nb; base += 256) {
            int i = base + threadIdx.x;
            int v = (i < nb) ? bs[i] : 0;
            sdata[threadIdx.x] = v;
            __syncthreads();
            for (int off = 1; off < 256; off <<= 1) {
                int t = (threadIdx.x >= off) ? sdata[threadIdx.x - off] : 0;
                __syncthreads();
                sdata[threadIdx.x] += t;
                __syncthreads();
            }
            if (i < nb) bs[i] = s_carry + sdata[threadIdx.x] - v;
            __syncthreads();
            if (threadIdx.x == 255) s_carry += sdata[255];
            __syncthreads();
        }
        if (threadIdx.x == 0) rp[n] = s_carry;
        __syncthreads();
    }
}

__global__ void scan_phase3(int* __restrict__ rpA, int* __restrict__ rpB,
                            const int* __restrict__ bsA, const int* __restrict__ bsB,
                            int* __restrict__ curA, int* __restrict__ curB, int n, int nb) {
    int bid = blockIdx.x;
    if (bid < nb) {
        int i = bid * 256 + threadIdx.x;
        if (i < n) { int v = rpA[i] + bsA[bid]; rpA[i] = v; curA[i] = v; }
    } else {
        int seg = bid - nb;
        int i = seg * 256 + threadIdx.x;
        if (i < n) { int v = rpB[i] + bsB[seg]; rpB[i] = v; curB[i] = v; }
    }
}

// src-CSR: CSRS[p] = dst (4B). dst-CSR: SRCd[q] = src (4B).
// alpha is computed inline in the scatter kernels, so no qslot/eid links needed.
__global__ void fill_csr(const int* __restrict__ src, const int* __restrict__ dst,
                         int* __restrict__ cur_src, int* __restrict__ cur_dst,
                         int* __restrict__ CSRS, int* __restrict__ SRCd, int E) {
    int e = blockIdx.x * blockDim.x + threadIdx.x;
    if (e < E) {
        int s = src[e], d = dst[e];
        int p = atomicAdd(&cur_src[s], 1);
        int q = atomicAdd(&cur_dst[d], 1);
        __builtin_nontemporal_store(d, CSRS + p);
        __builtin_nontemporal_store(s, SRCd + q);
    }
}

// ---------------- casts / packing ----------------
__global__ void cast_bf16(const float* __restrict__ X, short* __restrict__ Y, int n4) {
    int i = blockIdx.x * blockDim.x + threadIdx.x;
    if (i >= n4) return;
    float4 v = reinterpret_cast<const float4*>(X)[i];
    short4 o;
    o.x = (short)f2bf(v.x); o.y = (short)f2bf(v.y);
    o.z = (short)f2bf(v.z); o.w = (short)f2bf(v.w);
    reinterpret_cast<short4*>(Y)[i] = o;
}

// Pack W (K x ncols f32, row-major) into per-lane MFMA B-fragment layout
__global__ void pack_w(const float* __restrict__ W, short* __restrict__ Wp,
                       int KT, int NCT_total, int ct_base, int nct_local, int ncols) {
    int idx = blockIdx.x * blockDim.x + threadIdx.x;
    int total = KT * nct_local * 512;
    if (idx >= total) return;
    int j = idx & 7;
    int l = (idx >> 3) & 63;
    int t = idx >> 9;
    int ctl = t % nct_local;
    int kt = t / nct_local;
    int k = kt * 32 + (l >> 4) * 8 + j;
    int col = ctl * 16 + (l & 15);
    float v = (col < ncols) ? W[(size_t)k * ncols + col] : 0.f;
    Wp[(((size_t)kt * NCT_total + ct_base + ctl) * 64 + l) * 8 + j] = (short)f2bf(v);
}

// ---------------- MFMA GEMM v4: 8 waves/block, B staged via LDS, fused LN ----------------
template<int KT, int NCT, int NCT_A, bool LNF>
__global__ __launch_bounds__(512) void mfma_gemm_v4(const short* __restrict__ Xb,
                                                    const short* __restrict__ Wp,
                                                    short* __restrict__ XL,
                                                    short* __restrict__ XBb,
                                                    const float* __restrict__ g,
                                                    const float* __restrict__ b,
                                                    int M, int CoA) {
    __shared__ short bsm[NCT * 512];
    const int K = KT * 32;
    int lane = threadIdx.x & 63;
    int wave = threadIdx.x >> 6;
    size_t row0 = ((size_t)blockIdx.x * 8 + wave) * 16;
    bool active = row0 < (size_t)M;
    const short* arow = Xb + (row0 + (lane & 15)) * K + (lane >> 4) * 8;

    f32x4 acc[NCT];
#pragma unroll
    for (int ct = 0; ct < NCT; ++ct) {
        f32x4 z = {0.f, 0.f, 0.f, 0.f};
        acc[ct] = z;
    }

#pragma unroll 1
    for (int kt = 0; kt < KT; ++kt) {
        __syncthreads();   // previous kt's LDS reads complete
        const int4* wsrc = reinterpret_cast<const int4*>(Wp + (size_t)kt * NCT * 512);
        int4* wdst = reinterpret_cast<int4*>(bsm);
        for (int i = threadIdx.x; i < NCT * 64; i += 512) wdst[i] = wsrc[i];
        __syncthreads();
        if (active) {
            bf16x8 a = *reinterpret_cast<const bf16x8*>(arow + kt * 32);
#pragma unroll
            for (int ct = 0; ct < NCT; ++ct) {
                bf16x8 bv = *reinterpret_cast<const bf16x8*>(bsm + ct * 512 + lane * 8);
                acc[ct] = __builtin_amdgcn_mfma_f32_16x16x32_bf16(a, bv, acc[ct], 0, 0, 0);
            }
        }
    }
    if (!active) return;

    int c0 = lane & 15;
    int r0 = (lane >> 4) * 4;
    if constexpr (LNF) {
        float gg[4], bv[4];
#pragma unroll
        for (int m = 0; m < 4; ++m) {
            gg[m] = g[m * 16 + c0];
            bv[m] = b[m * 16 + c0];
        }
#pragma unroll
        for (int h = 0; h < NCT_A / 4; ++h) {
#pragma unroll
            for (int j = 0; j < 4; ++j) {
                float s = acc[4*h+0][j] + acc[4*h+1][j] + acc[4*h+2][j] + acc[4*h+3][j];
                s += __shfl_xor(s, 1, 64); s += __shfl_xor(s, 2, 64);
                s += __shfl_xor(s, 4, 64); s += __shfl_xor(s, 8, 64);
                float mu_ = s * 0.015625f;                 // /64
                float d0 = acc[4*h+0][j] - mu_, d1 = acc[4*h+1][j] - mu_;
                float d2 = acc[4*h+2][j] - mu_, d3 = acc[4*h+3][j] - mu_;
                float s2 = d0*d0 + d1*d1 + d2*d2 + d3*d3;
                s2 += __shfl_xor(s2, 1, 64); s2 += __shfl_xor(s2, 2, 64);
                s2 += __shfl_xor(s2, 4, 64); s2 += __shfl_xor(s2, 8, 64);
                float rs = rsqrtf(s2 * 0.015625f + LN_EPS);
                size_t row = row0 + r0 + j;
                short* rowp = XL + row * 256 + c0;
                rowp[(4*h+0)*16] = (short)f2bf(d0 * rs * gg[0] + bv[0]);
                rowp[(4*h+1)*16] = (short)f2bf(d1 * rs * gg[1] + bv[1]);
                rowp[(4*h+2)*16] = (short)f2bf(d2 * rs * gg[2] + bv[2]);
                rowp[(4*h+3)*16] = (short)f2bf(d3 * rs * gg[3] + bv[3]);
            }
        }
#pragma unroll
        for (int ct = NCT_A; ct < NCT; ++ct) {
#pragma unroll
            for (int j = 0; j < 4; ++j) {
                size_t row = row0 + r0 + j;
                XBb[row * 256 + (ct - NCT_A) * 16 + c0] = (short)f2bf(acc[ct][j]);
            }
        }
    } else {
#pragma unroll
        for (int ct = 0; ct < NCT; ++ct) {
            int col = ct * 16 + c0;
#pragma unroll
            for (int j = 0; j < 4; ++j) {
                size_t row = row0 + r0 + j;
                if (ct < NCT_A) {
                    if (col < CoA) XL[row * CoA + col] = (short)f2bf(acc[ct][j]);
                } else {
                    XBb[row * 256 + (col - NCT_A * 16)] = (short)f2bf(acc[ct][j]);
                }
            }
        }
    }
}

// ---------------- gather kernels: one WAVE per node ----------------

// mu + normalize: MUn[n] = mu[n]/max(||mu[n]||,1e-8) bf16; NRM[n] = ||mu[n]||.
template<int EPL>
__global__ void mu_norm_v3(const short* __restrict__ Xb, const int* __restrict__ rp,
                           const int* __restrict__ CSRS, short* __restrict__ MUn,
                           float* __restrict__ NRM, int N) {
    int n = (blockIdx.x * blockDim.x + threadIdx.x) >> 6;
    int lane = threadIdx.x & 63;
    if (n >= N) return;
    const int Fin = EPL * 64;
    int j0 = rp[n], j1 = rp[n + 1];
    float acc[EPL];
#pragma unroll
    for (int k = 0; k < EPL; ++k) acc[k] = 0.f;
    int j = j0;
    for (; j + 8 <= j1; j += 8) {
        int dd[8];
#pragma unroll
        for (int u = 0; u < 8; ++u) dd[u] = CSRS[j + u];
        float r[8][EPL];
#pragma unroll
        for (int u = 0; u < 8; ++u)
            loadrow<EPL>(Xb + (size_t)dd[u] * Fin + lane * EPL, r[u]);
#pragma unroll
        for (int u = 0; u < 8; ++u)
#pragma unroll
            for (int k = 0; k < EPL; ++k) acc[k] += r[u][k];
    }
    for (; j < j1; ++j) {
        int d = CSRS[j];
        float r[EPL];
        loadrow<EPL>(Xb + (size_t)d * Fin + lane * EPL, r);
#pragma unroll
        for (int k = 0; k < EPL; ++k) acc[k] += r[k];
    }
    float inv = 1.f / fmaxf((float)(j1 - j0), 1.f);
    float m[EPL];
    float s = 0.f;
#pragma unroll
    for (int k = 0; k < EPL; ++k) { m[k] = acc[k] * inv; s += m[k] * m[k]; }
    for (int msk = 32; msk > 0; msk >>= 1) s += __shfl_xor(s, msk, 64);
    float nrm = sqrtf(s);
    float innv = 1.f / fmaxf(nrm, 1e-8f);
#pragma unroll
    for (int k = 0; k < EPL; ++k) m[k] *= innv;
    storerow<EPL>(MUn + (size_t)n * Fin + lane * EPL, m);
    if (lane == 0) NRM[n] = nrm;
}

// per-head LayerNorm in place on bf16 (layer 2 only: H=1, C=40)
__global__ void ln_kernel_bf(short* __restrict__ XL, const float* __restrict__ g,
                             const float* __restrict__ b, int H, int C) {
    int n = blockIdx.x;
    int h = threadIdx.x >> 6;
    int lane = threadIdx.x & 63;
    size_t idx = (size_t)n * H * C + (size_t)h * C + lane;
    float v = (lane < C) ? bf2f(XL[idx]) : 0.f;
    float s = v;
    for (int msk = 32; msk > 0; msk >>= 1) s += __shfl_xor(s, msk, 64);
    float mu_ = s / (float)C;
    float d = (lane < C) ? (v - mu_) : 0.f;
    float s2 = d * d;
    for (int msk = 32; msk > 0; msk >>= 1) s2 += __shfl_xor(s2, msk, 64);
    float var = s2 / (float)C;
    if (lane < C) {
        float y = (v - mu_) * rsqrtf(var + LN_EPS) * g[lane] + b[lane];
        XL[idx] = (short)f2bf(y);
    }
}

// layers 0/1: one wave per dst node. Per edge: gather MUn[s] + XLN[s], compute
// alpha = dot(MUn[n],MUn[s]) inline (normalized rows), accumulate alpha*XLN[s].
// Epilogue: + self + XB + bb, ELU -> bf16. 4-deep unroll = 8 gathers in flight.
template<int EPLM>
__global__ void scatter_fused_elu(const short* __restrict__ MUn, const short* __restrict__ XLN,
                                  const int* __restrict__ rp_dst, const int* __restrict__ SRCd,
                                  const float* __restrict__ NRM,
                                  const short* __restrict__ XB, const float* __restrict__ bb,
                                  short* __restrict__ Yb, int N) {
    int n = (blockIdx.x * blockDim.x + threadIdx.x) >> 6;
    int lane = threadIdx.x & 63;
    if (n >= N) return;
    const int FinM = EPLM * 64;
    float mn[EPLM];
    loadrow<EPLM>(MUn + (size_t)n * FinM + lane * EPLM, mn);
    int j0 = rp_dst[n], j1 = rp_dst[n + 1];
    float acc[4] = {0.f, 0.f, 0.f, 0.f};
    int j = j0;
    for (; j + 4 <= j1; j += 4) {
        int ss[4];
#pragma unroll
        for (int u = 0; u < 4; ++u) ss[u] = SRCd[j + u];
        float ms[4][EPLM], xl[4][4];
#pragma unroll
        for (int u = 0; u < 4; ++u)
            loadrow<EPLM>(MUn + (size_t)ss[u] * FinM + lane * EPLM, ms[u]);
#pragma unroll
        for (int u = 0; u < 4; ++u)
            loadrow<4>(XLN + (size_t)ss[u] * 256 + lane * 4, xl[u]);
        float t[4];
#pragma unroll
        for (int u = 0; u < 4; ++u) {
            float tt = 0.f;
#pragma unroll
            for (int k = 0; k < EPLM; ++k) tt += mn[k] * ms[u][k];
            t[u] = tt;
        }
#pragma unroll
        for (int u = 0; u < 4; ++u)
            for (int msk = 32; msk > 0; msk >>= 1) t[u] += __shfl_xor(t[u], msk, 64);
#pragma unroll
        for (int u = 0; u < 4; ++u)
#pragma unroll
            for (int k = 0; k < 4; ++k) acc[k] += xl[u][k] * t[u];
    }
    for (; j < j1; ++j) {
        int s = SRCd[j];
        float ms[EPLM], xl[4];
        loadrow<EPLM>(MUn + (size_t)s * FinM + lane * EPLM, ms);
        loadrow<4>(XLN + (size_t)s * 256 + lane * 4, xl);
        float t = 0.f;
#pragma unroll
        for (int k = 0; k < EPLM; ++k) t += mn[k] * ms[k];
        for (int msk = 32; msk > 0; msk >>= 1) t += __shfl_xor(t, msk, 64);
#pragma unroll
        for (int k = 0; k < 4; ++k) acc[k] += xl[k] * t;
    }
    float nn = NRM[n], n2 = nn * nn;
    float aself = n2 / fmaxf(n2, COS_EPS);
    float rs[4];
    loadrow<4>(XLN + (size_t)n * 256 + lane * 4, rs);
#pragma unroll
    for (int k = 0; k < 4; ++k) acc[k] += rs[k] * aself;

    float xb[4], o[4];
    loadrow<4>(XB + (size_t)n * 256 + lane * 4, xb);
    float4 bv = *reinterpret_cast<const float4*>(bb + lane * 4);
    o[0] = acc[0] + xb[0] + bv.x; o[1] = acc[1] + xb[1] + bv.y;
    o[2] = acc[2] + xb[2] + bv.z; o[3] = acc[3] + xb[3] + bv.w;
#pragma unroll
    for (int k = 0; k < 4; ++k) o[k] = (o[k] > 0.f) ? o[k] : expm1f(o[k]);
    storerow<4>(Yb + (size_t)n * 256 + lane * 4, o);
}

// layer 2: Co=40, inline alpha (EPLM=4), fused log_softmax -> OUT (f32)
__global__ void scatter_final_fused(const short* __restrict__ MUn, const short* __restrict__ XLN,
                                    const int* __restrict__ rp_dst, const int* __restrict__ SRCd,
                                    const float* __restrict__ NRM, float* __restrict__ OUT,
                                    int N) {
    int n = (blockIdx.x * blockDim.x + threadIdx.x) >> 6;
    int lane = threadIdx.x & 63;
    if (n >= N) return;
    bool act = lane < 40;
    float mn[4];
    loadrow<4>(MUn + (size_t)n * 256 + lane * 4, mn);
    int j0 = rp_dst[n], j1 = rp_dst[n + 1];
    float acc = 0.f;
    int j = j0;
    for (; j + 4 <= j1; j += 4) {
        int ss[4];
#pragma unroll
        for (int u = 0; u < 4; ++u) ss[u] = SRCd[j + u];
        float ms[4][4], xl[4];
#pragma unroll
        for (int u = 0; u < 4; ++u)
            loadrow<4>(MUn + (size_t)ss[u] * 256 + lane * 4, ms[u]);
#pragma unroll
        for (int u = 0; u < 4; ++u)
            xl[u] = act ? bf2f(XLN[(size_t)ss[u] * 40 + lane]) : 0.f;
        float t[4];
#pragma unroll
        for (int u = 0; u < 4; ++u)
            t[u] = mn[0]*ms[u][0] + mn[1]*ms[u][1] + mn[2]*ms[u][2] + mn[3]*ms[u][3];
#pragma unroll
        for (int u = 0; u < 4; ++u)
            for (int msk = 32; msk > 0; msk >>= 1) t[u] += __shfl_xor(t[u], msk, 64);
#pragma unroll
        for (int u = 0; u < 4; ++u) acc += xl[u] * t[u];
    }
    for (; j < j1; ++j) {
        int s = SRCd[j];
        float ms[4];
        loadrow<4>(MUn + (size_t)s * 256 + lane * 4, ms);
        float xl = act ? bf2f(XLN[(size_t)s * 40 + lane]) : 0.f;
        float t = mn[0]*ms[0] + mn[1]*ms[1] + mn[2]*ms[2] + mn[3]*ms[3];
        for (int msk = 32; msk > 0; msk >>= 1) t += __shfl_xor(t, msk, 64);
        acc += xl * t;
    }
    float nn = NRM[n], n2 = nn * nn;
    float aself = n2 / fmaxf(n2, COS_EPS);
    acc += (act ? bf2f(XLN[(size_t)n * 40 + lane]) : 0.f) * aself;

    float v = act ? acc : -INFINITY;
    float mx = v;
    for (int msk = 32; msk > 0; msk >>= 1) mx = fmaxf(mx, __shfl_xor(mx, msk, 64));
    float ex = act ? expf(v - mx) : 0.f;
    float se = ex;
    for (int msk = 32; msk > 0; msk >>= 1) se += __shfl_xor(se, msk, 64);
    if (act) OUT[(size_t)n * 40 + lane] = v - mx - logf(se);
}

extern "C" void kernel_launch(void* const* d_in, const int* in_sizes, int n_in,
                              void* d_out, int out_size, void* d_ws, size_t ws_size,
                              hipStream_t stream) {
    const float* x   = (const float*)d_in[0];
    const int*   ei  = (const int*)d_in[1];
    const float* W0  = (const float*)d_in[2];
    const float* g0  = (const float*)d_in[3];
    const float* b0  = (const float*)d_in[4];
    const float* B0  = (const float*)d_in[5];
    const float* bb0 = (const float*)d_in[6];
    const float* W1  = (const float*)d_in[7];
    const float* g1  = (const float*)d_in[8];
    const float* b1  = (const float*)d_in[9];
    const float* B1  = (const float*)d_in[10];
    const float* bb1 = (const float*)d_in[11];
    const float* W2  = (const float*)d_in[12];
    const float* g2  = (const float*)d_in[13];
    const float* b2  = (const float*)d_in[14];
    // d_in[15]/d_in[16] (B2 256x1, bb2): per-row constant shift, dead under log_softmax.
    float* out = (float*)d_out;

    const int N = in_sizes[0] / 128;
    const int E = in_sizes[1] / 2;
    const int* src = ei;
    const int* dst = ei + E;

    char* ws = (char*)d_ws;
    size_t off = 0;
    auto alloc = [&](size_t bytes) -> void* {
        void* p = ws + off;
        off += (bytes + 255) & ~(size_t)255;
        return p;
    };
    int* deg_src     = (int*)alloc((size_t)N * 4);
    int* deg_dst     = (int*)alloc((size_t)N * 4);
    int* rp_src      = (int*)alloc((size_t)(N + 1) * 4);
    int* rp_dst      = (int*)alloc((size_t)(N + 1) * 4);
    int* cur_src     = (int*)alloc((size_t)N * 4);
    int* cur_dst     = (int*)alloc((size_t)N * 4);
    int* bs_src      = (int*)alloc((size_t)1024 * 4);
    int* bs_dst      = (int*)alloc((size_t)1024 * 4);
    int* CSRS        = (int*)alloc((size_t)E * 4);
    int* SRCd        = (int*)alloc((size_t)E * 4);
    float* NRM       = (float*)alloc((size_t)N * 4);
    short* XBb       = (short*)alloc((size_t)N * 256 * 2);   // bias-path GEMM output (bf16)
    short* MUn       = (short*)alloc((size_t)N * 256 * 2);   // normalized neighborhood means
    short* XLb       = (short*)alloc((size_t)N * 256 * 2);
    short* Xb_a      = (short*)alloc((size_t)N * 256 * 2);
    short* Xb_b      = (short*)alloc((size_t)N * 256 * 2);
    short* Wp        = (short*)alloc((size_t)8 * 32 * 64 * 8 * 2);
    (void)ws_size;

    // ---- CSR build (graph static across layers) ----
    hipMemsetAsync(deg_src, 0, (size_t)N * 4, stream);
    hipMemsetAsync(deg_dst, 0, (size_t)N * 4, stream);
    int egrid = (E + 255) / 256;
    count_deg<<<egrid, 256, 0, stream>>>(src, dst, deg_src, deg_dst, E);
    int nb = (N + 255) / 256;
    scan_phase1<<<2 * nb, 256, 0, stream>>>(deg_src, deg_dst, rp_src, rp_dst,
                                            bs_src, bs_dst, N, nb);
    scan_phase2<<<1, 256, 0, stream>>>(bs_src, bs_dst, nb, rp_src, rp_dst, N);
    scan_phase3<<<2 * nb, 256, 0, stream>>>(rp_src, rp_dst, bs_src, bs_dst,
                                            cur_src, cur_dst, N, nb);
    fill_csr<<<egrid, 256, 0, stream>>>(src, dst, cur_src, cur_dst, CSRS, SRCd, E);

    // cast x -> bf16
    {
        int n4 = (N * 128) / 4;
        cast_bf16<<<(n4 + 255) / 256, 256, 0, stream>>>(x, Xb_a, n4);
    }

    int wgridN = (N * 64 + 255) / 256;  // one wave per node, 4 waves/block
    int ggrid  = (N + 127) / 128;       // 128 rows per GEMM block (8 waves)

    // ---------------- layer 0: Xb_a[N,128] -> Xb_b[N,256] ----------------
    mu_norm_v3<2><<<wgridN, 256, 0, stream>>>(Xb_a, rp_src, CSRS, MUn, NRM, N);
    {
        int tot = 4 * 16 * 512;
        pack_w<<<(tot + 255) / 256, 256, 0, stream>>>(W0, Wp, 4, 32, 0, 16, 256);
        pack_w<<<(tot + 255) / 256, 256, 0, stream>>>(B0, Wp, 4, 32, 16, 16, 256);
    }
    mfma_gemm_v4<4, 32, 16, true><<<ggrid, 512, 0, stream>>>(Xb_a, Wp, XLb, XBb,
                                                             g0, b0, N, 256);
    scatter_fused_elu<2><<<wgridN, 256, 0, stream>>>(MUn, XLb, rp_dst, SRCd, NRM,
                                                     XBb, bb0, Xb_b, N);

    // ---------------- layer 1: Xb_b[N,256] -> Xb_a[N,256] ----------------
    mu_norm_v3<4><<<wgridN, 256, 0, stream>>>(Xb_b, rp_src, CSRS, MUn, NRM, N);
    {
        int tot = 8 * 16 * 512;
        pack_w<<<(tot + 255) / 256, 256, 0, stream>>>(W1, Wp, 8, 32, 0, 16, 256);
        pack_w<<<(tot + 255) / 256, 256, 0, stream>>>(B1, Wp, 8, 32, 16, 16, 256);
    }
    mfma_gemm_v4<8, 32, 16, true><<<ggrid, 512, 0, stream>>>(Xb_b, Wp, XLb, XBb,
                                                             g1, b1, N, 256);
    scatter_fused_elu<4><<<wgridN, 256, 0, stream>>>(MUn, XLb, rp_dst, SRCd, NRM,
                                                     XBb, bb1, Xb_a, N);

    // ---------------- layer 2: Xb_a[N,256] -> out (fused log_softmax) ----------------
    mu_norm_v3<4><<<wgridN, 256, 0, stream>>>(Xb_a, rp_src, CSRS, MUn, NRM, N);
    {
        int tot = 8 * 3 * 512;
        pack_w<<<(tot + 255) / 256, 256, 0, stream>>>(W2, Wp, 8, 3, 0, 3, 40);
    }
    mfma_gemm_v4<8, 3, 3, false><<<ggrid, 512, 0, stream>>>(Xb_a, Wp, XLb, nullptr,
                                                            nullptr, nullptr, N, 40);
    ln_kernel_bf<<<N, 64, 0, stream>>>(XLb, g2, b2, 1, 40);
    scatter_final_fused<<<wgridN, 256, 0, stream>>>(MUn, XLb, rp_dst, SRCd, NRM, out, N);
}

// Round 11
// 674.172 us; speedup vs baseline: 4.0563x; 1.0112x over previous
//
#include <hip/hip_runtime.h>
#include <math.h>

#define LN_EPS 1e-5f
#define COS_EPS 1e-8f

typedef short bf16x8 __attribute__((ext_vector_type(8)));
typedef float f32x4 __attribute__((ext_vector_type(4)));

static __device__ __forceinline__ unsigned short f2bf(float f) {
    unsigned u = __float_as_uint(f);
    u = u + 0x7FFFu + ((u >> 16) & 1u);   // round-to-nearest-even
    return (unsigned short)(u >> 16);
}
static __device__ __forceinline__ float bf2f(short s) {
    return __uint_as_float(((unsigned)(unsigned short)s) << 16);
}

// ---- self-consistent fp8 e4m3 (bias 7) encode/decode, branchless, FTZ ----
static __device__ __forceinline__ unsigned f2fp8(float f) {
    unsigned u = __float_as_uint(f);
    unsigned s = (u >> 24) & 0x80u;
    unsigned mag = (u & 0x7fffffffu) + 0x00080000u;  // round at bit 20
    int e = (int)(mag >> 23) - 120;
    unsigned m = (mag >> 20) & 7u;
    if (e <= 0) return s;                    // flush to zero
    if (e > 15) { e = 15; m = 7u; }          // clamp
    return s | ((unsigned)e << 3) | m;
}
static __device__ __forceinline__ float fp82f(unsigned b) {
    unsigned em = b & 0x7fu;
    unsigned f = ((b & 0x80u) << 24) | ((em << 20) + (120u << 23));
    float v = __uint_as_float(f);
    return (em < 8u) ? 0.f : v;
}

// load/store EPL bf16 elements per lane as one vector op
template<int EPL>
static __device__ __forceinline__ void loadrow(const short* __restrict__ p, float* r) {
    if constexpr (EPL == 4) {
        short4 v = *reinterpret_cast<const short4*>(p);
        r[0] = bf2f(v.x); r[1] = bf2f(v.y); r[2] = bf2f(v.z); r[3] = bf2f(v.w);
    } else {
        short2 v = *reinterpret_cast<const short2*>(p);
        r[0] = bf2f(v.x); r[1] = bf2f(v.y);
    }
}
template<int EPL>
static __device__ __forceinline__ void storerow(short* __restrict__ p, const float* m) {
    if constexpr (EPL == 4) {
        short4 v;
        v.x = (short)f2bf(m[0]); v.y = (short)f2bf(m[1]);
        v.z = (short)f2bf(m[2]); v.w = (short)f2bf(m[3]);
        *reinterpret_cast<short4*>(p) = v;
    } else {
        short2 v;
        v.x = (short)f2bf(m[0]); v.y = (short)f2bf(m[1]);
        *reinterpret_cast<short2*>(p) = v;
    }
}

// load EPL fp8 elements per lane (2 or 4 bytes) and decode
template<int EPL>
static __device__ __forceinline__ void loadrow8(const unsigned char* __restrict__ p, float* r) {
    if constexpr (EPL == 4) {
        unsigned v = *reinterpret_cast<const unsigned*>(p);
        r[0] = fp82f(v & 0xffu); r[1] = fp82f((v >> 8) & 0xffu);
        r[2] = fp82f((v >> 16) & 0xffu); r[3] = fp82f(v >> 24);
    } else {
        unsigned v = *reinterpret_cast<const unsigned short*>(p);
        r[0] = fp82f(v & 0xffu); r[1] = fp82f((v >> 8) & 0xffu);
    }
}

// ---------------- CSR build ----------------
__global__ void count_deg(const int* __restrict__ src, const int* __restrict__ dst,
                          int* __restrict__ deg_src, int* __restrict__ deg_dst, int E) {
    int e = blockIdx.x * blockDim.x + threadIdx.x;
    if (e < E) {
        atomicAdd(&deg_src[src[e]], 1);
        atomicAdd(&deg_dst[dst[e]], 1);
    }
}

__global__ void scan_phase1(const int* __restrict__ degA, const int* __restrict__ degB,
                            int* __restrict__ rpA, int* __restrict__ rpB,
                            int* __restrict__ bsA, int* __restrict__ bsB, int n, int nb) {
    __shared__ int sdata[256];
    int bid = blockIdx.x;
    const int* deg; int* rp; int* bs; int seg;
    if (bid < nb) { deg = degA; rp = rpA; bs = bsA; seg = bid; }
    else          { deg = degB; rp = rpB; bs = bsB; seg = bid - nb; }
    int i = seg * 256 + threadIdx.x;
    int v = (i < n) ? deg[i] : 0;
    sdata[threadIdx.x] = v;
    __syncthreads();
    for (int off = 1; off < 256; off <<= 1) {
        int t = (threadIdx.x >= off) ? sdata[threadIdx.x - off] : 0;
        __syncthreads();
        sdata[threadIdx.x] += t;
        __syncthreads();
    }
    if (i < n) rp[i] = sdata[threadIdx.x] - v;   // exclusive within block
    if (threadIdx.x == 255) bs[seg] = sdata[255];
}

__global__ void scan_phase2(int* __restrict__ bsA, int* __restrict__ bsB, int nb,
                            int* __restrict__ rpA, int* __restrict__ rpB, int n) {
    __shared__ int sdata[256];
    __shared__ int s_carry;
    for (int arr = 0; arr < 2; ++arr) {
        int* bs = arr ? bsB : bsA;
        int* rp = arr ? rpB : rpA;
        if (threadIdx.x == 0) s_carry = 0;
        __syncthreads();
        for (int base = 0; base < nb; base += 256) {
            int i = base + threadIdx.x;
            int v = (i < nb) ? bs[i] : 0;
            sdata[threadIdx.x] = v;
            __syncthreads();
            for (int off = 1; off < 256; off <<= 1) {
                int t = (threadIdx.x >= off) ? sdata[threadIdx.x - off] : 0;
                __syncthreads();
                sdata[threadIdx.x] += t;
                __syncthreads();
            }
            if (i < nb) bs[i] = s_carry + sdata[threadIdx.x] - v;
            __syncthreads();
            if (threadIdx.x == 255) s_carry += sdata[255];
            __syncthreads();
        }
        if (threadIdx.x == 0) rp[n] = s_carry;
        __syncthreads();
    }
}

__global__ void scan_phase3(int* __restrict__ rpA, int* __restrict__ rpB,
                            const int* __restrict__ bsA, const int* __restrict__ bsB,
                            int* __restrict__ curA, int* __restrict__ curB, int n, int nb) {
    int bid = blockIdx.x;
    if (bid < nb) {
        int i = bid * 256 + threadIdx.x;
        if (i < n) { int v = rpA[i] + bsA[bid]; rpA[i] = v; curA[i] = v; }
    } else {
        int seg = bid - nb;
        int i = seg * 256 + threadIdx.x;
        if (i < n) { int v = rpB[i] + bsB[seg]; rpB[i] = v; curB[i] = v; }
    }
}

// src-CSR: CSRS[p] = dst. dst-CSR: SRCd[q] = src. (alpha computed inline later)
__global__ void fill_csr(const int* __restrict__ src, const int* __restrict__ dst,
                         int* __restrict__ cur_src, int* __restrict__ cur_dst,
                         int* __restrict__ CSRS, int* __restrict__ SRCd, int E) {
    int e = blockIdx.x * blockDim.x + threadIdx.x;
    if (e < E) {
        int s = src[e], d = dst[e];
        int p = atomicAdd(&cur_src[s], 1);
        int q = atomicAdd(&cur_dst[d], 1);
        __builtin_nontemporal_store(d, CSRS + p);
        __builtin_nontemporal_store(s, SRCd + q);
    }
}

// ---------------- casts / packing ----------------
__global__ void cast_bf16(const float* __restrict__ X, short* __restrict__ Y, int n4) {
    int i = blockIdx.x * blockDim.x + threadIdx.x;
    if (i >= n4) return;
    float4 v = reinterpret_cast<const float4*>(X)[i];
    short4 o;
    o.x = (short)f2bf(v.x); o.y = (short)f2bf(v.y);
    o.z = (short)f2bf(v.z); o.w = (short)f2bf(v.w);
    reinterpret_cast<short4*>(Y)[i] = o;
}

// Pack W (K x ncols f32, row-major) into per-lane MFMA B-fragment layout
__global__ void pack_w(const float* __restrict__ W, short* __restrict__ Wp,
                       int KT, int NCT_total, int ct_base, int nct_local, int ncols) {
    int idx = blockIdx.x * blockDim.x + threadIdx.x;
    int total = KT * nct_local * 512;
    if (idx >= total) return;
    int j = idx & 7;
    int l = (idx >> 3) & 63;
    int t = idx >> 9;
    int ctl = t % nct_local;
    int kt = t / nct_local;
    int k = kt * 32 + (l >> 4) * 8 + j;
    int col = ctl * 16 + (l & 15);
    float v = (col < ncols) ? W[(size_t)k * ncols + col] : 0.f;
    Wp[(((size_t)kt * NCT_total + ct_base + ctl) * 64 + l) * 8 + j] = (short)f2bf(v);
}

// ---------------- MFMA GEMM v5: 8 waves/block, B via LDS, fused LN epilogues ----
// MODE 0: plain bf16 store (first NCT_A tiles -> XL stride CoA, rest -> XBb bf16)
// MODE 1: per-head LN (heads of 64 cols = 4 tiles) on tiles [0,NCT_A), rest -> XBb
// MODE 2: LN over the first 40 cols (NCT=3 tiles, cols 40-47 padded) -> XL stride 40
template<int KT, int NCT, int NCT_A, int MODE>
__global__ __launch_bounds__(512) void mfma_gemm_v5(const short* __restrict__ Xb,
                                                    const short* __restrict__ Wp,
                                                    short* __restrict__ XL,
                                                    short* __restrict__ XBb,
                                                    const float* __restrict__ g,
                                                    const float* __restrict__ b,
                                                    int M, int CoA) {
    __shared__ short bsm[NCT * 512];
    const int K = KT * 32;
    int lane = threadIdx.x & 63;
    int wave = threadIdx.x >> 6;
    size_t row0 = ((size_t)blockIdx.x * 8 + wave) * 16;
    bool active = row0 < (size_t)M;
    const short* arow = Xb + (row0 + (lane & 15)) * K + (lane >> 4) * 8;

    f32x4 acc[NCT];
#pragma unroll
    for (int ct = 0; ct < NCT; ++ct) {
        f32x4 z = {0.f, 0.f, 0.f, 0.f};
        acc[ct] = z;
    }

#pragma unroll 1
    for (int kt = 0; kt < KT; ++kt) {
        __syncthreads();   // previous kt's LDS reads complete
        const int4* wsrc = reinterpret_cast<const int4*>(Wp + (size_t)kt * NCT * 512);
        int4* wdst = reinterpret_cast<int4*>(bsm);
        for (int i = threadIdx.x; i < NCT * 64; i += 512) wdst[i] = wsrc[i];
        __syncthreads();
        if (active) {
            bf16x8 a = *reinterpret_cast<const bf16x8*>(arow + kt * 32);
#pragma unroll
            for (int ct = 0; ct < NCT; ++ct) {
                bf16x8 bv = *reinterpret_cast<const bf16x8*>(bsm + ct * 512 + lane * 8);
                acc[ct] = __builtin_amdgcn_mfma_f32_16x16x32_bf16(a, bv, acc[ct], 0, 0, 0);
            }
        }
    }
    if (!active) return;

    int c0 = lane & 15;
    int r0 = (lane >> 4) * 4;
    if constexpr (MODE == 1) {
        float gg[4], bv[4];
#pragma unroll
        for (int m = 0; m < 4; ++m) {
            gg[m] = g[m * 16 + c0];
            bv[m] = b[m * 16 + c0];
        }
#pragma unroll
        for (int h = 0; h < NCT_A / 4; ++h) {
#pragma unroll
            for (int j = 0; j < 4; ++j) {
                float s = acc[4*h+0][j] + acc[4*h+1][j] + acc[4*h+2][j] + acc[4*h+3][j];
                s += __shfl_xor(s, 1, 64); s += __shfl_xor(s, 2, 64);
                s += __shfl_xor(s, 4, 64); s += __shfl_xor(s, 8, 64);
                float mu_ = s * 0.015625f;                 // /64
                float d0 = acc[4*h+0][j] - mu_, d1 = acc[4*h+1][j] - mu_;
                float d2 = acc[4*h+2][j] - mu_, d3 = acc[4*h+3][j] - mu_;
                float s2 = d0*d0 + d1*d1 + d2*d2 + d3*d3;
                s2 += __shfl_xor(s2, 1, 64); s2 += __shfl_xor(s2, 2, 64);
                s2 += __shfl_xor(s2, 4, 64); s2 += __shfl_xor(s2, 8, 64);
                float rs = rsqrtf(s2 * 0.015625f + LN_EPS);
                size_t row = row0 + r0 + j;
                short* rowp = XL + row * 256 + c0;
                rowp[(4*h+0)*16] = (short)f2bf(d0 * rs * gg[0] + bv[0]);
                rowp[(4*h+1)*16] = (short)f2bf(d1 * rs * gg[1] + bv[1]);
                rowp[(4*h+2)*16] = (short)f2bf(d2 * rs * gg[2] + bv[2]);
                rowp[(4*h+3)*16] = (short)f2bf(d3 * rs * gg[3] + bv[3]);
            }
        }
#pragma unroll
        for (int ct = NCT_A; ct < NCT; ++ct) {
#pragma unroll
            for (int j = 0; j < 4; ++j) {
                size_t row = row0 + r0 + j;
                XBb[row * 256 + (ct - NCT_A) * 16 + c0] = (short)f2bf(acc[ct][j]);
            }
        }
    } else if constexpr (MODE == 2) {
        // LN over 40 valid cols (tiles 0..2, mask ct==2 && c0>=8)
        bool valid[NCT];
        float gg[NCT], bv[NCT];
#pragma unroll
        for (int ct = 0; ct < NCT; ++ct) {
            int col = ct * 16 + c0;
            valid[ct] = col < 40;
            gg[ct] = valid[ct] ? g[col] : 0.f;
            bv[ct] = valid[ct] ? b[col] : 0.f;
        }
#pragma unroll
        for (int j = 0; j < 4; ++j) {
            float s = 0.f;
#pragma unroll
            for (int ct = 0; ct < NCT; ++ct) s += valid[ct] ? acc[ct][j] : 0.f;
            s += __shfl_xor(s, 1, 64); s += __shfl_xor(s, 2, 64);
            s += __shfl_xor(s, 4, 64); s += __shfl_xor(s, 8, 64);
            float mu_ = s * 0.025f;                        // /40
            float d[NCT];
            float s2 = 0.f;
#pragma unroll
            for (int ct = 0; ct < NCT; ++ct) {
                d[ct] = valid[ct] ? (acc[ct][j] - mu_) : 0.f;
                s2 += d[ct] * d[ct];
            }
            s2 += __shfl_xor(s2, 1, 64); s2 += __shfl_xor(s2, 2, 64);
            s2 += __shfl_xor(s2, 4, 64); s2 += __shfl_xor(s2, 8, 64);
            float rs = rsqrtf(s2 * 0.025f + LN_EPS);
            size_t row = row0 + r0 + j;
#pragma unroll
            for (int ct = 0; ct < NCT; ++ct) {
                int col = ct * 16 + c0;
                if (valid[ct]) XL[row * 40 + col] = (short)f2bf(d[ct] * rs * gg[ct] + bv[ct]);
            }
        }
    } else {
#pragma unroll
        for (int ct = 0; ct < NCT; ++ct) {
            int col = ct * 16 + c0;
#pragma unroll
            for (int j = 0; j < 4; ++j) {
                size_t row = row0 + r0 + j;
                if (ct < NCT_A) {
                    if (col < CoA) XL[row * CoA + col] = (short)f2bf(acc[ct][j]);
                } else {
                    XBb[row * 256 + (col - NCT_A * 16)] = (short)f2bf(acc[ct][j]);
                }
            }
        }
    }
}

// ---------------- gather kernels: one WAVE per node ----------------

// mu + normalize: MUn[n] = fp8(16 * mu[n]/max(||mu[n]||,1e-8)); NRM[n] = ||mu[n]||.
template<int EPL>
__global__ void mu_norm_v4(const short* __restrict__ Xb, const int* __restrict__ rp,
                           const int* __restrict__ CSRS, unsigned char* __restrict__ MUn,
                           float* __restrict__ NRM, int N) {
    int n = (blockIdx.x * blockDim.x + threadIdx.x) >> 6;
    int lane = threadIdx.x & 63;
    if (n >= N) return;
    const int Fin = EPL * 64;
    int j0 = rp[n], j1 = rp[n + 1];
    float acc[EPL];
#pragma unroll
    for (int k = 0; k < EPL; ++k) acc[k] = 0.f;
    int j = j0;
    for (; j + 8 <= j1; j += 8) {
        int dd[8];
#pragma unroll
        for (int u = 0; u < 8; ++u) dd[u] = CSRS[j + u];
        float r[8][EPL];
#pragma unroll
        for (int u = 0; u < 8; ++u)
            loadrow<EPL>(Xb + (size_t)dd[u] * Fin + lane * EPL, r[u]);
#pragma unroll
        for (int u = 0; u < 8; ++u)
#pragma unroll
            for (int k = 0; k < EPL; ++k) acc[k] += r[u][k];
    }
    for (; j < j1; ++j) {
        int d = CSRS[j];
        float r[EPL];
        loadrow<EPL>(Xb + (size_t)d * Fin + lane * EPL, r);
#pragma unroll
        for (int k = 0; k < EPL; ++k) acc[k] += r[k];
    }
    float inv = 1.f / fmaxf((float)(j1 - j0), 1.f);
    float m[EPL];
    float s = 0.f;
#pragma unroll
    for (int k = 0; k < EPL; ++k) { m[k] = acc[k] * inv; s += m[k] * m[k]; }
    for (int msk = 32; msk > 0; msk >>= 1) s += __shfl_xor(s, msk, 64);
    float nrm = sqrtf(s);
    float innv = 16.f / fmaxf(nrm, 1e-8f);      // scale x16 into fp8
    unsigned pk = 0;
#pragma unroll
    for (int k = 0; k < EPL; ++k) pk |= f2fp8(m[k] * innv) << (8 * k);
    if constexpr (EPL == 4)
        *reinterpret_cast<unsigned*>(MUn + (size_t)n * Fin + lane * 4) = pk;
    else
        *reinterpret_cast<unsigned short*>(MUn + (size_t)n * Fin + lane * 2) =
            (unsigned short)pk;
    if (lane == 0) NRM[n] = nrm;
}

// layers 0/1: one wave per dst node. Per edge: gather MUn[s] (fp8) + XLN[s] (bf16),
// alpha = dot(MUn[n],MUn[s])/256 inline, accumulate alpha*XLN[s].
// Epilogue: + self + XB + bb, ELU -> bf16.
template<int EPLM>
__global__ void scatter_fused_elu(const unsigned char* __restrict__ MUn,
                                  const short* __restrict__ XLN,
                                  const int* __restrict__ rp_dst, const int* __restrict__ SRCd,
                                  const float* __restrict__ NRM,
                                  const short* __restrict__ XB, const float* __restrict__ bb,
                                  short* __restrict__ Yb, int N) {
    int n = (blockIdx.x * blockDim.x + threadIdx.x) >> 6;
    int lane = threadIdx.x & 63;
    if (n >= N) return;
    const int FinM = EPLM * 64;
    float mn[EPLM];
    loadrow8<EPLM>(MUn + (size_t)n * FinM + lane * EPLM, mn);
    int j0 = rp_dst[n], j1 = rp_dst[n + 1];
    float acc[4] = {0.f, 0.f, 0.f, 0.f};
    int j = j0;
    for (; j + 4 <= j1; j += 4) {
        int ss[4];
#pragma unroll
        for (int u = 0; u < 4; ++u) ss[u] = SRCd[j + u];
        float ms[4][EPLM], xl[4][4];
#pragma unroll
        for (int u = 0; u < 4; ++u)
            loadrow8<EPLM>(MUn + (size_t)ss[u] * FinM + lane * EPLM, ms[u]);
#pragma unroll
        for (int u = 0; u < 4; ++u)
            loadrow<4>(XLN + (size_t)ss[u] * 256 + lane * 4, xl[u]);
        float t[4];
#pragma unroll
        for (int u = 0; u < 4; ++u) {
            float tt = 0.f;
#pragma unroll
            for (int k = 0; k < EPLM; ++k) tt += mn[k] * ms[u][k];
            t[u] = tt;
        }
#pragma unroll
        for (int u = 0; u < 4; ++u)
            for (int msk = 32; msk > 0; msk >>= 1) t[u] += __shfl_xor(t[u], msk, 64);
#pragma unroll
        for (int u = 0; u < 4; ++u) {
            float al = t[u] * 0.00390625f;   // /256 (16*16 scaling)
#pragma unroll
            for (int k = 0; k < 4; ++k) acc[k] += xl[u][k] * al;
        }
    }
    for (; j < j1; ++j) {
        int s = SRCd[j];
        float ms[EPLM], xl[4];
        loadrow8<EPLM>(MUn + (size_t)s * FinM + lane * EPLM, ms);
        loadrow<4>(XLN + (size_t)s * 256 + lane * 4, xl);
        float t = 0.f;
#pragma unroll
        for (int k = 0; k < EPLM; ++k) t += mn[k] * ms[k];
        for (int msk = 32; msk > 0; msk >>= 1) t += __shfl_xor(t, msk, 64);
        float al = t * 0.00390625f;
#pragma unroll
        for (int k = 0; k < 4; ++k) acc[k] += xl[k] * al;
    }
    float nn = NRM[n], n2 = nn * nn;
    float aself = n2 / fmaxf(n2, COS_EPS);
    float rs[4];
    loadrow<4>(XLN + (size_t)n * 256 + lane * 4, rs);
#pragma unroll
    for (int k = 0; k < 4; ++k) acc[k] += rs[k] * aself;

    float xb[4], o[4];
    loadrow<4>(XB + (size_t)n * 256 + lane * 4, xb);
    float4 bv = *reinterpret_cast<const float4*>(bb + lane * 4);
    o[0] = acc[0] + xb[0] + bv.x; o[1] = acc[1] + xb[1] + bv.y;
    o[2] = acc[2] + xb[2] + bv.z; o[3] = acc[3] + xb[3] + bv.w;
#pragma unroll
    for (int k = 0; k < 4; ++k) o[k] = (o[k] > 0.f) ? o[k] : expm1f(o[k]);
    storerow<4>(Yb + (size_t)n * 256 + lane * 4, o);
}

// layer 2: Co=40, inline alpha (fp8 MUn, EPLM=4), fused log_softmax -> OUT (f32)
__global__ void scatter_final_fused(const unsigned char* __restrict__ MUn,
                                    const short* __restrict__ XLN,
                                    const int* __restrict__ rp_dst, const int* __restrict__ SRCd,
                                    const float* __restrict__ NRM, float* __restrict__ OUT,
                                    int N) {
    int n = (blockIdx.x * blockDim.x + threadIdx.x) >> 6;
    int lane = threadIdx.x & 63;
    if (n >= N) return;
    bool act = lane < 40;
    float mn[4];
    loadrow8<4>(MUn + (size_t)n * 256 + lane * 4, mn);
    int j0 = rp_dst[n], j1 = rp_dst[n + 1];
    float acc = 0.f;
    int j = j0;
    for (; j + 4 <= j1; j += 4) {
        int ss[4];
#pragma unroll
        for (int u = 0; u < 4; ++u) ss[u] = SRCd[j + u];
        float ms[4][4], xl[4];
#pragma unroll
        for (int u = 0; u < 4; ++u)
            loadrow8<4>(MUn + (size_t)ss[u] * 256 + lane * 4, ms[u]);
#pragma unroll
        for (int u = 0; u < 4; ++u)
            xl[u] = act ? bf2f(XLN[(size_t)ss[u] * 40 + lane]) : 0.f;
        float t[4];
#pragma unroll
        for (int u = 0; u < 4; ++u)
            t[u] = mn[0]*ms[u][0] + mn[1]*ms[u][1] + mn[2]*ms[u][2] + mn[3]*ms[u][3];
#pragma unroll
        for (int u = 0; u < 4; ++u)
            for (int msk = 32; msk > 0; msk >>= 1) t[u] += __shfl_xor(t[u], msk, 64);
#pragma unroll
        for (int u = 0; u < 4; ++u) acc += xl[u] * (t[u] * 0.00390625f);
    }
    for (; j < j1; ++j) {
        int s = SRCd[j];
        float ms[4];
        loadrow8<4>(MUn + (size_t)s * 256 + lane * 4, ms);
        float xl = act ? bf2f(XLN[(size_t)s * 40 + lane]) : 0.f;
        float t = mn[0]*ms[0] + mn[1]*ms[1] + mn[2]*ms[2] + mn[3]*ms[3];
        for (int msk = 32; msk > 0; msk >>= 1) t += __shfl_xor(t, msk, 64);
        acc += xl * (t * 0.00390625f);
    }
    float nn = NRM[n], n2 = nn * nn;
    float aself = n2 / fmaxf(n2, COS_EPS);
    acc += (act ? bf2f(XLN[(size_t)n * 40 + lane]) : 0.f) * aself;

    float v = act ? acc : -INFINITY;
    float mx = v;
    for (int msk = 32; msk > 0; msk >>= 1) mx = fmaxf(mx, __shfl_xor(mx, msk, 64));
    float ex = act ? expf(v - mx) : 0.f;
    float se = ex;
    for (int msk = 32; msk > 0; msk >>= 1) se += __shfl_xor(se, msk, 64);
    if (act) OUT[(size_t)n * 40 + lane] = v - mx - logf(se);
}

extern "C" void kernel_launch(void* const* d_in, const int* in_sizes, int n_in,
                              void* d_out, int out_size, void* d_ws, size_t ws_size,
                              hipStream_t stream) {
    const float* x   = (const float*)d_in[0];
    const int*   ei  = (const int*)d_in[1];
    const float* W0  = (const float*)d_in[2];
    const float* g0  = (const float*)d_in[3];
    const float* b0  = (const float*)d_in[4];
    const float* B0  = (const float*)d_in[5];
    const float* bb0 = (const float*)d_in[6];
    const float* W1  = (const float*)d_in[7];
    const float* g1  = (const float*)d_in[8];
    const float* b1  = (const float*)d_in[9];
    const float* B1  = (const float*)d_in[10];
    const float* bb1 = (const float*)d_in[11];
    const float* W2  = (const float*)d_in[12];
    const float* g2  = (const float*)d_in[13];
    const float* b2  = (const float*)d_in[14];
    // d_in[15]/d_in[16] (B2 256x1, bb2): per-row constant shift, dead under log_softmax.
    float* out = (float*)d_out;

    const int N = in_sizes[0] / 128;
    const int E = in_sizes[1] / 2;
    const int* src = ei;
    const int* dst = ei + E;

    char* ws = (char*)d_ws;
    size_t off = 0;
    auto alloc = [&](size_t bytes) -> void* {
        void* p = ws + off;
        off += (bytes + 255) & ~(size_t)255;
        return p;
    };
    int* deg_src     = (int*)alloc((size_t)N * 4);
    int* deg_dst     = (int*)alloc((size_t)N * 4);
    int* rp_src      = (int*)alloc((size_t)(N + 1) * 4);
    int* rp_dst      = (int*)alloc((size_t)(N + 1) * 4);
    int* cur_src     = (int*)alloc((size_t)N * 4);
    int* cur_dst     = (int*)alloc((size_t)N * 4);
    int* bs_src      = (int*)alloc((size_t)1024 * 4);
    int* bs_dst      = (int*)alloc((size_t)1024 * 4);
    int* CSRS        = (int*)alloc((size_t)E * 4);
    int* SRCd        = (int*)alloc((size_t)E * 4);
    float* NRM       = (float*)alloc((size_t)N * 4);
    unsigned char* MUn = (unsigned char*)alloc((size_t)N * 256);  // fp8 normalized means
    short* XBb       = (short*)alloc((size_t)N * 256 * 2);   // bias-path GEMM output (bf16)
    short* XLb       = (short*)alloc((size_t)N * 256 * 2);
    short* Xb_a      = (short*)alloc((size_t)N * 256 * 2);
    short* Xb_b      = (short*)alloc((size_t)N * 256 * 2);
    short* Wp        = (short*)alloc((size_t)8 * 32 * 64 * 8 * 2);
    (void)ws_size;

    // ---- CSR build (graph static across layers) ----
    hipMemsetAsync(deg_src, 0, (size_t)N * 4, stream);
    hipMemsetAsync(deg_dst, 0, (size_t)N * 4, stream);
    int egrid = (E + 255) / 256;
    count_deg<<<egrid, 256, 0, stream>>>(src, dst, deg_src, deg_dst, E);
    int nb = (N + 255) / 256;
    scan_phase1<<<2 * nb, 256, 0, stream>>>(deg_src, deg_dst, rp_src, rp_dst,
                                            bs_src, bs_dst, N, nb);
    scan_phase2<<<1, 256, 0, stream>>>(bs_src, bs_dst, nb, rp_src, rp_dst, N);
    scan_phase3<<<2 * nb, 256, 0, stream>>>(rp_src, rp_dst, bs_src, bs_dst,
                                            cur_src, cur_dst, N, nb);
    fill_csr<<<egrid, 256, 0, stream>>>(src, dst, cur_src, cur_dst, CSRS, SRCd, E);

    // cast x -> bf16
    {
        int n4 = (N * 128) / 4;
        cast_bf16<<<(n4 + 255) / 256, 256, 0, stream>>>(x, Xb_a, n4);
    }

    int wgridN = (N * 64 + 255) / 256;  // one wave per node, 4 waves/block
    int ggrid  = (N + 127) / 128;       // 128 rows per GEMM block (8 waves)

    // ---------------- layer 0: Xb_a[N,128] -> Xb_b[N,256] ----------------
    mu_norm_v4<2><<<wgridN, 256, 0, stream>>>(Xb_a, rp_src, CSRS, MUn, NRM, N);
    {
        int tot = 4 * 16 * 512;
        pack_w<<<(tot + 255) / 256, 256, 0, stream>>>(W0, Wp, 4, 32, 0, 16, 256);
        pack_w<<<(tot + 255) / 256, 256, 0, stream>>>(B0, Wp, 4, 32, 16, 16, 256);
    }
    mfma_gemm_v5<4, 32, 16, 1><<<ggrid, 512, 0, stream>>>(Xb_a, Wp, XLb, XBb,
                                                          g0, b0, N, 256);
    scatter_fused_elu<2><<<wgridN, 256, 0, stream>>>(MUn, XLb, rp_dst, SRCd, NRM,
                                                     XBb, bb0, Xb_b, N);

    // ---------------- layer 1: Xb_b[N,256] -> Xb_a[N,256] ----------------
    mu_norm_v4<4><<<wgridN, 256, 0, stream>>>(Xb_b, rp_src, CSRS, MUn, NRM, N);
    {
        int tot = 8 * 16 * 512;
        pack_w<<<(tot + 255) / 256, 256, 0, stream>>>(W1, Wp, 8, 32, 0, 16, 256);
        pack_w<<<(tot + 255) / 256, 256, 0, stream>>>(B1, Wp, 8, 32, 16, 16, 256);
    }
    mfma_gemm_v5<8, 32, 16, 1><<<ggrid, 512, 0, stream>>>(Xb_b, Wp, XLb, XBb,
                                                          g1, b1, N, 256);
    scatter_fused_elu<4><<<wgridN, 256, 0, stream>>>(MUn, XLb, rp_dst, SRCd, NRM,
                                                     XBb, bb1, Xb_a, N);

    // ---------------- layer 2: Xb_a[N,256] -> out (fused LN + log_softmax) ----------
    mu_norm_v4<4><<<wgridN, 256, 0, stream>>>(Xb_a, rp_src, CSRS, MUn, NRM, N);
    {
        int tot = 8 * 3 * 512;
        pack_w<<<(tot + 255) / 256, 256, 0, stream>>>(W2, Wp, 8, 3, 0, 3, 40);
    }
    mfma_gemm_v5<8, 3, 3, 2><<<ggrid, 512, 0, stream>>>(Xb_a, Wp, XLb, nullptr,
                                                        g2, b2, N, 40);
    scatter_final_fused<<<wgridN, 256, 0, stream>>>(MUn, XLb, rp_dst, SRCd, NRM, out, N);
}

// Round 12
// 632.053 us; speedup vs baseline: 4.3266x; 1.0666x over previous
//
#include <hip/hip_runtime.h>
#include <math.h>

#define LN_EPS 1e-5f
#define COS_EPS 1e-8f

typedef short bf16x8 __attribute__((ext_vector_type(8)));
typedef float f32x4 __attribute__((ext_vector_type(4)));

static __device__ __forceinline__ unsigned short f2bf(float f) {
    unsigned u = __float_as_uint(f);
    u = u + 0x7FFFu + ((u >> 16) & 1u);   // round-to-nearest-even
    return (unsigned short)(u >> 16);
}
static __device__ __forceinline__ float bf2f(short s) {
    return __uint_as_float(((unsigned)(unsigned short)s) << 16);
}

// int8 quantize: clamp(round(f)) to [-127,127], return low byte
static __device__ __forceinline__ unsigned f2i8(float f) {
    int i = (int)rintf(f);
    i = max(-127, min(127, i));
    return (unsigned)i & 0xffu;
}

// 4-way int8 dot: d = a.b + c (per-byte signed). v_dot4_i32_i8 when available.
static __device__ __forceinline__ int dot4i8(int a, int b, int c) {
#if defined(__has_builtin) && __has_builtin(__builtin_amdgcn_sdot4)
    return __builtin_amdgcn_sdot4(a, b, c, false);
#else
    int s = c;
#pragma unroll
    for (int k = 0; k < 4; ++k) {
        int av = (a << (24 - 8 * k)) >> 24;
        int bv = (b << (24 - 8 * k)) >> 24;
        s += av * bv;
    }
    return s;
#endif
}

// load/store EPL bf16 elements per lane as one vector op
template<int EPL>
static __device__ __forceinline__ void loadrow(const short* __restrict__ p, float* r) {
    if constexpr (EPL == 4) {
        short4 v = *reinterpret_cast<const short4*>(p);
        r[0] = bf2f(v.x); r[1] = bf2f(v.y); r[2] = bf2f(v.z); r[3] = bf2f(v.w);
    } else {
        short2 v = *reinterpret_cast<const short2*>(p);
        r[0] = bf2f(v.x); r[1] = bf2f(v.y);
    }
}
template<int EPL>
static __device__ __forceinline__ void storerow(short* __restrict__ p, const float* m) {
    if constexpr (EPL == 4) {
        short4 v;
        v.x = (short)f2bf(m[0]); v.y = (short)f2bf(m[1]);
        v.z = (short)f2bf(m[2]); v.w = (short)f2bf(m[3]);
        *reinterpret_cast<short4*>(p) = v;
    } else {
        short2 v;
        v.x = (short)f2bf(m[0]); v.y = (short)f2bf(m[1]);
        *reinterpret_cast<short2*>(p) = v;
    }
}

// load EPL packed int8 elements per lane as one scalar (zero-extended)
template<int EPL>
static __device__ __forceinline__ int loadpk(const unsigned char* __restrict__ p) {
    if constexpr (EPL == 4) return (int)*reinterpret_cast<const unsigned*>(p);
    else                    return (int)*reinterpret_cast<const unsigned short*>(p);
}

// ---------------- CSR build ----------------
__global__ void count_deg(const int* __restrict__ src, const int* __restrict__ dst,
                          int* __restrict__ deg_src, int* __restrict__ deg_dst, int E) {
    int e = blockIdx.x * blockDim.x + threadIdx.x;
    if (e < E) {
        atomicAdd(&deg_src[src[e]], 1);
        atomicAdd(&deg_dst[dst[e]], 1);
    }
}

__global__ void scan_phase1(const int* __restrict__ degA, const int* __restrict__ degB,
                            int* __restrict__ rpA, int* __restrict__ rpB,
                            int* __restrict__ bsA, int* __restrict__ bsB, int n, int nb) {
    __shared__ int sdata[256];
    int bid = blockIdx.x;
    const int* deg; int* rp; int* bs; int seg;
    if (bid < nb) { deg = degA; rp = rpA; bs = bsA; seg = bid; }
    else          { deg = degB; rp = rpB; bs = bsB; seg = bid - nb; }
    int i = seg * 256 + threadIdx.x;
    int v = (i < n) ? deg[i] : 0;
    sdata[threadIdx.x] = v;
    __syncthreads();
    for (int off = 1; off < 256; off <<= 1) {
        int t = (threadIdx.x >= off) ? sdata[threadIdx.x - off] : 0;
        __syncthreads();
        sdata[threadIdx.x] += t;
        __syncthreads();
    }
    if (i < n) rp[i] = sdata[threadIdx.x] - v;   // exclusive within block
    if (threadIdx.x == 255) bs[seg] = sdata[255];
}

__global__ void scan_phase2(int* __restrict__ bsA, int* __restrict__ bsB, int nb,
                            int* __restrict__ rpA, int* __restrict__ rpB, int n) {
    __shared__ int sdata[256];
    __shared__ int s_carry;
    for (int arr = 0; arr < 2; ++arr) {
        int* bs = arr ? bsB : bsA;
        int* rp = arr ? rpB : rpA;
        if (threadIdx.x == 0) s_carry = 0;
        __syncthreads();
        for (int base = 0; base < nb; base += 256) {
            int i = base + threadIdx.x;
            int v = (i < nb) ? bs[i] : 0;
            sdata[threadIdx.x] = v;
            __syncthreads();
            for (int off = 1; off < 256; off <<= 1) {
                int t = (threadIdx.x >= off) ? sdata[threadIdx.x - off] : 0;
                __syncthreads();
                sdata[threadIdx.x] += t;
                __syncthreads();
            }
            if (i < nb) bs[i] = s_carry + sdata[threadIdx.x] - v;
            __syncthreads();
            if (threadIdx.x == 255) s_carry += sdata[255];
            __syncthreads();
        }
        if (threadIdx.x == 0) rp[n] = s_carry;
        __syncthreads();
    }
}

__global__ void scan_phase3(int* __restrict__ rpA, int* __restrict__ rpB,
                            const int* __restrict__ bsA, const int* __restrict__ bsB,
                            int* __restrict__ curA, int* __restrict__ curB, int n, int nb) {
    int bid = blockIdx.x;
    if (bid < nb) {
        int i = bid * 256 + threadIdx.x;
        if (i < n) { int v = rpA[i] + bsA[bid]; rpA[i] = v; curA[i] = v; }
    } else {
        int seg = bid - nb;
        int i = seg * 256 + threadIdx.x;
        if (i < n) { int v = rpB[i] + bsB[seg]; rpB[i] = v; curB[i] = v; }
    }
}

// src-CSR: CSRS[p] = dst. dst-CSR: SRCd[q] = src. (alpha computed inline later)
__global__ void fill_csr(const int* __restrict__ src, const int* __restrict__ dst,
                         int* __restrict__ cur_src, int* __restrict__ cur_dst,
                         int* __restrict__ CSRS, int* __restrict__ SRCd, int E) {
    int e = blockIdx.x * blockDim.x + threadIdx.x;
    if (e < E) {
        int s = src[e], d = dst[e];
        int p = atomicAdd(&cur_src[s], 1);
        int q = atomicAdd(&cur_dst[d], 1);
        __builtin_nontemporal_store(d, CSRS + p);
        __builtin_nontemporal_store(s, SRCd + q);
    }
}

// ---------------- casts / packing ----------------
__global__ void cast_bf16(const float* __restrict__ X, short* __restrict__ Y, int n4) {
    int i = blockIdx.x * blockDim.x + threadIdx.x;
    if (i >= n4) return;
    float4 v = reinterpret_cast<const float4*>(X)[i];
    short4 o;
    o.x = (short)f2bf(v.x); o.y = (short)f2bf(v.y);
    o.z = (short)f2bf(v.z); o.w = (short)f2bf(v.w);
    reinterpret_cast<short4*>(Y)[i] = o;
}

// Pack W (K x ncols f32, row-major) into per-lane MFMA B-fragment layout
__global__ void pack_w(const float* __restrict__ W, short* __restrict__ Wp,
                       int KT, int NCT_total, int ct_base, int nct_local, int ncols) {
    int idx = blockIdx.x * blockDim.x + threadIdx.x;
    int total = KT * nct_local * 512;
    if (idx >= total) return;
    int j = idx & 7;
    int l = (idx >> 3) & 63;
    int t = idx >> 9;
    int ctl = t % nct_local;
    int kt = t / nct_local;
    int k = kt * 32 + (l >> 4) * 8 + j;
    int col = ctl * 16 + (l & 15);
    float v = (col < ncols) ? W[(size_t)k * ncols + col] : 0.f;
    Wp[(((size_t)kt * NCT_total + ct_base + ctl) * 64 + l) * 8 + j] = (short)f2bf(v);
}

// ---------------- MFMA GEMM v5: 8 waves/block, B via LDS, fused LN epilogues ----
// MODE 0: plain bf16 store. MODE 1: per-head LN (heads of 64 cols), rest -> XBb.
// MODE 2: LN over first 40 cols (NCT=3 tiles, cols 40-47 padded) -> XL stride 40.
template<int KT, int NCT, int NCT_A, int MODE>
__global__ __launch_bounds__(512) void mfma_gemm_v5(const short* __restrict__ Xb,
                                                    const short* __restrict__ Wp,
                                                    short* __restrict__ XL,
                                                    short* __restrict__ XBb,
                                                    const float* __restrict__ g,
                                                    const float* __restrict__ b,
                                                    int M, int CoA) {
    __shared__ short bsm[NCT * 512];
    const int K = KT * 32;
    int lane = threadIdx.x & 63;
    int wave = threadIdx.x >> 6;
    size_t row0 = ((size_t)blockIdx.x * 8 + wave) * 16;
    bool active = row0 < (size_t)M;
    const short* arow = Xb + (row0 + (lane & 15)) * K + (lane >> 4) * 8;

    f32x4 acc[NCT];
#pragma unroll
    for (int ct = 0; ct < NCT; ++ct) {
        f32x4 z = {0.f, 0.f, 0.f, 0.f};
        acc[ct] = z;
    }

#pragma unroll 1
    for (int kt = 0; kt < KT; ++kt) {
        __syncthreads();   // previous kt's LDS reads complete
        const int4* wsrc = reinterpret_cast<const int4*>(Wp + (size_t)kt * NCT * 512);
        int4* wdst = reinterpret_cast<int4*>(bsm);
        for (int i = threadIdx.x; i < NCT * 64; i += 512) wdst[i] = wsrc[i];
        __syncthreads();
        if (active) {
            bf16x8 a = *reinterpret_cast<const bf16x8*>(arow + kt * 32);
#pragma unroll
            for (int ct = 0; ct < NCT; ++ct) {
                bf16x8 bv = *reinterpret_cast<const bf16x8*>(bsm + ct * 512 + lane * 8);
                acc[ct] = __builtin_amdgcn_mfma_f32_16x16x32_bf16(a, bv, acc[ct], 0, 0, 0);
            }
        }
    }
    if (!active) return;

    int c0 = lane & 15;
    int r0 = (lane >> 4) * 4;
    if constexpr (MODE == 1) {
        float gg[4], bv[4];
#pragma unroll
        for (int m = 0; m < 4; ++m) {
            gg[m] = g[m * 16 + c0];
            bv[m] = b[m * 16 + c0];
        }
#pragma unroll
        for (int h = 0; h < NCT_A / 4; ++h) {
#pragma unroll
            for (int j = 0; j < 4; ++j) {
                float s = acc[4*h+0][j] + acc[4*h+1][j] + acc[4*h+2][j] + acc[4*h+3][j];
                s += __shfl_xor(s, 1, 64); s += __shfl_xor(s, 2, 64);
                s += __shfl_xor(s, 4, 64); s += __shfl_xor(s, 8, 64);
                float mu_ = s * 0.015625f;                 // /64
                float d0 = acc[4*h+0][j] - mu_, d1 = acc[4*h+1][j] - mu_;
                float d2 = acc[4*h+2][j] - mu_, d3 = acc[4*h+3][j] - mu_;
                float s2 = d0*d0 + d1*d1 + d2*d2 + d3*d3;
                s2 += __shfl_xor(s2, 1, 64); s2 += __shfl_xor(s2, 2, 64);
                s2 += __shfl_xor(s2, 4, 64); s2 += __shfl_xor(s2, 8, 64);
                float rs = rsqrtf(s2 * 0.015625f + LN_EPS);
                size_t row = row0 + r0 + j;
                short* rowp = XL + row * 256 + c0;
                rowp[(4*h+0)*16] = (short)f2bf(d0 * rs * gg[0] + bv[0]);
                rowp[(4*h+1)*16] = (short)f2bf(d1 * rs * gg[1] + bv[1]);
                rowp[(4*h+2)*16] = (short)f2bf(d2 * rs * gg[2] + bv[2]);
                rowp[(4*h+3)*16] = (short)f2bf(d3 * rs * gg[3] + bv[3]);
            }
        }
#pragma unroll
        for (int ct = NCT_A; ct < NCT; ++ct) {
#pragma unroll
            for (int j = 0; j < 4; ++j) {
                size_t row = row0 + r0 + j;
                XBb[row * 256 + (ct - NCT_A) * 16 + c0] = (short)f2bf(acc[ct][j]);
            }
        }
    } else if constexpr (MODE == 2) {
        bool valid[NCT];
        float gg[NCT], bv[NCT];
#pragma unroll
        for (int ct = 0; ct < NCT; ++ct) {
            int col = ct * 16 + c0;
            valid[ct] = col < 40;
            gg[ct] = valid[ct] ? g[col] : 0.f;
            bv[ct] = valid[ct] ? b[col] : 0.f;
        }
#pragma unroll
        for (int j = 0; j < 4; ++j) {
            float s = 0.f;
#pragma unroll
            for (int ct = 0; ct < NCT; ++ct) s += valid[ct] ? acc[ct][j] : 0.f;
            s += __shfl_xor(s, 1, 64); s += __shfl_xor(s, 2, 64);
            s += __shfl_xor(s, 4, 64); s += __shfl_xor(s, 8, 64);
            float mu_ = s * 0.025f;                        // /40
            float d[NCT];
            float s2 = 0.f;
#pragma unroll
            for (int ct = 0; ct < NCT; ++ct) {
                d[ct] = valid[ct] ? (acc[ct][j] - mu_) : 0.f;
                s2 += d[ct] * d[ct];
            }
            s2 += __shfl_xor(s2, 1, 64); s2 += __shfl_xor(s2, 2, 64);
            s2 += __shfl_xor(s2, 4, 64); s2 += __shfl_xor(s2, 8, 64);
            float rs = rsqrtf(s2 * 0.025f + LN_EPS);
            size_t row = row0 + r0 + j;
#pragma unroll
            for (int ct = 0; ct < NCT; ++ct) {
                int col = ct * 16 + c0;
                if (valid[ct]) XL[row * 40 + col] = (short)f2bf(d[ct] * rs * gg[ct] + bv[ct]);
            }
        }
    } else {
#pragma unroll
        for (int ct = 0; ct < NCT; ++ct) {
            int col = ct * 16 + c0;
#pragma unroll
            for (int j = 0; j < 4; ++j) {
                size_t row = row0 + r0 + j;
                if (ct < NCT_A) {
                    if (col < CoA) XL[row * CoA + col] = (short)f2bf(acc[ct][j]);
                } else {
                    XBb[row * 256 + (col - NCT_A * 16)] = (short)f2bf(acc[ct][j]);
                }
            }
        }
    }
}

// ---------------- gather kernels: one WAVE per node ----------------

// mu + normalize: MUn[n] = int8(127 * mu[n]/max(||mu[n]||,1e-8)); NRM[n] = ||mu[n]||.
template<int EPL>
__global__ void mu_norm_v5(const short* __restrict__ Xb, const int* __restrict__ rp,
                           const int* __restrict__ CSRS, unsigned char* __restrict__ MUn,
                           float* __restrict__ NRM, int N) {
    int n = (blockIdx.x * blockDim.x + threadIdx.x) >> 6;
    int lane = threadIdx.x & 63;
    if (n >= N) return;
    const int Fin = EPL * 64;
    int j0 = rp[n], j1 = rp[n + 1];
    float acc[EPL];
#pragma unroll
    for (int k = 0; k < EPL; ++k) acc[k] = 0.f;
    int j = j0;
    for (; j + 8 <= j1; j += 8) {
        int dd[8];
#pragma unroll
        for (int u = 0; u < 8; ++u) dd[u] = CSRS[j + u];
        float r[8][EPL];
#pragma unroll
        for (int u = 0; u < 8; ++u)
            loadrow<EPL>(Xb + (size_t)dd[u] * Fin + lane * EPL, r[u]);
#pragma unroll
        for (int u = 0; u < 8; ++u)
#pragma unroll
            for (int k = 0; k < EPL; ++k) acc[k] += r[u][k];
    }
    for (; j < j1; ++j) {
        int d = CSRS[j];
        float r[EPL];
        loadrow<EPL>(Xb + (size_t)d * Fin + lane * EPL, r);
#pragma unroll
        for (int k = 0; k < EPL; ++k) acc[k] += r[k];
    }
    float inv = 1.f / fmaxf((float)(j1 - j0), 1.f);
    float m[EPL];
    float s = 0.f;
#pragma unroll
    for (int k = 0; k < EPL; ++k) { m[k] = acc[k] * inv; s += m[k] * m[k]; }
    for (int msk = 32; msk > 0; msk >>= 1) s += __shfl_xor(s, msk, 64);
    float nrm = sqrtf(s);
    float innv = 127.f / fmaxf(nrm, 1e-8f);     // scale x127 into int8
    unsigned pk = 0;
#pragma unroll
    for (int k = 0; k < EPL; ++k) pk |= f2i8(m[k] * innv) << (8 * k);
    if constexpr (EPL == 4)
        *reinterpret_cast<unsigned*>(MUn + (size_t)n * Fin + lane * 4) = pk;
    else
        *reinterpret_cast<unsigned short*>(MUn + (size_t)n * Fin + lane * 2) =
            (unsigned short)pk;
    if (lane == 0) NRM[n] = nrm;
}

// layers 0/1: one wave per dst node. Per edge: gather MUn[s] (int8) + XLN[s] (bf16),
// alpha = sdot4(MUn[n],MUn[s])/127^2 inline, accumulate alpha*XLN[s].
// Epilogue: + self + XB + bb, ELU -> bf16.
template<int EPLM>
__global__ void scatter_fused_elu(const unsigned char* __restrict__ MUn,
                                  const short* __restrict__ XLN,
                                  const int* __restrict__ rp_dst, const int* __restrict__ SRCd,
                                  const float* __restrict__ NRM,
                                  const short* __restrict__ XB, const float* __restrict__ bb,
                                  short* __restrict__ Yb, int N) {
    const float ISC = 1.f / 16129.f;   // 1/127^2
    int n = (blockIdx.x * blockDim.x + threadIdx.x) >> 6;
    int lane = threadIdx.x & 63;
    if (n >= N) return;
    const int FinM = EPLM * 64;
    int mn_i = loadpk<EPLM>(MUn + (size_t)n * FinM + lane * EPLM);
    int j0 = rp_dst[n], j1 = rp_dst[n + 1];
    float acc[4] = {0.f, 0.f, 0.f, 0.f};
    int j = j0;
    for (; j + 4 <= j1; j += 4) {
        int ss[4];
#pragma unroll
        for (int u = 0; u < 4; ++u) ss[u] = SRCd[j + u];
        int ms[4];
        float xl[4][4];
#pragma unroll
        for (int u = 0; u < 4; ++u)
            ms[u] = loadpk<EPLM>(MUn + (size_t)ss[u] * FinM + lane * EPLM);
#pragma unroll
        for (int u = 0; u < 4; ++u)
            loadrow<4>(XLN + (size_t)ss[u] * 256 + lane * 4, xl[u]);
        int t[4];
#pragma unroll
        for (int u = 0; u < 4; ++u) t[u] = dot4i8(mn_i, ms[u], 0);
#pragma unroll
        for (int u = 0; u < 4; ++u)
            for (int msk = 32; msk > 0; msk >>= 1) t[u] += __shfl_xor(t[u], msk, 64);
#pragma unroll
        for (int u = 0; u < 4; ++u) {
            float al = (float)t[u] * ISC;
#pragma unroll
            for (int k = 0; k < 4; ++k) acc[k] += xl[u][k] * al;
        }
    }
    for (; j < j1; ++j) {
        int s = SRCd[j];
        int ms = loadpk<EPLM>(MUn + (size_t)s * FinM + lane * EPLM);
        float xl[4];
        loadrow<4>(XLN + (size_t)s * 256 + lane * 4, xl);
        int t = dot4i8(mn_i, ms, 0);
        for (int msk = 32; msk > 0; msk >>= 1) t += __shfl_xor(t, msk, 64);
        float al = (float)t * ISC;
#pragma unroll
        for (int k = 0; k < 4; ++k) acc[k] += xl[k] * al;
    }
    float nn = NRM[n], n2 = nn * nn;
    float aself = n2 / fmaxf(n2, COS_EPS);
    float rs[4];
    loadrow<4>(XLN + (size_t)n * 256 + lane * 4, rs);
#pragma unroll
    for (int k = 0; k < 4; ++k) acc[k] += rs[k] * aself;

    float xb[4], o[4];
    loadrow<4>(XB + (size_t)n * 256 + lane * 4, xb);
    float4 bv = *reinterpret_cast<const float4*>(bb + lane * 4);
    o[0] = acc[0] + xb[0] + bv.x; o[1] = acc[1] + xb[1] + bv.y;
    o[2] = acc[2] + xb[2] + bv.z; o[3] = acc[3] + xb[3] + bv.w;
#pragma unroll
    for (int k = 0; k < 4; ++k) o[k] = (o[k] > 0.f) ? o[k] : expm1f(o[k]);
    storerow<4>(Yb + (size_t)n * 256 + lane * 4, o);
}

// layer 2: Co=40, inline int8 alpha (EPLM=4), fused log_softmax -> OUT (f32)
__global__ void scatter_final_fused(const unsigned char* __restrict__ MUn,
                                    const short* __restrict__ XLN,
                                    const int* __restrict__ rp_dst, const int* __restrict__ SRCd,
                                    const float* __restrict__ NRM, float* __restrict__ OUT,
                                    int N) {
    const float ISC = 1.f / 16129.f;
    int n = (blockIdx.x * blockDim.x + threadIdx.x) >> 6;
    int lane = threadIdx.x & 63;
    if (n >= N) return;
    bool act = lane < 40;
    int mn_i = loadpk<4>(MUn + (size_t)n * 256 + lane * 4);
    int j0 = rp_dst[n], j1 = rp_dst[n + 1];
    float acc = 0.f;
    int j = j0;
    for (; j + 4 <= j1; j += 4) {
        int ss[4];
#pragma unroll
        for (int u = 0; u < 4; ++u) ss[u] = SRCd[j + u];
        int ms[4];
        float xl[4];
#pragma unroll
        for (int u = 0; u < 4; ++u)
            ms[u] = loadpk<4>(MUn + (size_t)ss[u] * 256 + lane * 4);
#pragma unroll
        for (int u = 0; u < 4; ++u)
            xl[u] = act ? bf2f(XLN[(size_t)ss[u] * 40 + lane]) : 0.f;
        int t[4];
#pragma unroll
        for (int u = 0; u < 4; ++u) t[u] = dot4i8(mn_i, ms[u], 0);
#pragma unroll
        for (int u = 0; u < 4; ++u)
            for (int msk = 32; msk > 0; msk >>= 1) t[u] += __shfl_xor(t[u], msk, 64);
#pragma unroll
        for (int u = 0; u < 4; ++u) acc += xl[u] * ((float)t[u] * ISC);
    }
    for (; j < j1; ++j) {
        int s = SRCd[j];
        int ms = loadpk<4>(MUn + (size_t)s * 256 + lane * 4);
        float xl = act ? bf2f(XLN[(size_t)s * 40 + lane]) : 0.f;
        int t = dot4i8(mn_i, ms, 0);
        for (int msk = 32; msk > 0; msk >>= 1) t += __shfl_xor(t, msk, 64);
        acc += xl * ((float)t * ISC);
    }
    float nn = NRM[n], n2 = nn * nn;
    float aself = n2 / fmaxf(n2, COS_EPS);
    acc += (act ? bf2f(XLN[(size_t)n * 40 + lane]) : 0.f) * aself;

    float v = act ? acc : -INFINITY;
    float mx = v;
    for (int msk = 32; msk > 0; msk >>= 1) mx = fmaxf(mx, __shfl_xor(mx, msk, 64));
    float ex = act ? expf(v - mx) : 0.f;
    float se = ex;
    for (int msk = 32; msk > 0; msk >>= 1) se += __shfl_xor(se, msk, 64);
    if (act) OUT[(size_t)n * 40 + lane] = v - mx - logf(se);
}

extern "C" void kernel_launch(void* const* d_in, const int* in_sizes, int n_in,
                              void* d_out, int out_size, void* d_ws, size_t ws_size,
                              hipStream_t stream) {
    const float* x   = (const float*)d_in[0];
    const int*   ei  = (const int*)d_in[1];
    const float* W0  = (const float*)d_in[2];
    const float* g0  = (const float*)d_in[3];
    const float* b0  = (const float*)d_in[4];
    const float* B0  = (const float*)d_in[5];
    const float* bb0 = (const float*)d_in[6];
    const float* W1  = (const float*)d_in[7];
    const float* g1  = (const float*)d_in[8];
    const float* b1  = (const float*)d_in[9];
    const float* B1  = (const float*)d_in[10];
    const float* bb1 = (const float*)d_in[11];
    const float* W2  = (const float*)d_in[12];
    const float* g2  = (const float*)d_in[13];
    const float* b2  = (const float*)d_in[14];
    // d_in[15]/d_in[16] (B2 256x1, bb2): per-row constant shift, dead under log_softmax.
    float* out = (float*)d_out;

    const int N = in_sizes[0] / 128;
    const int E = in_sizes[1] / 2;
    const int* src = ei;
    const int* dst = ei + E;

    char* ws = (char*)d_ws;
    size_t off = 0;
    auto alloc = [&](size_t bytes) -> void* {
        void* p = ws + off;
        off += (bytes + 255) & ~(size_t)255;
        return p;
    };
    int* deg_src     = (int*)alloc((size_t)N * 4);
    int* deg_dst     = (int*)alloc((size_t)N * 4);
    int* rp_src      = (int*)alloc((size_t)(N + 1) * 4);
    int* rp_dst      = (int*)alloc((size_t)(N + 1) * 4);
    int* cur_src     = (int*)alloc((size_t)N * 4);
    int* cur_dst     = (int*)alloc((size_t)N * 4);
    int* bs_src      = (int*)alloc((size_t)1024 * 4);
    int* bs_dst      = (int*)alloc((size_t)1024 * 4);
    int* CSRS        = (int*)alloc((size_t)E * 4);
    int* SRCd        = (int*)alloc((size_t)E * 4);
    float* NRM       = (float*)alloc((size_t)N * 4);
    unsigned char* MUn = (unsigned char*)alloc((size_t)N * 256);  // int8 normalized means
    short* XBb       = (short*)alloc((size_t)N * 256 * 2);   // bias-path GEMM output (bf16)
    short* XLb       = (short*)alloc((size_t)N * 256 * 2);
    short* Xb_a      = (short*)alloc((size_t)N * 256 * 2);
    short* Xb_b      = (short*)alloc((size_t)N * 256 * 2);
    short* Wp        = (short*)alloc((size_t)8 * 32 * 64 * 8 * 2);
    (void)ws_size;

    // ---- CSR build (graph static across layers) ----
    hipMemsetAsync(deg_src, 0, (size_t)N * 4, stream);
    hipMemsetAsync(deg_dst, 0, (size_t)N * 4, stream);
    int egrid = (E + 255) / 256;
    count_deg<<<egrid, 256, 0, stream>>>(src, dst, deg_src, deg_dst, E);
    int nb = (N + 255) / 256;
    scan_phase1<<<2 * nb, 256, 0, stream>>>(deg_src, deg_dst, rp_src, rp_dst,
                                            bs_src, bs_dst, N, nb);
    scan_phase2<<<1, 256, 0, stream>>>(bs_src, bs_dst, nb, rp_src, rp_dst, N);
    scan_phase3<<<2 * nb, 256, 0, stream>>>(rp_src, rp_dst, bs_src, bs_dst,
                                            cur_src, cur_dst, N, nb);
    fill_csr<<<egrid, 256, 0, stream>>>(src, dst, cur_src, cur_dst, CSRS, SRCd, E);

    // cast x -> bf16
    {
        int n4 = (N * 128) / 4;
        cast_bf16<<<(n4 + 255) / 256, 256, 0, stream>>>(x, Xb_a, n4);
    }

    int wgridN = (N * 64 + 255) / 256;  // one wave per node, 4 waves/block
    int ggrid  = (N + 127) / 128;       // 128 rows per GEMM block (8 waves)

    // ---------------- layer 0: Xb_a[N,128] -> Xb_b[N,256] ----------------
    mu_norm_v5<2><<<wgridN, 256, 0, stream>>>(Xb_a, rp_src, CSRS, MUn, NRM, N);
    {
        int tot = 4 * 16 * 512;
        pack_w<<<(tot + 255) / 256, 256, 0, stream>>>(W0, Wp, 4, 32, 0, 16, 256);
        pack_w<<<(tot + 255) / 256, 256, 0, stream>>>(B0, Wp, 4, 32, 16, 16, 256);
    }
    mfma_gemm_v5<4, 32, 16, 1><<<ggrid, 512, 0, stream>>>(Xb_a, Wp, XLb, XBb,
                                                          g0, b0, N, 256);
    scatter_fused_elu<2><<<wgridN, 256, 0, stream>>>(MUn, XLb, rp_dst, SRCd, NRM,
                                                     XBb, bb0, Xb_b, N);

    // ---------------- layer 1: Xb_b[N,256] -> Xb_a[N,256] ----------------
    mu_norm_v5<4><<<wgridN, 256, 0, stream>>>(Xb_b, rp_src, CSRS, MUn, NRM, N);
    {
        int tot = 8 * 16 * 512;
        pack_w<<<(tot + 255) / 256, 256, 0, stream>>>(W1, Wp, 8, 32, 0, 16, 256);
        pack_w<<<(tot + 255) / 256, 256, 0, stream>>>(B1, Wp, 8, 32, 16, 16, 256);
    }
    mfma_gemm_v5<8, 32, 16, 1><<<ggrid, 512, 0, stream>>>(Xb_b, Wp, XLb, XBb,
                                                          g1, b1, N, 256);
    scatter_fused_elu<4><<<wgridN, 256, 0, stream>>>(MUn, XLb, rp_dst, SRCd, NRM,
                                                     XBb, bb1, Xb_a, N);

    // ---------------- layer 2: Xb_a[N,256] -> out (fused LN + log_softmax) ----------
    mu_norm_v5<4><<<wgridN, 256, 0, stream>>>(Xb_a, rp_src, CSRS, MUn, NRM, N);
    {
        int tot = 8 * 3 * 512;
        pack_w<<<(tot + 255) / 256, 256, 0, stream>>>(W2, Wp, 8, 3, 0, 3, 40);
    }
    mfma_gemm_v5<8, 3, 3, 2><<<ggrid, 512, 0, stream>>>(Xb_a, Wp, XLb, nullptr,
                                                        g2, b2, N, 40);
    scatter_final_fused<<<wgridN, 256, 0, stream>>>(MUn, XLb, rp_dst, SRCd, NRM, out, N);
}